// Round 5
// baseline (42772.723 us; speedup 1.0000x reference)
//
#include <hip/hip_runtime.h>
#include <hip/hip_bf16.h>
#include <cfloat>
#include <cmath>

static constexpr int Bb = 2, Nn = 1024, Dd = 768, Hh = 12, HDd = 64, FFf = 3072, NLl = 12, NCc = 1000;
static constexpr int Mm = Bb * Nn; // 2048
static constexpr float NEGF = -3.402823466e38f;

// ---------- reductions (256-thread blocks = 4 waves) ----------
__device__ __forceinline__ float block_reduce_sum(float v, volatile float* smem) {
  for (int o = 32; o; o >>= 1) v += __shfl_down(v, o);
  int lane = threadIdx.x & 63, w = threadIdx.x >> 6;
  __syncthreads();
  if (lane == 0) smem[w] = v;
  __syncthreads();
  return smem[0] + smem[1] + smem[2] + smem[3];
}

__device__ __forceinline__ float block_reduce_max(float v, volatile float* smem) {
  for (int o = 32; o; o >>= 1) v = fmaxf(v, __shfl_down(v, o));
  int lane = threadIdx.x & 63, w = threadIdx.x >> 6;
  __syncthreads();
  if (lane == 0) smem[w] = v;
  __syncthreads();
  return fmaxf(fmaxf(smem[0], smem[1]), fmaxf(smem[2], smem[3]));
}

// ---------- mask dtype detection: 0=int32 1=bytes 2=f32 3=int64 4=bf16 ----------
__global__ void detect_mask(const unsigned char* __restrict__ m, int* __restrict__ flag) {
  __shared__ int s_nz1, s_nz2, s_nz3, s_nz84, s_pv;
  int tid = threadIdx.x;
  if (tid == 0) { s_nz1 = 0; s_nz2 = 0; s_nz3 = 0; s_nz84 = 0; s_pv = 0; }
  __syncthreads();
  int nz1 = 0, nz2 = 0, nz3 = 0, nz84 = 0, pv = 0;
  for (int i = tid; i < 2048; i += 256) {
    unsigned char v = m[i];
    if (v) {
      int p4 = i & 3;
      if (p4 == 1) nz1 = 1;
      if (p4 == 2) nz2 = 1;
      if (p4 == 3) nz3 = 1;
      if ((i & 7) == 4) nz84 = 1;
      if ((i & 1) == 0) { if (v != 0x80) pv = 1; }
      else              { if (v != 0x3f) pv = 1; }
    }
  }
  if (nz1)  atomicOr(&s_nz1, 1);
  if (nz2)  atomicOr(&s_nz2, 1);
  if (nz3)  atomicOr(&s_nz3, 1);
  if (nz84) atomicOr(&s_nz84, 1);
  if (pv)   atomicOr(&s_pv, 1);
  __syncthreads();
  if (tid == 0) {
    int f;
    if (!s_nz1 && !s_nz2 && !s_nz3) f = s_nz84 ? 0 : 3;  // nonzeros only on 4B boundaries: int32 vs int64
    else if (!s_pv)                 f = s_nz1 ? 4 : 2;   // clean 0x80/0x3f pattern: bf16 vs f32
    else                            f = 1;               // arbitrary bytes: bool8
    *flag = f;
  }
}

__device__ __forceinline__ bool mask_at(const void* mraw, int flag, int idx) {
  switch (flag) {
    case 0:  return ((const int*)mraw)[idx] != 0;
    case 1:  return ((const unsigned char*)mraw)[idx] != 0;
    case 2:  return ((const float*)mraw)[idx] != 0.f;
    case 3:  return ((const long long*)mraw)[idx] != 0;
    default: return ((const unsigned short*)mraw)[idx] != 0;
  }
}

// ---------- h = x + pe (pe broadcast over batch) ----------
__global__ __launch_bounds__(256) void add_pe_k(const float* __restrict__ x, const float* __restrict__ pe,
                                                float* __restrict__ h) {
  long i = (long)blockIdx.x * 256 + threadIdx.x;
  long nd = i % ((long)Nn * Dd);
  h[i] = x[i] + pe[nd];
}

// ---------- LayerNorm (optionally with residual input added first), row = 768 ----------
__global__ __launch_bounds__(256) void ln_kernel(const float* __restrict__ X, const float* __restrict__ R,
                                                 const float* __restrict__ w, const float* __restrict__ b,
                                                 float* __restrict__ Y) {
  __shared__ float smem[4];
  int row = blockIdx.x, tid = threadIdx.x;
  const float* x = X + (size_t)row * Dd;
  const bool hasR = (R != nullptr);
  const float* r = hasR ? R + (size_t)row * Dd : nullptr;
  float v[3];
  for (int j = 0; j < 3; ++j) {
    int c = tid + j * 256;
    v[j] = x[c] + (hasR ? r[c] : 0.f);
  }
  float s = v[0] + v[1] + v[2];
  s = block_reduce_sum(s, smem);
  float mean = s * (1.f / 768.f);
  float q = 0.f;
  for (int j = 0; j < 3; ++j) { float d = v[j] - mean; q += d * d; }
  q = block_reduce_sum(q, smem);
  float inv = rsqrtf(q * (1.f / 768.f) + 1e-5f);
  for (int j = 0; j < 3; ++j) {
    int c = tid + j * 256;
    Y[(size_t)row * Dd + c] = (v[j] - mean) * inv * w[c] + b[c];
  }
}

// ---------- naive, correct-by-construction f32 GEMM ----------
// grid: (Nsz/64, Msz/4, Z), block: (64, 4).
template<int BLAY, int EPI>
__global__ __launch_bounds__(256) void gemm_naive(
    const float* __restrict__ A, long lda, long Azq, long Azr,
    const float* __restrict__ Bm, long ldb, long Bzq, long Bzr,
    const float* __restrict__ bias, const float* __restrict__ resid,
    float* __restrict__ C, long ldc, long Czq, long Czr,
    int Ksize, float alpha, int zdiv)
{
  int n = blockIdx.x * 64 + threadIdx.x;
  int m = blockIdx.y * 4 + threadIdx.y;
  int z = blockIdx.z;
  int zq = z / zdiv, zr = z % zdiv;
  const float* Ap = A + (long)zq * Azq + (long)zr * Azr + (long)m * lda;
  const float* Bp = Bm + (long)zq * Bzq + (long)zr * Bzr;
  float acc = 0.f;
  if (BLAY == 1) {
    const float* Bn = Bp + (long)n * ldb;
    #pragma unroll 8
    for (int k = 0; k < Ksize; ++k) acc = fmaf(Ap[k], Bn[k], acc);
  } else {
    #pragma unroll 8
    for (int k = 0; k < Ksize; ++k) acc = fmaf(Ap[k], Bp[(long)k * ldb + n], acc);
  }
  float v = acc * alpha;
  if (EPI >= 1) v += bias[n];
  if (EPI == 2) v = 0.5f * v * (1.f + erff(v * 0.70710678118654752f));
  if (EPI == 3) v += resid[(long)m * ldc + n];
  C[(long)zq * Czq + (long)zr * Czr + (long)m * ldc + n] = v;
}

// ---------- flash attention: streaming masked softmax(QK^T/8) @ V, no scores buffer ----------
// grid: (Nn/4, Hh, Bb), block 256 (4 waves; wave w handles q-row blockIdx.x*4 + w).
// qkvf layout: row-major (B*N, 3*768); Q at col h*64, K at 768+h*64, V at 1536+h*64.
// o layout: row-major (B*N, 768), head h at col h*64.
__global__ __launch_bounds__(256) void flash_attn(const float* __restrict__ qkvf,
                                                  const void* __restrict__ mraw,
                                                  const int* __restrict__ flagp,
                                                  float* __restrict__ o) {
  __shared__ float Kt[64][65];
  __shared__ float Vt[64][65];
  __shared__ float qs[4][64];
  __shared__ float ps[4][64];
  int b = blockIdx.z, hh = blockIdx.y;
  int tid = threadIdx.x, lane = tid & 63, w = tid >> 6;
  int qrow = blockIdx.x * 4 + w;
  int flag = *flagp;

  const long qbase = ((long)(b * Nn + qrow)) * (3 * Dd) + hh * HDd;
  qs[w][lane] = qkvf[qbase + lane];
  bool mi = mask_at(mraw, flag, b * Nn + qrow);

  float m = -INFINITY, l = 0.f, accd = 0.f;

  const int sr = tid >> 2;          // staging row 0..63
  const int sc = (tid & 3) * 16;    // staging col start

  for (int j0 = 0; j0 < Nn; j0 += 64) {
    __syncthreads();  // previous tile fully consumed by all waves
    {
      const float* Ksrc = qkvf + ((long)(b * Nn + j0 + sr)) * (3 * Dd) + Dd + hh * HDd + sc;
      const float* Vsrc = Ksrc + Dd;
      #pragma unroll
      for (int j = 0; j < 16; ++j) {
        Kt[sr][sc + j] = Ksrc[j];
        Vt[sr][sc + j] = Vsrc[j];
      }
    }
    __syncthreads();

    // s_j for this wave's q-row: lane j owns key j0+j
    float s = 0.f;
    #pragma unroll 8
    for (int d = 0; d < 64; ++d) s = fmaf(qs[w][d], Kt[lane][d], s);
    s *= 0.125f;
    bool mj = mask_at(mraw, flag, b * Nn + j0 + lane);
    if (!(mi && mj)) s = NEGF;

    float mt = s;
    for (int off = 32; off; off >>= 1) mt = fmaxf(mt, __shfl_xor(mt, off));
    float mn = fmaxf(m, mt);                 // mn >= NEGF (finite) always
    float r = expf(m - mn);                  // first tile: exp(-inf)=0
    float p = expf(s - mn);                  // masked & mn==NEGF -> exp(0)=1 (uniform row), matches ref
    ps[w][lane] = p;
    float ls = p;
    for (int off = 32; off; off >>= 1) ls += __shfl_xor(ls, off);
    l = l * r + ls;

    float av = 0.f;
    #pragma unroll 8
    for (int j = 0; j < 64; ++j) av = fmaf(ps[w][j], Vt[j][lane], av);
    accd = accd * r + av;
    m = mn;
  }
  o[((long)(b * Nn + qrow)) * Dd + hh * HDd + lane] = accd / l;
}

// ---------- seq-pool ----------
__global__ __launch_bounds__(256) void pool_score(const float* __restrict__ hn, const float* __restrict__ pw,
                                                  const float* __restrict__ pb, float* __restrict__ s) {
  __shared__ float smem[4];
  int row = blockIdx.x, tid = threadIdx.x;
  const float* x = hn + (size_t)row * Dd;
  float acc = 0.f;
  for (int j = 0; j < 3; ++j) { int c = tid + j * 256; acc += x[c] * pw[c]; }
  acc = block_reduce_sum(acc, smem);
  if (tid == 0) s[row] = acc + pb[0];
}

__global__ __launch_bounds__(256) void pool_softmax(const float* __restrict__ s, float* __restrict__ w) {
  __shared__ float smem[4];
  int b = blockIdx.x, tid = threadIdx.x;
  const float* x = s + b * Nn;
  float v[4];
  for (int j = 0; j < 4; ++j) v[j] = x[tid * 4 + j];
  float mx = fmaxf(fmaxf(v[0], v[1]), fmaxf(v[2], v[3]));
  mx = block_reduce_max(mx, smem);
  float e[4], sum = 0.f;
  for (int j = 0; j < 4; ++j) { e[j] = expf(v[j] - mx); sum += e[j]; }
  sum = block_reduce_sum(sum, smem);
  float inv = 1.f / sum;
  for (int j = 0; j < 4; ++j) w[b * Nn + tid * 4 + j] = e[j] * inv;
}

__global__ __launch_bounds__(256) void pool_reduce(const float* __restrict__ hn, const float* __restrict__ w,
                                                   float* __restrict__ pooled) {
  int b = blockIdx.x, tid = threadIdx.x;
  float acc[3] = {0.f, 0.f, 0.f};
  for (int n = 0; n < Nn; ++n) {
    float wn = w[b * Nn + n];
    const float* hr = hn + ((size_t)(b * Nn + n)) * Dd;
    for (int j = 0; j < 3; ++j) acc[j] += wn * hr[tid + j * 256];
  }
  for (int j = 0; j < 3; ++j) pooled[b * Dd + tid + j * 256] = acc[j];
}

__global__ __launch_bounds__(256) void fc_kernel(const float* __restrict__ pooled, const float* __restrict__ fw,
                                                 const float* __restrict__ fb, float* __restrict__ out) {
  __shared__ float p[768];
  int b = blockIdx.x, tid = threadIdx.x;
  for (int j = 0; j < 3; ++j) p[tid + j * 256] = pooled[b * Dd + tid + j * 256];
  __syncthreads();
  for (int c = tid; c < NCc; c += 256) {
    float acc = fb[c];
    for (int d = 0; d < Dd; ++d) acc += p[d] * fw[(size_t)d * NCc + c];
    out[b * NCc + c] = acc;
  }
}

extern "C" void kernel_launch(void* const* d_in, const int* in_sizes, int n_in,
                              void* d_out, int out_size, void* d_ws, size_t ws_size,
                              hipStream_t stream) {
  const float* x      = (const float*)d_in[0];
  const void*  mask   = d_in[1];
  const float* pe     = (const float*)d_in[2];
  const float* ln0_w  = (const float*)d_in[3];
  const float* ln0_b  = (const float*)d_in[4];
  const float* qkv_w  = (const float*)d_in[5];
  const float* proj_w = (const float*)d_in[6];
  const float* proj_b = (const float*)d_in[7];
  const float* ln1_w  = (const float*)d_in[8];
  const float* ln1_b  = (const float*)d_in[9];
  const float* ff1_w  = (const float*)d_in[10];
  const float* ff1_b  = (const float*)d_in[11];
  const float* ff2_w  = (const float*)d_in[12];
  const float* ff2_b  = (const float*)d_in[13];
  const float* norm_w = (const float*)d_in[14];
  const float* norm_b = (const float*)d_in[15];
  const float* pool_w = (const float*)d_in[16];
  const float* pool_b = (const float*)d_in[17];
  const float* fc_w   = (const float*)d_in[18];
  const float* fc_b   = (const float*)d_in[19];
  float* out = (float*)d_out;

  // Compact workspace: ~44 MB total (no N x N scores buffer).
  float* ws = (float*)d_ws;
  float* h      = ws;                        // Mm*Dd   = 1,572,864
  float* y      = h + (long)Mm * Dd;         // Mm*Dd
  float* qkvf   = y + (long)Mm * Dd;         // Mm*3*Dd = 4,718,592
  float* o      = qkvf + (long)Mm * 3 * Dd;  // Mm*Dd
  float* hn     = o + (long)Mm * Dd;         // Mm*Dd
  float* spool  = hn + (long)Mm * Dd;        // Mm
  float* wpool  = spool + Mm;                // Mm
  float* pooled = wpool + Mm;                // Bb*Dd
  int*   mflag  = (int*)(pooled + Bb * Dd);
  float* po = y;      // alias: y dead after qkv gemm
  float* g  = qkvf;   // alias: ff1 out (Mm*FFf = 6,291,456) fits exactly in qkvf+o (dead after proj)

  detect_mask<<<1, 256, 0, stream>>>((const unsigned char*)mask, mflag);
  add_pe_k<<<(Mm * Dd) / 256, 256, 0, stream>>>(x, pe, h);

  dim3 blk(64, 4);

  for (int l = 0; l < NLl; ++l) {
    ln_kernel<<<Mm, 256, 0, stream>>>(h, nullptr, ln0_w + l * Dd, ln0_b + l * Dd, y);

    // qkv: (Mm x 768) @ (768 x 2304) -> qkvf
    gemm_naive<0,0><<<dim3(3 * Dd / 64, Mm / 4, 1), blk, 0, stream>>>(
        y, Dd, 0, 0,
        qkv_w + (long)l * Dd * 3 * Dd, 3 * Dd, 0, 0,
        nullptr, nullptr,
        qkvf, 3 * Dd, 0, 0, Dd, 1.f, 1);

    // fused attention: o = softmax(mask(QK^T/8)) @ V
    flash_attn<<<dim3(Nn / 4, Hh, Bb), 256, 0, stream>>>(qkvf, mask, mflag, o);

    // proj: o @ proj_w + b -> po (=y)
    gemm_naive<0,1><<<dim3(Dd / 64, Mm / 4, 1), blk, 0, stream>>>(
        o, Dd, 0, 0,
        proj_w + (long)l * Dd * Dd, Dd, 0, 0,
        proj_b + l * Dd, nullptr,
        po, Dd, 0, 0, Dd, 1.f, 1);

    ln_kernel<<<Mm, 256, 0, stream>>>(h, po, ln1_w + l * Dd, ln1_b + l * Dd, h);

    // ff1: h @ ff1_w + b -> gelu -> g
    gemm_naive<0,2><<<dim3(FFf / 64, Mm / 4, 1), blk, 0, stream>>>(
        h, Dd, 0, 0,
        ff1_w + (long)l * Dd * FFf, FFf, 0, 0,
        ff1_b + l * FFf, nullptr,
        g, FFf, 0, 0, Dd, 1.f, 1);

    // ff2: g @ ff2_w + b + h -> h
    gemm_naive<0,3><<<dim3(Dd / 64, Mm / 4, 1), blk, 0, stream>>>(
        g, FFf, 0, 0,
        ff2_w + (long)l * FFf * Dd, Dd, 0, 0,
        ff2_b + l * Dd, h,
        h, Dd, 0, 0, FFf, 1.f, 1);
  }

  ln_kernel<<<Mm, 256, 0, stream>>>(h, nullptr, norm_w, norm_b, hn);
  pool_score<<<Mm, 256, 0, stream>>>(hn, pool_w, pool_b, spool);
  pool_softmax<<<Bb, 256, 0, stream>>>(spool, wpool);
  pool_reduce<<<Bb, 256, 0, stream>>>(hn, wpool, pooled);
  fc_kernel<<<Bb, 256, 0, stream>>>(pooled, fc_w, fc_b, out);
}

// Round 6
// 9701.519 us; speedup vs baseline: 4.4089x; 4.4089x over previous
//
#include <hip/hip_runtime.h>
#include <hip/hip_bf16.h>
#include <cfloat>
#include <cmath>

typedef __bf16 bf16x8 __attribute__((ext_vector_type(8)));
typedef float  f32x4  __attribute__((ext_vector_type(4)));

static constexpr int Bb = 2, Nn = 1024, Dd = 768, Hh = 12, HDd = 64, FFf = 3072, NLl = 12, NCc = 1000;
static constexpr int Mm = Bb * Nn; // 2048
static constexpr float NEGF = -3.402823466e38f;

// ---------- reductions (256-thread blocks = 4 waves) ----------
__device__ __forceinline__ float block_reduce_sum(float v, volatile float* smem) {
  for (int o = 32; o; o >>= 1) v += __shfl_down(v, o);
  int lane = threadIdx.x & 63, w = threadIdx.x >> 6;
  __syncthreads();
  if (lane == 0) smem[w] = v;
  __syncthreads();
  return smem[0] + smem[1] + smem[2] + smem[3];
}

__device__ __forceinline__ float block_reduce_max(float v, volatile float* smem) {
  for (int o = 32; o; o >>= 1) v = fmaxf(v, __shfl_down(v, o));
  int lane = threadIdx.x & 63, w = threadIdx.x >> 6;
  __syncthreads();
  if (lane == 0) smem[w] = v;
  __syncthreads();
  return fmaxf(fmaxf(smem[0], smem[1]), fmaxf(smem[2], smem[3]));
}

// ---------- mask dtype detection: 0=int32 1=bytes 2=f32 3=int64 4=bf16 ----------
__global__ void detect_mask(const unsigned char* __restrict__ m, int* __restrict__ flag) {
  __shared__ int s_nz1, s_nz2, s_nz3, s_nz84, s_pv;
  int tid = threadIdx.x;
  if (tid == 0) { s_nz1 = 0; s_nz2 = 0; s_nz3 = 0; s_nz84 = 0; s_pv = 0; }
  __syncthreads();
  int nz1 = 0, nz2 = 0, nz3 = 0, nz84 = 0, pv = 0;
  for (int i = tid; i < 2048; i += 256) {
    unsigned char v = m[i];
    if (v) {
      int p4 = i & 3;
      if (p4 == 1) nz1 = 1;
      if (p4 == 2) nz2 = 1;
      if (p4 == 3) nz3 = 1;
      if ((i & 7) == 4) nz84 = 1;
      if ((i & 1) == 0) { if (v != 0x80) pv = 1; }
      else              { if (v != 0x3f) pv = 1; }
    }
  }
  if (nz1)  atomicOr(&s_nz1, 1);
  if (nz2)  atomicOr(&s_nz2, 1);
  if (nz3)  atomicOr(&s_nz3, 1);
  if (nz84) atomicOr(&s_nz84, 1);
  if (pv)   atomicOr(&s_pv, 1);
  __syncthreads();
  if (tid == 0) {
    int f;
    if (!s_nz1 && !s_nz2 && !s_nz3) f = s_nz84 ? 0 : 3;
    else if (!s_pv)                 f = s_nz1 ? 4 : 2;
    else                            f = 1;
    *flag = f;
  }
}

__device__ __forceinline__ bool mask_at(const void* mraw, int flag, int idx) {
  switch (flag) {
    case 0:  return ((const int*)mraw)[idx] != 0;
    case 1:  return ((const unsigned char*)mraw)[idx] != 0;
    case 2:  return ((const float*)mraw)[idx] != 0.f;
    case 3:  return ((const long long*)mraw)[idx] != 0;
    default: return ((const unsigned short*)mraw)[idx] != 0;
  }
}

// ---------- h = x + pe (pe broadcast over batch) ----------
__global__ __launch_bounds__(256) void add_pe_k(const float* __restrict__ x, const float* __restrict__ pe,
                                                float* __restrict__ h) {
  long i = (long)blockIdx.x * 256 + threadIdx.x;
  long nd = i % ((long)Nn * Dd);
  h[i] = x[i] + pe[nd];
}

// ---------- LayerNorm (optionally with residual input added first), row = 768 ----------
__global__ __launch_bounds__(256) void ln_kernel(const float* __restrict__ X, const float* __restrict__ R,
                                                 const float* __restrict__ w, const float* __restrict__ b,
                                                 float* __restrict__ Y) {
  __shared__ float smem[4];
  int row = blockIdx.x, tid = threadIdx.x;
  const float* x = X + (size_t)row * Dd;
  const bool hasR = (R != nullptr);
  const float* r = hasR ? R + (size_t)row * Dd : nullptr;
  float v[3];
  for (int j = 0; j < 3; ++j) {
    int c = tid + j * 256;
    v[j] = x[c] + (hasR ? r[c] : 0.f);
  }
  float s = v[0] + v[1] + v[2];
  s = block_reduce_sum(s, smem);
  float mean = s * (1.f / 768.f);
  float q = 0.f;
  for (int j = 0; j < 3; ++j) { float d = v[j] - mean; q += d * d; }
  q = block_reduce_sum(q, smem);
  float inv = rsqrtf(q * (1.f / 768.f) + 1e-5f);
  for (int j = 0; j < 3; ++j) {
    int c = tid + j * 256;
    Y[(size_t)row * Dd + c] = (v[j] - mean) * inv * w[c] + b[c];
  }
}

// ---------- split helpers: f32 -> bf16 hi + bf16 lo ----------
__device__ __forceinline__ void split8(const float* __restrict__ a, bf16x8& hi, bf16x8& lo) {
  float4 f0 = *reinterpret_cast<const float4*>(a);
  float4 f1 = *reinterpret_cast<const float4*>(a + 4);
  float v[8] = {f0.x, f0.y, f0.z, f0.w, f1.x, f1.y, f1.z, f1.w};
  for (int j = 0; j < 8; ++j) {
    __bf16 h = (__bf16)v[j];
    hi[j] = h;
    lo[j] = (__bf16)(v[j] - (float)h);
  }
}

// ---------- 64x64 split-precision MFMA GEMM (f32 in/out, ~18-bit effective inputs) ----------
// C = A*B (+bias/gelu/resid per EPI). B is row-major K x N (transpose-staged to LDS).
// EPI: 0 none, 1 +bias, 2 +bias->exact gelu, 3 +bias +resid.
// grid: (Nsz/64, Msz/64), block 256 (4 waves, 2x2 wave grid of 32x32 tiles).
template<int EPI>
__global__ __launch_bounds__(256) void gemm64s(
    const float* __restrict__ Ap, long lda,
    const float* __restrict__ Bp, long ldb,
    const float* __restrict__ bias, const float* __restrict__ resid,
    float* __restrict__ Cp, long ldc,
    int Ksize)
{
  int tid = threadIdx.x;
  int m0 = blockIdx.y * 64, n0 = blockIdx.x * 64;

  __shared__ __align__(16) __bf16 Ah[64][40];
  __shared__ __align__(16) __bf16 Al[64][40];
  __shared__ __align__(16) __bf16 Bh[64][40];
  __shared__ __align__(16) __bf16 Bl[64][40];

  f32x4 acc[2][2];
  for (int i = 0; i < 2; ++i)
    for (int j = 0; j < 2; ++j)
      for (int k = 0; k < 4; ++k) acc[i][j][k] = 0.f;

  int lane = tid & 63;
  int wv = tid >> 6;
  int wr = (wv >> 1) * 32, wc = (wv & 1) * 32;
  int fr = lane & 15, kg = lane >> 4;

  const int ar = tid >> 2, acs = (tid & 3) * 8;   // A stage: 64 rows x (4 thr x 8)
  const int bkr = tid >> 3, bns = (tid & 7) * 8;  // B stage: 32 k-rows x (8 thr x 8)

  for (int k0 = 0; k0 < Ksize; k0 += 32) {
    { // stage A -> Ah/Al[r][k]
      bf16x8 th, tl;
      split8(Ap + (long)(m0 + ar) * lda + (k0 + acs), th, tl);
      *reinterpret_cast<bf16x8*>(&Ah[ar][acs]) = th;
      *reinterpret_cast<bf16x8*>(&Al[ar][acs]) = tl;
    }
    { // stage B (K x N) -> Bh/Bl[n][k] transposed
      const float* a = Bp + (long)(k0 + bkr) * ldb + (n0 + bns);
      float4 f0 = *reinterpret_cast<const float4*>(a);
      float4 f1 = *reinterpret_cast<const float4*>(a + 4);
      float v[8] = {f0.x, f0.y, f0.z, f0.w, f1.x, f1.y, f1.z, f1.w};
      for (int j = 0; j < 8; ++j) {
        __bf16 h = (__bf16)v[j];
        Bh[bns + j][bkr] = h;
        Bl[bns + j][bkr] = (__bf16)(v[j] - (float)h);
      }
    }
    __syncthreads();

    bf16x8 a0h = *reinterpret_cast<const bf16x8*>(&Ah[wr + fr][kg * 8]);
    bf16x8 a1h = *reinterpret_cast<const bf16x8*>(&Ah[wr + 16 + fr][kg * 8]);
    bf16x8 a0l = *reinterpret_cast<const bf16x8*>(&Al[wr + fr][kg * 8]);
    bf16x8 a1l = *reinterpret_cast<const bf16x8*>(&Al[wr + 16 + fr][kg * 8]);
    bf16x8 b0h = *reinterpret_cast<const bf16x8*>(&Bh[wc + fr][kg * 8]);
    bf16x8 b1h = *reinterpret_cast<const bf16x8*>(&Bh[wc + 16 + fr][kg * 8]);
    bf16x8 b0l = *reinterpret_cast<const bf16x8*>(&Bl[wc + fr][kg * 8]);
    bf16x8 b1l = *reinterpret_cast<const bf16x8*>(&Bl[wc + 16 + fr][kg * 8]);

    acc[0][0] = __builtin_amdgcn_mfma_f32_16x16x32_bf16(a0h, b0h, acc[0][0], 0, 0, 0);
    acc[0][0] = __builtin_amdgcn_mfma_f32_16x16x32_bf16(a0l, b0h, acc[0][0], 0, 0, 0);
    acc[0][0] = __builtin_amdgcn_mfma_f32_16x16x32_bf16(a0h, b0l, acc[0][0], 0, 0, 0);
    acc[0][1] = __builtin_amdgcn_mfma_f32_16x16x32_bf16(a0h, b1h, acc[0][1], 0, 0, 0);
    acc[0][1] = __builtin_amdgcn_mfma_f32_16x16x32_bf16(a0l, b1h, acc[0][1], 0, 0, 0);
    acc[0][1] = __builtin_amdgcn_mfma_f32_16x16x32_bf16(a0h, b1l, acc[0][1], 0, 0, 0);
    acc[1][0] = __builtin_amdgcn_mfma_f32_16x16x32_bf16(a1h, b0h, acc[1][0], 0, 0, 0);
    acc[1][0] = __builtin_amdgcn_mfma_f32_16x16x32_bf16(a1l, b0h, acc[1][0], 0, 0, 0);
    acc[1][0] = __builtin_amdgcn_mfma_f32_16x16x32_bf16(a1h, b0l, acc[1][0], 0, 0, 0);
    acc[1][1] = __builtin_amdgcn_mfma_f32_16x16x32_bf16(a1h, b1h, acc[1][1], 0, 0, 0);
    acc[1][1] = __builtin_amdgcn_mfma_f32_16x16x32_bf16(a1l, b1h, acc[1][1], 0, 0, 0);
    acc[1][1] = __builtin_amdgcn_mfma_f32_16x16x32_bf16(a1h, b1l, acc[1][1], 0, 0, 0);
    __syncthreads();
  }

  for (int fm = 0; fm < 2; ++fm)
    for (int fn = 0; fn < 2; ++fn)
      for (int i = 0; i < 4; ++i) {
        int rowg = m0 + wr + fm * 16 + kg * 4 + i;
        int coln = n0 + wc + fn * 16 + fr;
        float v = acc[fm][fn][i];
        if (EPI >= 1) v += bias[coln];
        if (EPI == 2) v = 0.5f * v * (1.f + erff(v * 0.70710678118654752f));
        if (EPI == 3) v += resid[(long)rowg * ldc + coln];
        Cp[(long)rowg * ldc + coln] = v;
      }
}

// ---------- flash attention: streaming masked softmax(QK^T/8) @ V, no scores buffer ----------
__global__ __launch_bounds__(256) void flash_attn(const float* __restrict__ qkvf,
                                                  const void* __restrict__ mraw,
                                                  const int* __restrict__ flagp,
                                                  float* __restrict__ o) {
  __shared__ float Kt[64][65];
  __shared__ float Vt[64][65];
  __shared__ float qs[4][64];
  __shared__ float ps[4][64];
  int b = blockIdx.z, hh = blockIdx.y;
  int tid = threadIdx.x, lane = tid & 63, w = tid >> 6;
  int qrow = blockIdx.x * 4 + w;
  int flag = *flagp;

  const long qbase = ((long)(b * Nn + qrow)) * (3 * Dd) + hh * HDd;
  qs[w][lane] = qkvf[qbase + lane];
  bool mi = mask_at(mraw, flag, b * Nn + qrow);

  float m = -INFINITY, l = 0.f, accd = 0.f;

  const int sr = tid >> 2;
  const int sc = (tid & 3) * 16;

  for (int j0 = 0; j0 < Nn; j0 += 64) {
    __syncthreads();
    {
      const float* Ksrc = qkvf + ((long)(b * Nn + j0 + sr)) * (3 * Dd) + Dd + hh * HDd + sc;
      const float* Vsrc = Ksrc + Dd;
      #pragma unroll
      for (int j = 0; j < 16; ++j) {
        Kt[sr][sc + j] = Ksrc[j];
        Vt[sr][sc + j] = Vsrc[j];
      }
    }
    __syncthreads();

    float s = 0.f;
    #pragma unroll 8
    for (int d = 0; d < 64; ++d) s = fmaf(qs[w][d], Kt[lane][d], s);
    s *= 0.125f;
    bool mj = mask_at(mraw, flag, b * Nn + j0 + lane);
    if (!(mi && mj)) s = NEGF;

    float mt = s;
    for (int off = 32; off; off >>= 1) mt = fmaxf(mt, __shfl_xor(mt, off));
    float mn = fmaxf(m, mt);
    float r = expf(m - mn);
    float p = expf(s - mn);
    ps[w][lane] = p;
    float ls = p;
    for (int off = 32; off; off >>= 1) ls += __shfl_xor(ls, off);
    l = l * r + ls;

    float av = 0.f;
    #pragma unroll 8
    for (int j = 0; j < 64; ++j) av = fmaf(ps[w][j], Vt[j][lane], av);
    accd = accd * r + av;
    m = mn;
  }
  o[((long)(b * Nn + qrow)) * Dd + hh * HDd + lane] = accd / l;
}

// ---------- seq-pool ----------
__global__ __launch_bounds__(256) void pool_score(const float* __restrict__ hn, const float* __restrict__ pw,
                                                  const float* __restrict__ pb, float* __restrict__ s) {
  __shared__ float smem[4];
  int row = blockIdx.x, tid = threadIdx.x;
  const float* x = hn + (size_t)row * Dd;
  float acc = 0.f;
  for (int j = 0; j < 3; ++j) { int c = tid + j * 256; acc += x[c] * pw[c]; }
  acc = block_reduce_sum(acc, smem);
  if (tid == 0) s[row] = acc + pb[0];
}

__global__ __launch_bounds__(256) void pool_softmax(const float* __restrict__ s, float* __restrict__ w) {
  __shared__ float smem[4];
  int b = blockIdx.x, tid = threadIdx.x;
  const float* x = s + b * Nn;
  float v[4];
  for (int j = 0; j < 4; ++j) v[j] = x[tid * 4 + j];
  float mx = fmaxf(fmaxf(v[0], v[1]), fmaxf(v[2], v[3]));
  mx = block_reduce_max(mx, smem);
  float e[4], sum = 0.f;
  for (int j = 0; j < 4; ++j) { e[j] = expf(v[j] - mx); sum += e[j]; }
  sum = block_reduce_sum(sum, smem);
  float inv = 1.f / sum;
  for (int j = 0; j < 4; ++j) w[b * Nn + tid * 4 + j] = e[j] * inv;
}

__global__ __launch_bounds__(256) void pool_reduce(const float* __restrict__ hn, const float* __restrict__ w,
                                                   float* __restrict__ pooled) {
  int b = blockIdx.x, tid = threadIdx.x;
  float acc[3] = {0.f, 0.f, 0.f};
  for (int n = 0; n < Nn; ++n) {
    float wn = w[b * Nn + n];
    const float* hr = hn + ((size_t)(b * Nn + n)) * Dd;
    for (int j = 0; j < 3; ++j) acc[j] += wn * hr[tid + j * 256];
  }
  for (int j = 0; j < 3; ++j) pooled[b * Dd + tid + j * 256] = acc[j];
}

__global__ __launch_bounds__(256) void fc_kernel(const float* __restrict__ pooled, const float* __restrict__ fw,
                                                 const float* __restrict__ fb, float* __restrict__ out) {
  __shared__ float p[768];
  int b = blockIdx.x, tid = threadIdx.x;
  for (int j = 0; j < 3; ++j) p[tid + j * 256] = pooled[b * Dd + tid + j * 256];
  __syncthreads();
  for (int c = tid; c < NCc; c += 256) {
    float acc = fb[c];
    for (int d = 0; d < Dd; ++d) acc += p[d] * fw[(size_t)d * NCc + c];
    out[b * NCc + c] = acc;
  }
}

extern "C" void kernel_launch(void* const* d_in, const int* in_sizes, int n_in,
                              void* d_out, int out_size, void* d_ws, size_t ws_size,
                              hipStream_t stream) {
  const float* x      = (const float*)d_in[0];
  const void*  mask   = d_in[1];
  const float* pe     = (const float*)d_in[2];
  const float* ln0_w  = (const float*)d_in[3];
  const float* ln0_b  = (const float*)d_in[4];
  const float* qkv_w  = (const float*)d_in[5];
  const float* proj_w = (const float*)d_in[6];
  const float* proj_b = (const float*)d_in[7];
  const float* ln1_w  = (const float*)d_in[8];
  const float* ln1_b  = (const float*)d_in[9];
  const float* ff1_w  = (const float*)d_in[10];
  const float* ff1_b  = (const float*)d_in[11];
  const float* ff2_w  = (const float*)d_in[12];
  const float* ff2_b  = (const float*)d_in[13];
  const float* norm_w = (const float*)d_in[14];
  const float* norm_b = (const float*)d_in[15];
  const float* pool_w = (const float*)d_in[16];
  const float* pool_b = (const float*)d_in[17];
  const float* fc_w   = (const float*)d_in[18];
  const float* fc_b   = (const float*)d_in[19];
  float* out = (float*)d_out;

  // Compact workspace (~44 MB) — verified in round 5. Do NOT grow past this.
  float* ws = (float*)d_ws;
  float* h      = ws;                        // Mm*Dd
  float* y      = h + (long)Mm * Dd;         // Mm*Dd
  float* qkvf   = y + (long)Mm * Dd;         // Mm*3*Dd
  float* o      = qkvf + (long)Mm * 3 * Dd;  // Mm*Dd
  float* hn     = o + (long)Mm * Dd;         // Mm*Dd
  float* spool  = hn + (long)Mm * Dd;        // Mm
  float* wpool  = spool + Mm;                // Mm
  float* pooled = wpool + Mm;                // Bb*Dd
  int*   mflag  = (int*)(pooled + Bb * Dd);
  float* po = y;      // alias: y dead after qkv gemm
  float* g  = qkvf;   // alias: ff1 out fits exactly in qkvf+o (dead after proj)

  detect_mask<<<1, 256, 0, stream>>>((const unsigned char*)mask, mflag);
  add_pe_k<<<(Mm * Dd) / 256, 256, 0, stream>>>(x, pe, h);

  for (int l = 0; l < NLl; ++l) {
    ln_kernel<<<Mm, 256, 0, stream>>>(h, nullptr, ln0_w + l * Dd, ln0_b + l * Dd, y);

    // qkv: (Mm x 768) @ (768 x 2304) -> qkvf
    gemm64s<0><<<dim3(3 * Dd / 64, Mm / 64), 256, 0, stream>>>(
        y, Dd,
        qkv_w + (long)l * Dd * 3 * Dd, 3 * Dd,
        nullptr, nullptr,
        qkvf, 3 * Dd, Dd);

    // fused attention: o = softmax(mask(QK^T/8)) @ V
    flash_attn<<<dim3(Nn / 4, Hh, Bb), 256, 0, stream>>>(qkvf, mask, mflag, o);

    // proj: o @ proj_w + b -> po (=y)
    gemm64s<1><<<dim3(Dd / 64, Mm / 64), 256, 0, stream>>>(
        o, Dd,
        proj_w + (long)l * Dd * Dd, Dd,
        proj_b + l * Dd, nullptr,
        po, Dd, Dd);

    ln_kernel<<<Mm, 256, 0, stream>>>(h, po, ln1_w + l * Dd, ln1_b + l * Dd, h);

    // ff1: h @ ff1_w + b -> gelu -> g
    gemm64s<2><<<dim3(FFf / 64, Mm / 64), 256, 0, stream>>>(
        h, Dd,
        ff1_w + (long)l * Dd * FFf, FFf,
        ff1_b + l * FFf, nullptr,
        g, FFf, Dd);

    // ff2: g @ ff2_w + b + h -> h
    gemm64s<3><<<dim3(Dd / 64, Mm / 64), 256, 0, stream>>>(
        g, FFf,
        ff2_w + (long)l * FFf * Dd, Dd,
        ff2_b + l * Dd, h,
        h, Dd, FFf);
  }

  ln_kernel<<<Mm, 256, 0, stream>>>(h, nullptr, norm_w, norm_b, hn);
  pool_score<<<Mm, 256, 0, stream>>>(hn, pool_w, pool_b, spool);
  pool_softmax<<<Bb, 256, 0, stream>>>(spool, wpool);
  pool_reduce<<<Bb, 256, 0, stream>>>(hn, wpool, pooled);
  fc_kernel<<<Bb, 256, 0, stream>>>(pooled, fc_w, fc_b, out);
}

// Round 7
// 5681.164 us; speedup vs baseline: 7.5289x; 1.7077x over previous
//
#include <hip/hip_runtime.h>
#include <hip/hip_bf16.h>
#include <cfloat>
#include <cmath>

typedef __bf16 bf16x8 __attribute__((ext_vector_type(8)));
typedef float  f32x4  __attribute__((ext_vector_type(4)));

static constexpr int Bb = 2, Nn = 1024, Dd = 768, Hh = 12, HDd = 64, FFf = 3072, NLl = 12, NCc = 1000;
static constexpr int Mm = Bb * Nn; // 2048
static constexpr float NEGF = -3.402823466e38f;

// ---------- reductions (256-thread blocks = 4 waves) ----------
__device__ __forceinline__ float block_reduce_sum(float v, volatile float* smem) {
  for (int o = 32; o; o >>= 1) v += __shfl_down(v, o);
  int lane = threadIdx.x & 63, w = threadIdx.x >> 6;
  __syncthreads();
  if (lane == 0) smem[w] = v;
  __syncthreads();
  return smem[0] + smem[1] + smem[2] + smem[3];
}

__device__ __forceinline__ float block_reduce_max(float v, volatile float* smem) {
  for (int o = 32; o; o >>= 1) v = fmaxf(v, __shfl_down(v, o));
  int lane = threadIdx.x & 63, w = threadIdx.x >> 6;
  __syncthreads();
  if (lane == 0) smem[w] = v;
  __syncthreads();
  return fmaxf(fmaxf(smem[0], smem[1]), fmaxf(smem[2], smem[3]));
}

// ---------- mask dtype detection: 0=int32 1=bytes 2=f32 3=int64 4=bf16 ----------
__global__ void detect_mask(const unsigned char* __restrict__ m, int* __restrict__ flag) {
  __shared__ int s_nz1, s_nz2, s_nz3, s_nz84, s_pv;
  int tid = threadIdx.x;
  if (tid == 0) { s_nz1 = 0; s_nz2 = 0; s_nz3 = 0; s_nz84 = 0; s_pv = 0; }
  __syncthreads();
  int nz1 = 0, nz2 = 0, nz3 = 0, nz84 = 0, pv = 0;
  for (int i = tid; i < 2048; i += 256) {
    unsigned char v = m[i];
    if (v) {
      int p4 = i & 3;
      if (p4 == 1) nz1 = 1;
      if (p4 == 2) nz2 = 1;
      if (p4 == 3) nz3 = 1;
      if ((i & 7) == 4) nz84 = 1;
      if ((i & 1) == 0) { if (v != 0x80) pv = 1; }
      else              { if (v != 0x3f) pv = 1; }
    }
  }
  if (nz1)  atomicOr(&s_nz1, 1);
  if (nz2)  atomicOr(&s_nz2, 1);
  if (nz3)  atomicOr(&s_nz3, 1);
  if (nz84) atomicOr(&s_nz84, 1);
  if (pv)   atomicOr(&s_pv, 1);
  __syncthreads();
  if (tid == 0) {
    int f;
    if (!s_nz1 && !s_nz2 && !s_nz3) f = s_nz84 ? 0 : 3;
    else if (!s_pv)                 f = s_nz1 ? 4 : 2;
    else                            f = 1;
    *flag = f;
  }
}

__device__ __forceinline__ bool mask_at(const void* mraw, int flag, int idx) {
  switch (flag) {
    case 0:  return ((const int*)mraw)[idx] != 0;
    case 1:  return ((const unsigned char*)mraw)[idx] != 0;
    case 2:  return ((const float*)mraw)[idx] != 0.f;
    case 3:  return ((const long long*)mraw)[idx] != 0;
    default: return ((const unsigned short*)mraw)[idx] != 0;
  }
}

// ---------- h = x + pe (pe broadcast over batch) ----------
__global__ __launch_bounds__(256) void add_pe_k(const float* __restrict__ x, const float* __restrict__ pe,
                                                float* __restrict__ h) {
  long i = (long)blockIdx.x * 256 + threadIdx.x;
  long nd = i % ((long)Nn * Dd);
  h[i] = x[i] + pe[nd];
}

// ---------- LayerNorm (optionally with residual input added first), row = 768 ----------
__global__ __launch_bounds__(256) void ln_kernel(const float* __restrict__ X, const float* __restrict__ R,
                                                 const float* __restrict__ w, const float* __restrict__ b,
                                                 float* __restrict__ Y) {
  __shared__ float smem[4];
  int row = blockIdx.x, tid = threadIdx.x;
  const float* x = X + (size_t)row * Dd;
  const bool hasR = (R != nullptr);
  const float* r = hasR ? R + (size_t)row * Dd : nullptr;
  float v[3];
  for (int j = 0; j < 3; ++j) {
    int c = tid + j * 256;
    v[j] = x[c] + (hasR ? r[c] : 0.f);
  }
  float s = v[0] + v[1] + v[2];
  s = block_reduce_sum(s, smem);
  float mean = s * (1.f / 768.f);
  float q = 0.f;
  for (int j = 0; j < 3; ++j) { float d = v[j] - mean; q += d * d; }
  q = block_reduce_sum(q, smem);
  float inv = rsqrtf(q * (1.f / 768.f) + 1e-5f);
  for (int j = 0; j < 3; ++j) {
    int c = tid + j * 256;
    Y[(size_t)row * Dd + c] = (v[j] - mean) * inv * w[c] + b[c];
  }
}

// ---------- split helpers: f32 -> bf16 hi + bf16 lo ----------
__device__ __forceinline__ void split8(const float* __restrict__ a, bf16x8& hi, bf16x8& lo) {
  float4 f0 = *reinterpret_cast<const float4*>(a);
  float4 f1 = *reinterpret_cast<const float4*>(a + 4);
  float v[8] = {f0.x, f0.y, f0.z, f0.w, f1.x, f1.y, f1.z, f1.w};
  for (int j = 0; j < 8; ++j) {
    __bf16 h = (__bf16)v[j];
    hi[j] = h;
    lo[j] = (__bf16)(v[j] - (float)h);
  }
}

// ---------- 64x64 split-precision MFMA GEMM (f32 in/out, ~18-bit effective inputs) ----------
template<int EPI>
__global__ __launch_bounds__(256) void gemm64s(
    const float* __restrict__ Ap, long lda,
    const float* __restrict__ Bp, long ldb,
    const float* __restrict__ bias, const float* __restrict__ resid,
    float* __restrict__ Cp, long ldc,
    int Ksize)
{
  int tid = threadIdx.x;
  int m0 = blockIdx.y * 64, n0 = blockIdx.x * 64;

  __shared__ __align__(16) __bf16 Ah[64][40];
  __shared__ __align__(16) __bf16 Al[64][40];
  __shared__ __align__(16) __bf16 Bh[64][40];
  __shared__ __align__(16) __bf16 Bl[64][40];

  f32x4 acc[2][2];
  for (int i = 0; i < 2; ++i)
    for (int j = 0; j < 2; ++j)
      for (int k = 0; k < 4; ++k) acc[i][j][k] = 0.f;

  int lane = tid & 63;
  int wv = tid >> 6;
  int wr = (wv >> 1) * 32, wc = (wv & 1) * 32;
  int fr = lane & 15, kg = lane >> 4;

  const int ar = tid >> 2, acs = (tid & 3) * 8;
  const int bkr = tid >> 3, bns = (tid & 7) * 8;

  for (int k0 = 0; k0 < Ksize; k0 += 32) {
    {
      bf16x8 th, tl;
      split8(Ap + (long)(m0 + ar) * lda + (k0 + acs), th, tl);
      *reinterpret_cast<bf16x8*>(&Ah[ar][acs]) = th;
      *reinterpret_cast<bf16x8*>(&Al[ar][acs]) = tl;
    }
    {
      const float* a = Bp + (long)(k0 + bkr) * ldb + (n0 + bns);
      float4 f0 = *reinterpret_cast<const float4*>(a);
      float4 f1 = *reinterpret_cast<const float4*>(a + 4);
      float v[8] = {f0.x, f0.y, f0.z, f0.w, f1.x, f1.y, f1.z, f1.w};
      for (int j = 0; j < 8; ++j) {
        __bf16 h = (__bf16)v[j];
        Bh[bns + j][bkr] = h;
        Bl[bns + j][bkr] = (__bf16)(v[j] - (float)h);
      }
    }
    __syncthreads();

    bf16x8 a0h = *reinterpret_cast<const bf16x8*>(&Ah[wr + fr][kg * 8]);
    bf16x8 a1h = *reinterpret_cast<const bf16x8*>(&Ah[wr + 16 + fr][kg * 8]);
    bf16x8 a0l = *reinterpret_cast<const bf16x8*>(&Al[wr + fr][kg * 8]);
    bf16x8 a1l = *reinterpret_cast<const bf16x8*>(&Al[wr + 16 + fr][kg * 8]);
    bf16x8 b0h = *reinterpret_cast<const bf16x8*>(&Bh[wc + fr][kg * 8]);
    bf16x8 b1h = *reinterpret_cast<const bf16x8*>(&Bh[wc + 16 + fr][kg * 8]);
    bf16x8 b0l = *reinterpret_cast<const bf16x8*>(&Bl[wc + fr][kg * 8]);
    bf16x8 b1l = *reinterpret_cast<const bf16x8*>(&Bl[wc + 16 + fr][kg * 8]);

    acc[0][0] = __builtin_amdgcn_mfma_f32_16x16x32_bf16(a0h, b0h, acc[0][0], 0, 0, 0);
    acc[0][0] = __builtin_amdgcn_mfma_f32_16x16x32_bf16(a0l, b0h, acc[0][0], 0, 0, 0);
    acc[0][0] = __builtin_amdgcn_mfma_f32_16x16x32_bf16(a0h, b0l, acc[0][0], 0, 0, 0);
    acc[0][1] = __builtin_amdgcn_mfma_f32_16x16x32_bf16(a0h, b1h, acc[0][1], 0, 0, 0);
    acc[0][1] = __builtin_amdgcn_mfma_f32_16x16x32_bf16(a0l, b1h, acc[0][1], 0, 0, 0);
    acc[0][1] = __builtin_amdgcn_mfma_f32_16x16x32_bf16(a0h, b1l, acc[0][1], 0, 0, 0);
    acc[1][0] = __builtin_amdgcn_mfma_f32_16x16x32_bf16(a1h, b0h, acc[1][0], 0, 0, 0);
    acc[1][0] = __builtin_amdgcn_mfma_f32_16x16x32_bf16(a1l, b0h, acc[1][0], 0, 0, 0);
    acc[1][0] = __builtin_amdgcn_mfma_f32_16x16x32_bf16(a1h, b0l, acc[1][0], 0, 0, 0);
    acc[1][1] = __builtin_amdgcn_mfma_f32_16x16x32_bf16(a1h, b1h, acc[1][1], 0, 0, 0);
    acc[1][1] = __builtin_amdgcn_mfma_f32_16x16x32_bf16(a1l, b1h, acc[1][1], 0, 0, 0);
    acc[1][1] = __builtin_amdgcn_mfma_f32_16x16x32_bf16(a1h, b1l, acc[1][1], 0, 0, 0);
    __syncthreads();
  }

  for (int fm = 0; fm < 2; ++fm)
    for (int fn = 0; fn < 2; ++fn)
      for (int i = 0; i < 4; ++i) {
        int rowg = m0 + wr + fm * 16 + kg * 4 + i;
        int coln = n0 + wc + fn * 16 + fr;
        float v = acc[fm][fn][i];
        if (EPI >= 1) v += bias[coln];
        if (EPI == 2) v = 0.5f * v * (1.f + erff(v * 0.70710678118654752f));
        if (EPI == 3) v += resid[(long)rowg * ldc + coln];
        Cp[(long)rowg * ldc + coln] = v;
      }
}

// ---------- MFMA flash attention ----------
// grid: (Nn/64, Hh, Bb), block 256 (4 waves; wave w owns Q rows 16w..16w+15 of the 64-row tile).
// Split-precision (hi/lo bf16, 3-MFMA) on both QK^T and PV -> ~f32 accuracy.
// Fragment layouts match gemm64s (HW-verified): A[row=fr][k=kg*8+j], B[col=fr][k], C[row=kg*4+i][col=fr].
__global__ __launch_bounds__(256) void flash_attn_mfma(const float* __restrict__ qkvf,
                                                       const void* __restrict__ mraw,
                                                       const int* __restrict__ flagp,
                                                       float* __restrict__ o) {
  __shared__ __align__(16) __bf16 Qh[64][72], Ql[64][72];
  __shared__ __align__(16) __bf16 Kh[64][72], Kl[64][72];
  __shared__ __align__(16) __bf16 Vth[64][66], Vtl[64][66];  // V transposed: [d][key]
  __shared__ __align__(16) __bf16 Ph[64][72], Pl[64][72];
  __shared__ float kmf[64];
  __shared__ float qmf[64];

  int b = blockIdx.z, hh = blockIdx.y;
  int q0 = blockIdx.x * 64;
  int tid = threadIdx.x, lane = tid & 63, w = tid >> 6;
  int flag = *flagp;
  int fr = lane & 15, kg = lane >> 4;

  const int sr = tid >> 2;         // staging row 0..63
  const int sc = (tid & 3) * 16;   // staging col start

  // stage Q tile (split) + query mask
  {
    const float* Qsrc = qkvf + ((long)(b * Nn + q0 + sr)) * (3 * Dd) + hh * HDd + sc;
    bf16x8 th, tl;
    split8(Qsrc, th, tl);
    *reinterpret_cast<bf16x8*>(&Qh[sr][sc]) = th;
    *reinterpret_cast<bf16x8*>(&Ql[sr][sc]) = tl;
    split8(Qsrc + 8, th, tl);
    *reinterpret_cast<bf16x8*>(&Qh[sr][sc + 8]) = th;
    *reinterpret_cast<bf16x8*>(&Ql[sr][sc + 8]) = tl;
    if (tid < 64) qmf[tid] = mask_at(mraw, flag, b * Nn + q0 + tid) ? 1.f : 0.f;
  }
  __syncthreads();

  float qm[4];
  #pragma unroll
  for (int i = 0; i < 4; ++i) qm[i] = qmf[16 * w + kg * 4 + i];

  // Q fragments are loop-invariant: hoist
  bf16x8 qah[2], qal[2];
  #pragma unroll
  for (int ks = 0; ks < 2; ++ks) {
    qah[ks] = *reinterpret_cast<const bf16x8*>(&Qh[16 * w + fr][ks * 32 + kg * 8]);
    qal[ks] = *reinterpret_cast<const bf16x8*>(&Ql[16 * w + fr][ks * 32 + kg * 8]);
  }

  float mrow[4], lrow[4];
  f32x4 accO[4];
  #pragma unroll
  for (int i = 0; i < 4; ++i) { mrow[i] = -INFINITY; lrow[i] = 0.f; }
  #pragma unroll
  for (int t = 0; t < 4; ++t)
    for (int i = 0; i < 4; ++i) accO[t][i] = 0.f;

  for (int j0 = 0; j0 < Nn; j0 += 64) {
    __syncthreads();  // previous tile's PV reads done before overwrite
    {
      const float* Ksrc = qkvf + ((long)(b * Nn + j0 + sr)) * (3 * Dd) + Dd + hh * HDd + sc;
      const float* Vsrc = Ksrc + Dd;
      bf16x8 th, tl;
      split8(Ksrc, th, tl);
      *reinterpret_cast<bf16x8*>(&Kh[sr][sc]) = th;
      *reinterpret_cast<bf16x8*>(&Kl[sr][sc]) = tl;
      split8(Ksrc + 8, th, tl);
      *reinterpret_cast<bf16x8*>(&Kh[sr][sc + 8]) = th;
      *reinterpret_cast<bf16x8*>(&Kl[sr][sc + 8]) = tl;
      #pragma unroll
      for (int j = 0; j < 16; ++j) {
        float vv = Vsrc[j];
        __bf16 vh = (__bf16)vv;
        Vth[sc + j][sr] = vh;
        Vtl[sc + j][sr] = (__bf16)(vv - (float)vh);
      }
      if (tid < 64) kmf[tid] = mask_at(mraw, flag, b * Nn + j0 + tid) ? 1.f : 0.f;
    }
    __syncthreads();

    // S = Q K^T (split 3-MFMA), S[row=kg*4+i][col=16t+fr]
    f32x4 sacc[4];
    #pragma unroll
    for (int t = 0; t < 4; ++t)
      for (int i = 0; i < 4; ++i) sacc[t][i] = 0.f;
    #pragma unroll
    for (int ks = 0; ks < 2; ++ks) {
      #pragma unroll
      for (int t = 0; t < 4; ++t) {
        bf16x8 bh = *reinterpret_cast<const bf16x8*>(&Kh[16 * t + fr][ks * 32 + kg * 8]);
        bf16x8 bl = *reinterpret_cast<const bf16x8*>(&Kl[16 * t + fr][ks * 32 + kg * 8]);
        sacc[t] = __builtin_amdgcn_mfma_f32_16x16x32_bf16(qah[ks], bh, sacc[t], 0, 0, 0);
        sacc[t] = __builtin_amdgcn_mfma_f32_16x16x32_bf16(qal[ks], bh, sacc[t], 0, 0, 0);
        sacc[t] = __builtin_amdgcn_mfma_f32_16x16x32_bf16(qah[ks], bl, sacc[t], 0, 0, 0);
      }
    }

    // scale + mask + row-max
    float sv[4][4];
    float mt[4] = {-INFINITY, -INFINITY, -INFINITY, -INFINITY};
    #pragma unroll
    for (int t = 0; t < 4; ++t) {
      float km = kmf[16 * t + fr];
      #pragma unroll
      for (int i = 0; i < 4; ++i) {
        float s = (km > 0.f && qm[i] > 0.f) ? sacc[t][i] * 0.125f : NEGF;
        sv[t][i] = s;
        mt[i] = fmaxf(mt[i], s);
      }
    }
    #pragma unroll
    for (int off = 8; off; off >>= 1)
      #pragma unroll
      for (int i = 0; i < 4; ++i) mt[i] = fmaxf(mt[i], __shfl_xor(mt[i], off));

    float r[4], psum[4];
    #pragma unroll
    for (int i = 0; i < 4; ++i) {
      float mn = fmaxf(mrow[i], mt[i]);
      r[i] = expf(mrow[i] - mn);
      mrow[i] = mn;
      psum[i] = 0.f;
    }
    // P = exp(S - m), write split P to LDS (row-major [q][key]) for PV A-fragments
    #pragma unroll
    for (int t = 0; t < 4; ++t) {
      #pragma unroll
      for (int i = 0; i < 4; ++i) {
        float p = expf(sv[t][i] - mrow[i]);
        psum[i] += p;
        __bf16 ph = (__bf16)p;
        Ph[16 * w + kg * 4 + i][16 * t + fr] = ph;
        Pl[16 * w + kg * 4 + i][16 * t + fr] = (__bf16)(p - (float)ph);
      }
    }
    #pragma unroll
    for (int off = 8; off; off >>= 1)
      #pragma unroll
      for (int i = 0; i < 4; ++i) psum[i] += __shfl_xor(psum[i], off);
    #pragma unroll
    for (int i = 0; i < 4; ++i) lrow[i] = lrow[i] * r[i] + psum[i];
    #pragma unroll
    for (int t = 0; t < 4; ++t)
      #pragma unroll
      for (int i = 0; i < 4; ++i) accO[t][i] *= r[i];

    __syncthreads();  // P writes visible (safety; also separates phases)

    // O += P V (split 3-MFMA); accO[t2][i] = O[row=kg*4+i][col=16*t2+fr]
    #pragma unroll
    for (int ks = 0; ks < 2; ++ks) {
      bf16x8 pah = *reinterpret_cast<const bf16x8*>(&Ph[16 * w + fr][ks * 32 + kg * 8]);
      bf16x8 pal = *reinterpret_cast<const bf16x8*>(&Pl[16 * w + fr][ks * 32 + kg * 8]);
      #pragma unroll
      for (int t2 = 0; t2 < 4; ++t2) {
        bf16x8 vbh = *reinterpret_cast<const bf16x8*>(&Vth[16 * t2 + fr][ks * 32 + kg * 8]);
        bf16x8 vbl = *reinterpret_cast<const bf16x8*>(&Vtl[16 * t2 + fr][ks * 32 + kg * 8]);
        accO[t2] = __builtin_amdgcn_mfma_f32_16x16x32_bf16(pah, vbh, accO[t2], 0, 0, 0);
        accO[t2] = __builtin_amdgcn_mfma_f32_16x16x32_bf16(pal, vbh, accO[t2], 0, 0, 0);
        accO[t2] = __builtin_amdgcn_mfma_f32_16x16x32_bf16(pah, vbl, accO[t2], 0, 0, 0);
      }
    }
  }

  #pragma unroll
  for (int t2 = 0; t2 < 4; ++t2)
    #pragma unroll
    for (int i = 0; i < 4; ++i) {
      int qrow = q0 + 16 * w + kg * 4 + i;
      int col = 16 * t2 + fr;
      o[((long)(b * Nn + qrow)) * Dd + hh * HDd + col] = accO[t2][i] / lrow[i];
    }
}

// ---------- seq-pool ----------
__global__ __launch_bounds__(256) void pool_score(const float* __restrict__ hn, const float* __restrict__ pw,
                                                  const float* __restrict__ pb, float* __restrict__ s) {
  __shared__ float smem[4];
  int row = blockIdx.x, tid = threadIdx.x;
  const float* x = hn + (size_t)row * Dd;
  float acc = 0.f;
  for (int j = 0; j < 3; ++j) { int c = tid + j * 256; acc += x[c] * pw[c]; }
  acc = block_reduce_sum(acc, smem);
  if (tid == 0) s[row] = acc + pb[0];
}

__global__ __launch_bounds__(256) void pool_softmax(const float* __restrict__ s, float* __restrict__ w) {
  __shared__ float smem[4];
  int b = blockIdx.x, tid = threadIdx.x;
  const float* x = s + b * Nn;
  float v[4];
  for (int j = 0; j < 4; ++j) v[j] = x[tid * 4 + j];
  float mx = fmaxf(fmaxf(v[0], v[1]), fmaxf(v[2], v[3]));
  mx = block_reduce_max(mx, smem);
  float e[4], sum = 0.f;
  for (int j = 0; j < 4; ++j) { e[j] = expf(v[j] - mx); sum += e[j]; }
  sum = block_reduce_sum(sum, smem);
  float inv = 1.f / sum;
  for (int j = 0; j < 4; ++j) w[b * Nn + tid * 4 + j] = e[j] * inv;
}

__global__ __launch_bounds__(256) void pool_reduce(const float* __restrict__ hn, const float* __restrict__ w,
                                                   float* __restrict__ pooled) {
  int b = blockIdx.x, tid = threadIdx.x;
  float acc[3] = {0.f, 0.f, 0.f};
  for (int n = 0; n < Nn; ++n) {
    float wn = w[b * Nn + n];
    const float* hr = hn + ((size_t)(b * Nn + n)) * Dd;
    for (int j = 0; j < 3; ++j) acc[j] += wn * hr[tid + j * 256];
  }
  for (int j = 0; j < 3; ++j) pooled[b * Dd + tid + j * 256] = acc[j];
}

__global__ __launch_bounds__(256) void fc_kernel(const float* __restrict__ pooled, const float* __restrict__ fw,
                                                 const float* __restrict__ fb, float* __restrict__ out) {
  __shared__ float p[768];
  int b = blockIdx.x, tid = threadIdx.x;
  for (int j = 0; j < 3; ++j) p[tid + j * 256] = pooled[b * Dd + tid + j * 256];
  __syncthreads();
  for (int c = tid; c < NCc; c += 256) {
    float acc = fb[c];
    for (int d = 0; d < Dd; ++d) acc += p[d] * fw[(size_t)d * NCc + c];
    out[b * NCc + c] = acc;
  }
}

extern "C" void kernel_launch(void* const* d_in, const int* in_sizes, int n_in,
                              void* d_out, int out_size, void* d_ws, size_t ws_size,
                              hipStream_t stream) {
  const float* x      = (const float*)d_in[0];
  const void*  mask   = d_in[1];
  const float* pe     = (const float*)d_in[2];
  const float* ln0_w  = (const float*)d_in[3];
  const float* ln0_b  = (const float*)d_in[4];
  const float* qkv_w  = (const float*)d_in[5];
  const float* proj_w = (const float*)d_in[6];
  const float* proj_b = (const float*)d_in[7];
  const float* ln1_w  = (const float*)d_in[8];
  const float* ln1_b  = (const float*)d_in[9];
  const float* ff1_w  = (const float*)d_in[10];
  const float* ff1_b  = (const float*)d_in[11];
  const float* ff2_w  = (const float*)d_in[12];
  const float* ff2_b  = (const float*)d_in[13];
  const float* norm_w = (const float*)d_in[14];
  const float* norm_b = (const float*)d_in[15];
  const float* pool_w = (const float*)d_in[16];
  const float* pool_b = (const float*)d_in[17];
  const float* fc_w   = (const float*)d_in[18];
  const float* fc_b   = (const float*)d_in[19];
  float* out = (float*)d_out;

  // Compact workspace (~44 MB) — verified in round 5. Do NOT grow past this.
  float* ws = (float*)d_ws;
  float* h      = ws;                        // Mm*Dd
  float* y      = h + (long)Mm * Dd;         // Mm*Dd
  float* qkvf   = y + (long)Mm * Dd;         // Mm*3*Dd
  float* o      = qkvf + (long)Mm * 3 * Dd;  // Mm*Dd
  float* hn     = o + (long)Mm * Dd;         // Mm*Dd
  float* spool  = hn + (long)Mm * Dd;        // Mm
  float* wpool  = spool + Mm;                // Mm
  float* pooled = wpool + Mm;                // Bb*Dd
  int*   mflag  = (int*)(pooled + Bb * Dd);
  float* po = y;      // alias: y dead after qkv gemm
  float* g  = qkvf;   // alias: ff1 out fits exactly in qkvf+o (dead after proj)

  detect_mask<<<1, 256, 0, stream>>>((const unsigned char*)mask, mflag);
  add_pe_k<<<(Mm * Dd) / 256, 256, 0, stream>>>(x, pe, h);

  for (int l = 0; l < NLl; ++l) {
    ln_kernel<<<Mm, 256, 0, stream>>>(h, nullptr, ln0_w + l * Dd, ln0_b + l * Dd, y);

    // qkv: (Mm x 768) @ (768 x 2304) -> qkvf
    gemm64s<0><<<dim3(3 * Dd / 64, Mm / 64), 256, 0, stream>>>(
        y, Dd,
        qkv_w + (long)l * Dd * 3 * Dd, 3 * Dd,
        nullptr, nullptr,
        qkvf, 3 * Dd, Dd);

    // fused attention: o = softmax(mask(QK^T/8)) @ V   (MFMA flash)
    flash_attn_mfma<<<dim3(Nn / 64, Hh, Bb), 256, 0, stream>>>(qkvf, mask, mflag, o);

    // proj: o @ proj_w + b -> po (=y)
    gemm64s<1><<<dim3(Dd / 64, Mm / 64), 256, 0, stream>>>(
        o, Dd,
        proj_w + (long)l * Dd * Dd, Dd,
        proj_b + l * Dd, nullptr,
        po, Dd, Dd);

    ln_kernel<<<Mm, 256, 0, stream>>>(h, po, ln1_w + l * Dd, ln1_b + l * Dd, h);

    // ff1: h @ ff1_w + b -> gelu -> g
    gemm64s<2><<<dim3(FFf / 64, Mm / 64), 256, 0, stream>>>(
        h, Dd,
        ff1_w + (long)l * Dd * FFf, FFf,
        ff1_b + l * FFf, nullptr,
        g, FFf, Dd);

    // ff2: g @ ff2_w + b + h -> h
    gemm64s<3><<<dim3(Dd / 64, Mm / 64), 256, 0, stream>>>(
        g, FFf,
        ff2_w + (long)l * FFf * Dd, Dd,
        ff2_b + l * Dd, h,
        h, Dd, FFf);
  }

  ln_kernel<<<Mm, 256, 0, stream>>>(h, nullptr, norm_w, norm_b, hn);
  pool_score<<<Mm, 256, 0, stream>>>(hn, pool_w, pool_b, spool);
  pool_softmax<<<Bb, 256, 0, stream>>>(spool, wpool);
  pool_reduce<<<Bb, 256, 0, stream>>>(hn, wpool, pooled);
  fc_kernel<<<Bb, 256, 0, stream>>>(pooled, fc_w, fc_b, out);
}

// Round 8
// 4113.877 us; speedup vs baseline: 10.3972x; 1.3810x over previous
//
#include <hip/hip_runtime.h>
#include <hip/hip_bf16.h>
#include <cfloat>
#include <cmath>

typedef __bf16 bf16x8 __attribute__((ext_vector_type(8)));
typedef float  f32x4  __attribute__((ext_vector_type(4)));

static constexpr int Bb = 2, Nn = 1024, Dd = 768, Hh = 12, HDd = 64, FFf = 3072, NLl = 12, NCc = 1000;
static constexpr int Mm = Bb * Nn; // 2048
static constexpr float NEGF = -3.402823466e38f;

// ---------- reductions (256-thread blocks = 4 waves) ----------
__device__ __forceinline__ float block_reduce_sum(float v, volatile float* smem) {
  for (int o = 32; o; o >>= 1) v += __shfl_down(v, o);
  int lane = threadIdx.x & 63, w = threadIdx.x >> 6;
  __syncthreads();
  if (lane == 0) smem[w] = v;
  __syncthreads();
  return smem[0] + smem[1] + smem[2] + smem[3];
}

__device__ __forceinline__ float block_reduce_max(float v, volatile float* smem) {
  for (int o = 32; o; o >>= 1) v = fmaxf(v, __shfl_down(v, o));
  int lane = threadIdx.x & 63, w = threadIdx.x >> 6;
  __syncthreads();
  if (lane == 0) smem[w] = v;
  __syncthreads();
  return fmaxf(fmaxf(smem[0], smem[1]), fmaxf(smem[2], smem[3]));
}

// ---------- mask dtype detection: 0=int32 1=bytes 2=f32 3=int64 4=bf16 ----------
__global__ void detect_mask(const unsigned char* __restrict__ m, int* __restrict__ flag) {
  __shared__ int s_nz1, s_nz2, s_nz3, s_nz84, s_pv;
  int tid = threadIdx.x;
  if (tid == 0) { s_nz1 = 0; s_nz2 = 0; s_nz3 = 0; s_nz84 = 0; s_pv = 0; }
  __syncthreads();
  int nz1 = 0, nz2 = 0, nz3 = 0, nz84 = 0, pv = 0;
  for (int i = tid; i < 2048; i += 256) {
    unsigned char v = m[i];
    if (v) {
      int p4 = i & 3;
      if (p4 == 1) nz1 = 1;
      if (p4 == 2) nz2 = 1;
      if (p4 == 3) nz3 = 1;
      if ((i & 7) == 4) nz84 = 1;
      if ((i & 1) == 0) { if (v != 0x80) pv = 1; }
      else              { if (v != 0x3f) pv = 1; }
    }
  }
  if (nz1)  atomicOr(&s_nz1, 1);
  if (nz2)  atomicOr(&s_nz2, 1);
  if (nz3)  atomicOr(&s_nz3, 1);
  if (nz84) atomicOr(&s_nz84, 1);
  if (pv)   atomicOr(&s_pv, 1);
  __syncthreads();
  if (tid == 0) {
    int f;
    if (!s_nz1 && !s_nz2 && !s_nz3) f = s_nz84 ? 0 : 3;
    else if (!s_pv)                 f = s_nz1 ? 4 : 2;
    else                            f = 1;
    *flag = f;
  }
}

__device__ __forceinline__ bool mask_at(const void* mraw, int flag, int idx) {
  switch (flag) {
    case 0:  return ((const int*)mraw)[idx] != 0;
    case 1:  return ((const unsigned char*)mraw)[idx] != 0;
    case 2:  return ((const float*)mraw)[idx] != 0.f;
    case 3:  return ((const long long*)mraw)[idx] != 0;
    default: return ((const unsigned short*)mraw)[idx] != 0;
  }
}

// ---------- h = x + pe (pe broadcast over batch) ----------
__global__ __launch_bounds__(256) void add_pe_k(const float* __restrict__ x, const float* __restrict__ pe,
                                                float* __restrict__ h) {
  long i = (long)blockIdx.x * 256 + threadIdx.x;
  long nd = i % ((long)Nn * Dd);
  h[i] = x[i] + pe[nd];
}

// ---------- LayerNorm (optionally with residual input added first), row = 768 ----------
__global__ __launch_bounds__(256) void ln_kernel(const float* __restrict__ X, const float* __restrict__ R,
                                                 const float* __restrict__ w, const float* __restrict__ b,
                                                 float* __restrict__ Y) {
  __shared__ float smem[4];
  int row = blockIdx.x, tid = threadIdx.x;
  const float* x = X + (size_t)row * Dd;
  const bool hasR = (R != nullptr);
  const float* r = hasR ? R + (size_t)row * Dd : nullptr;
  float v[3];
  for (int j = 0; j < 3; ++j) {
    int c = tid + j * 256;
    v[j] = x[c] + (hasR ? r[c] : 0.f);
  }
  float s = v[0] + v[1] + v[2];
  s = block_reduce_sum(s, smem);
  float mean = s * (1.f / 768.f);
  float q = 0.f;
  for (int j = 0; j < 3; ++j) { float d = v[j] - mean; q += d * d; }
  q = block_reduce_sum(q, smem);
  float inv = rsqrtf(q * (1.f / 768.f) + 1e-5f);
  for (int j = 0; j < 3; ++j) {
    int c = tid + j * 256;
    Y[(size_t)row * Dd + c] = (v[j] - mean) * inv * w[c] + b[c];
  }
}

// ---------- split helpers: f32 -> bf16 hi + bf16 lo ----------
__device__ __forceinline__ void split8(const float* __restrict__ a, bf16x8& hi, bf16x8& lo) {
  float4 f0 = *reinterpret_cast<const float4*>(a);
  float4 f1 = *reinterpret_cast<const float4*>(a + 4);
  float v[8] = {f0.x, f0.y, f0.z, f0.w, f1.x, f1.y, f1.z, f1.w};
  for (int j = 0; j < 8; ++j) {
    __bf16 h = (__bf16)v[j];
    hi[j] = h;
    lo[j] = (__bf16)(v[j] - (float)h);
  }
}

// ---------- 128xBN split-precision MFMA GEMM (f32 in/out, ~18-bit effective inputs) ----------
// C = A*B (+bias/gelu/resid per EPI). A row-major M x K; B row-major K x N (transpose-staged
// via coalesced column reads). 4 waves in 2x2; each wave owns 64 x BN/2 (4 x BN/32 fragments).
// EPI: 0 none, 1 +bias, 2 +bias->exact gelu, 3 +bias +resid.
// grid: (Nsz/BN, Msz/128), block 256.
template<int BN, int EPI>
__global__ __launch_bounds__(256) void gemm128(
    const float* __restrict__ Ap, long lda,
    const float* __restrict__ Bp, long ldb,
    const float* __restrict__ bias, const float* __restrict__ resid,
    float* __restrict__ Cp, long ldc,
    int Ksize)
{
  constexpr int FN = BN / 32;      // B fragments per wave
  constexpr int KB = BN / 8;       // B elements staged per thread
  int tid = threadIdx.x;
  int m0 = blockIdx.y * 128, n0 = blockIdx.x * BN;

  __shared__ __align__(16) __bf16 Ah[128][40], Al[128][40];
  __shared__ __align__(16) __bf16 Bh[BN][40],  Bl[BN][40];

  f32x4 acc[4][FN];
  #pragma unroll
  for (int i = 0; i < 4; ++i)
    #pragma unroll
    for (int j = 0; j < FN; ++j)
      #pragma unroll
      for (int k = 0; k < 4; ++k) acc[i][j][k] = 0.f;

  int lane = tid & 63;
  int w = tid >> 6;
  int WR = (w >> 1) * 64, WC = (w & 1) * (BN / 2);
  int fr = lane & 15, kg = lane >> 4;

  // A staging: thread t -> row ar, 16 consecutive k
  const int ar = tid >> 1, acs = (tid & 1) * 16;
  // B staging: thread t -> col n0+bn, KB consecutive k rows (coalesced across lanes)
  const int bn = tid % BN;
  const int kb = (tid / BN) * KB;

  for (int k0 = 0; k0 < Ksize; k0 += 32) {
    { // A tile
      const float* As = Ap + (long)(m0 + ar) * lda + (k0 + acs);
      bf16x8 th, tl;
      split8(As, th, tl);
      *reinterpret_cast<bf16x8*>(&Ah[ar][acs]) = th;
      *reinterpret_cast<bf16x8*>(&Al[ar][acs]) = tl;
      split8(As + 8, th, tl);
      *reinterpret_cast<bf16x8*>(&Ah[ar][acs + 8]) = th;
      *reinterpret_cast<bf16x8*>(&Al[ar][acs + 8]) = tl;
    }
    { // B tile: column reads (lane-coalesced), b128 transposed writes
      const float* Bs = Bp + (long)(k0 + kb) * ldb + (n0 + bn);
      float bv[KB];
      #pragma unroll
      for (int j = 0; j < KB; ++j) bv[j] = Bs[(long)j * ldb];
      #pragma unroll
      for (int g8 = 0; g8 < KB / 8; ++g8) {
        bf16x8 th, tl;
        #pragma unroll
        for (int j = 0; j < 8; ++j) {
          float vv = bv[g8 * 8 + j];
          __bf16 hh = (__bf16)vv;
          th[j] = hh;
          tl[j] = (__bf16)(vv - (float)hh);
        }
        *reinterpret_cast<bf16x8*>(&Bh[bn][kb + g8 * 8]) = th;
        *reinterpret_cast<bf16x8*>(&Bl[bn][kb + g8 * 8]) = tl;
      }
    }
    __syncthreads();

    bf16x8 ah[4], al[4], bh[FN], bl[FN];
    #pragma unroll
    for (int fm = 0; fm < 4; ++fm) {
      ah[fm] = *reinterpret_cast<const bf16x8*>(&Ah[WR + fm * 16 + fr][kg * 8]);
      al[fm] = *reinterpret_cast<const bf16x8*>(&Al[WR + fm * 16 + fr][kg * 8]);
    }
    #pragma unroll
    for (int fn = 0; fn < FN; ++fn) {
      bh[fn] = *reinterpret_cast<const bf16x8*>(&Bh[WC + fn * 16 + fr][kg * 8]);
      bl[fn] = *reinterpret_cast<const bf16x8*>(&Bl[WC + fn * 16 + fr][kg * 8]);
    }
    #pragma unroll
    for (int fm = 0; fm < 4; ++fm)
      #pragma unroll
      for (int fn = 0; fn < FN; ++fn) {
        acc[fm][fn] = __builtin_amdgcn_mfma_f32_16x16x32_bf16(ah[fm], bh[fn], acc[fm][fn], 0, 0, 0);
        acc[fm][fn] = __builtin_amdgcn_mfma_f32_16x16x32_bf16(al[fm], bh[fn], acc[fm][fn], 0, 0, 0);
        acc[fm][fn] = __builtin_amdgcn_mfma_f32_16x16x32_bf16(ah[fm], bl[fn], acc[fm][fn], 0, 0, 0);
      }
    __syncthreads();
  }

  #pragma unroll
  for (int fm = 0; fm < 4; ++fm)
    #pragma unroll
    for (int fn = 0; fn < FN; ++fn)
      #pragma unroll
      for (int i = 0; i < 4; ++i) {
        int rowg = m0 + WR + fm * 16 + kg * 4 + i;
        int coln = n0 + WC + fn * 16 + fr;
        float v = acc[fm][fn][i];
        if (EPI >= 1) v += bias[coln];
        if (EPI == 2) v = 0.5f * v * (1.f + erff(v * 0.70710678118654752f));
        if (EPI == 3) v += resid[(long)rowg * ldc + coln];
        Cp[(long)rowg * ldc + coln] = v;
      }
}

// ---------- MFMA flash attention (verified round 7) ----------
__global__ __launch_bounds__(256) void flash_attn_mfma(const float* __restrict__ qkvf,
                                                       const void* __restrict__ mraw,
                                                       const int* __restrict__ flagp,
                                                       float* __restrict__ o) {
  __shared__ __align__(16) __bf16 Qh[64][72], Ql[64][72];
  __shared__ __align__(16) __bf16 Kh[64][72], Kl[64][72];
  __shared__ __align__(16) __bf16 Vth[64][66], Vtl[64][66];  // V transposed: [d][key]
  __shared__ __align__(16) __bf16 Ph[64][72], Pl[64][72];
  __shared__ float kmf[64];
  __shared__ float qmf[64];

  int b = blockIdx.z, hh = blockIdx.y;
  int q0 = blockIdx.x * 64;
  int tid = threadIdx.x, lane = tid & 63, w = tid >> 6;
  int flag = *flagp;
  int fr = lane & 15, kg = lane >> 4;

  const int sr = tid >> 2;
  const int sc = (tid & 3) * 16;

  {
    const float* Qsrc = qkvf + ((long)(b * Nn + q0 + sr)) * (3 * Dd) + hh * HDd + sc;
    bf16x8 th, tl;
    split8(Qsrc, th, tl);
    *reinterpret_cast<bf16x8*>(&Qh[sr][sc]) = th;
    *reinterpret_cast<bf16x8*>(&Ql[sr][sc]) = tl;
    split8(Qsrc + 8, th, tl);
    *reinterpret_cast<bf16x8*>(&Qh[sr][sc + 8]) = th;
    *reinterpret_cast<bf16x8*>(&Ql[sr][sc + 8]) = tl;
    if (tid < 64) qmf[tid] = mask_at(mraw, flag, b * Nn + q0 + tid) ? 1.f : 0.f;
  }
  __syncthreads();

  float qm[4];
  #pragma unroll
  for (int i = 0; i < 4; ++i) qm[i] = qmf[16 * w + kg * 4 + i];

  bf16x8 qah[2], qal[2];
  #pragma unroll
  for (int ks = 0; ks < 2; ++ks) {
    qah[ks] = *reinterpret_cast<const bf16x8*>(&Qh[16 * w + fr][ks * 32 + kg * 8]);
    qal[ks] = *reinterpret_cast<const bf16x8*>(&Ql[16 * w + fr][ks * 32 + kg * 8]);
  }

  float mrow[4], lrow[4];
  f32x4 accO[4];
  #pragma unroll
  for (int i = 0; i < 4; ++i) { mrow[i] = -INFINITY; lrow[i] = 0.f; }
  #pragma unroll
  for (int t = 0; t < 4; ++t)
    for (int i = 0; i < 4; ++i) accO[t][i] = 0.f;

  for (int j0 = 0; j0 < Nn; j0 += 64) {
    __syncthreads();
    {
      const float* Ksrc = qkvf + ((long)(b * Nn + j0 + sr)) * (3 * Dd) + Dd + hh * HDd + sc;
      const float* Vsrc = Ksrc + Dd;
      bf16x8 th, tl;
      split8(Ksrc, th, tl);
      *reinterpret_cast<bf16x8*>(&Kh[sr][sc]) = th;
      *reinterpret_cast<bf16x8*>(&Kl[sr][sc]) = tl;
      split8(Ksrc + 8, th, tl);
      *reinterpret_cast<bf16x8*>(&Kh[sr][sc + 8]) = th;
      *reinterpret_cast<bf16x8*>(&Kl[sr][sc + 8]) = tl;
      #pragma unroll
      for (int j = 0; j < 16; ++j) {
        float vv = Vsrc[j];
        __bf16 vh = (__bf16)vv;
        Vth[sc + j][sr] = vh;
        Vtl[sc + j][sr] = (__bf16)(vv - (float)vh);
      }
      if (tid < 64) kmf[tid] = mask_at(mraw, flag, b * Nn + j0 + tid) ? 1.f : 0.f;
    }
    __syncthreads();

    f32x4 sacc[4];
    #pragma unroll
    for (int t = 0; t < 4; ++t)
      for (int i = 0; i < 4; ++i) sacc[t][i] = 0.f;
    #pragma unroll
    for (int ks = 0; ks < 2; ++ks) {
      #pragma unroll
      for (int t = 0; t < 4; ++t) {
        bf16x8 bh = *reinterpret_cast<const bf16x8*>(&Kh[16 * t + fr][ks * 32 + kg * 8]);
        bf16x8 bl = *reinterpret_cast<const bf16x8*>(&Kl[16 * t + fr][ks * 32 + kg * 8]);
        sacc[t] = __builtin_amdgcn_mfma_f32_16x16x32_bf16(qah[ks], bh, sacc[t], 0, 0, 0);
        sacc[t] = __builtin_amdgcn_mfma_f32_16x16x32_bf16(qal[ks], bh, sacc[t], 0, 0, 0);
        sacc[t] = __builtin_amdgcn_mfma_f32_16x16x32_bf16(qah[ks], bl, sacc[t], 0, 0, 0);
      }
    }

    float sv[4][4];
    float mt[4] = {-INFINITY, -INFINITY, -INFINITY, -INFINITY};
    #pragma unroll
    for (int t = 0; t < 4; ++t) {
      float km = kmf[16 * t + fr];
      #pragma unroll
      for (int i = 0; i < 4; ++i) {
        float s = (km > 0.f && qm[i] > 0.f) ? sacc[t][i] * 0.125f : NEGF;
        sv[t][i] = s;
        mt[i] = fmaxf(mt[i], s);
      }
    }
    #pragma unroll
    for (int off = 8; off; off >>= 1)
      #pragma unroll
      for (int i = 0; i < 4; ++i) mt[i] = fmaxf(mt[i], __shfl_xor(mt[i], off));

    float r[4], psum[4];
    #pragma unroll
    for (int i = 0; i < 4; ++i) {
      float mn = fmaxf(mrow[i], mt[i]);
      r[i] = expf(mrow[i] - mn);
      mrow[i] = mn;
      psum[i] = 0.f;
    }
    #pragma unroll
    for (int t = 0; t < 4; ++t) {
      #pragma unroll
      for (int i = 0; i < 4; ++i) {
        float p = expf(sv[t][i] - mrow[i]);
        psum[i] += p;
        __bf16 ph = (__bf16)p;
        Ph[16 * w + kg * 4 + i][16 * t + fr] = ph;
        Pl[16 * w + kg * 4 + i][16 * t + fr] = (__bf16)(p - (float)ph);
      }
    }
    #pragma unroll
    for (int off = 8; off; off >>= 1)
      #pragma unroll
      for (int i = 0; i < 4; ++i) psum[i] += __shfl_xor(psum[i], off);
    #pragma unroll
    for (int i = 0; i < 4; ++i) lrow[i] = lrow[i] * r[i] + psum[i];
    #pragma unroll
    for (int t = 0; t < 4; ++t)
      #pragma unroll
      for (int i = 0; i < 4; ++i) accO[t][i] *= r[i];

    __syncthreads();

    #pragma unroll
    for (int ks = 0; ks < 2; ++ks) {
      bf16x8 pah = *reinterpret_cast<const bf16x8*>(&Ph[16 * w + fr][ks * 32 + kg * 8]);
      bf16x8 pal = *reinterpret_cast<const bf16x8*>(&Pl[16 * w + fr][ks * 32 + kg * 8]);
      #pragma unroll
      for (int t2 = 0; t2 < 4; ++t2) {
        bf16x8 vbh = *reinterpret_cast<const bf16x8*>(&Vth[16 * t2 + fr][ks * 32 + kg * 8]);
        bf16x8 vbl = *reinterpret_cast<const bf16x8*>(&Vtl[16 * t2 + fr][ks * 32 + kg * 8]);
        accO[t2] = __builtin_amdgcn_mfma_f32_16x16x32_bf16(pah, vbh, accO[t2], 0, 0, 0);
        accO[t2] = __builtin_amdgcn_mfma_f32_16x16x32_bf16(pal, vbh, accO[t2], 0, 0, 0);
        accO[t2] = __builtin_amdgcn_mfma_f32_16x16x32_bf16(pah, vbl, accO[t2], 0, 0, 0);
      }
    }
  }

  #pragma unroll
  for (int t2 = 0; t2 < 4; ++t2)
    #pragma unroll
    for (int i = 0; i < 4; ++i) {
      int qrow = q0 + 16 * w + kg * 4 + i;
      int col = 16 * t2 + fr;
      o[((long)(b * Nn + qrow)) * Dd + hh * HDd + col] = accO[t2][i] / lrow[i];
    }
}

// ---------- seq-pool ----------
__global__ __launch_bounds__(256) void pool_score(const float* __restrict__ hn, const float* __restrict__ pw,
                                                  const float* __restrict__ pb, float* __restrict__ s) {
  __shared__ float smem[4];
  int row = blockIdx.x, tid = threadIdx.x;
  const float* x = hn + (size_t)row * Dd;
  float acc = 0.f;
  for (int j = 0; j < 3; ++j) { int c = tid + j * 256; acc += x[c] * pw[c]; }
  acc = block_reduce_sum(acc, smem);
  if (tid == 0) s[row] = acc + pb[0];
}

__global__ __launch_bounds__(256) void pool_softmax(const float* __restrict__ s, float* __restrict__ w) {
  __shared__ float smem[4];
  int b = blockIdx.x, tid = threadIdx.x;
  const float* x = s + b * Nn;
  float v[4];
  for (int j = 0; j < 4; ++j) v[j] = x[tid * 4 + j];
  float mx = fmaxf(fmaxf(v[0], v[1]), fmaxf(v[2], v[3]));
  mx = block_reduce_max(mx, smem);
  float e[4], sum = 0.f;
  for (int j = 0; j < 4; ++j) { e[j] = expf(v[j] - mx); sum += e[j]; }
  sum = block_reduce_sum(sum, smem);
  float inv = 1.f / sum;
  for (int j = 0; j < 4; ++j) w[b * Nn + tid * 4 + j] = e[j] * inv;
}

__global__ __launch_bounds__(256) void pool_reduce(const float* __restrict__ hn, const float* __restrict__ w,
                                                   float* __restrict__ pooled) {
  int b = blockIdx.x, tid = threadIdx.x;
  float acc[3] = {0.f, 0.f, 0.f};
  for (int n = 0; n < Nn; ++n) {
    float wn = w[b * Nn + n];
    const float* hr = hn + ((size_t)(b * Nn + n)) * Dd;
    for (int j = 0; j < 3; ++j) acc[j] += wn * hr[tid + j * 256];
  }
  for (int j = 0; j < 3; ++j) pooled[b * Dd + tid + j * 256] = acc[j];
}

__global__ __launch_bounds__(256) void fc_kernel(const float* __restrict__ pooled, const float* __restrict__ fw,
                                                 const float* __restrict__ fb, float* __restrict__ out) {
  __shared__ float p[768];
  int b = blockIdx.x, tid = threadIdx.x;
  for (int j = 0; j < 3; ++j) p[tid + j * 256] = pooled[b * Dd + tid + j * 256];
  __syncthreads();
  for (int c = tid; c < NCc; c += 256) {
    float acc = fb[c];
    for (int d = 0; d < Dd; ++d) acc += p[d] * fw[(size_t)d * NCc + c];
    out[b * NCc + c] = acc;
  }
}

extern "C" void kernel_launch(void* const* d_in, const int* in_sizes, int n_in,
                              void* d_out, int out_size, void* d_ws, size_t ws_size,
                              hipStream_t stream) {
  const float* x      = (const float*)d_in[0];
  const void*  mask   = d_in[1];
  const float* pe     = (const float*)d_in[2];
  const float* ln0_w  = (const float*)d_in[3];
  const float* ln0_b  = (const float*)d_in[4];
  const float* qkv_w  = (const float*)d_in[5];
  const float* proj_w = (const float*)d_in[6];
  const float* proj_b = (const float*)d_in[7];
  const float* ln1_w  = (const float*)d_in[8];
  const float* ln1_b  = (const float*)d_in[9];
  const float* ff1_w  = (const float*)d_in[10];
  const float* ff1_b  = (const float*)d_in[11];
  const float* ff2_w  = (const float*)d_in[12];
  const float* ff2_b  = (const float*)d_in[13];
  const float* norm_w = (const float*)d_in[14];
  const float* norm_b = (const float*)d_in[15];
  const float* pool_w = (const float*)d_in[16];
  const float* pool_b = (const float*)d_in[17];
  const float* fc_w   = (const float*)d_in[18];
  const float* fc_b   = (const float*)d_in[19];
  float* out = (float*)d_out;

  // Compact workspace (~44 MB) — verified in round 5. Do NOT grow past this.
  float* ws = (float*)d_ws;
  float* h      = ws;                        // Mm*Dd
  float* y      = h + (long)Mm * Dd;         // Mm*Dd
  float* qkvf   = y + (long)Mm * Dd;         // Mm*3*Dd
  float* o      = qkvf + (long)Mm * 3 * Dd;  // Mm*Dd
  float* hn     = o + (long)Mm * Dd;         // Mm*Dd
  float* spool  = hn + (long)Mm * Dd;        // Mm
  float* wpool  = spool + Mm;                // Mm
  float* pooled = wpool + Mm;                // Bb*Dd
  int*   mflag  = (int*)(pooled + Bb * Dd);
  float* po = y;      // alias: y dead after qkv gemm
  float* g  = qkvf;   // alias: ff1 out fits exactly in qkvf+o (dead after proj)

  detect_mask<<<1, 256, 0, stream>>>((const unsigned char*)mask, mflag);
  add_pe_k<<<(Mm * Dd) / 256, 256, 0, stream>>>(x, pe, h);

  for (int l = 0; l < NLl; ++l) {
    ln_kernel<<<Mm, 256, 0, stream>>>(h, nullptr, ln0_w + l * Dd, ln0_b + l * Dd, y);

    // qkv: (Mm x 768) @ (768 x 2304) -> qkvf
    gemm128<64,0><<<dim3(3 * Dd / 64, Mm / 128), 256, 0, stream>>>(
        y, Dd,
        qkv_w + (long)l * Dd * 3 * Dd, 3 * Dd,
        nullptr, nullptr,
        qkvf, 3 * Dd, Dd);

    // fused attention: o = softmax(mask(QK^T/8)) @ V   (MFMA flash)
    flash_attn_mfma<<<dim3(Nn / 64, Hh, Bb), 256, 0, stream>>>(qkvf, mask, mflag, o);

    // proj: o @ proj_w + b -> po (=y)
    gemm128<64,1><<<dim3(Dd / 64, Mm / 128), 256, 0, stream>>>(
        o, Dd,
        proj_w + (long)l * Dd * Dd, Dd,
        proj_b + l * Dd, nullptr,
        po, Dd, Dd);

    ln_kernel<<<Mm, 256, 0, stream>>>(h, po, ln1_w + l * Dd, ln1_b + l * Dd, h);

    // ff1: h @ ff1_w + b -> gelu -> g
    gemm128<64,2><<<dim3(FFf / 64, Mm / 128), 256, 0, stream>>>(
        h, Dd,
        ff1_w + (long)l * Dd * FFf, FFf,
        ff1_b + l * FFf, nullptr,
        g, FFf, Dd);

    // ff2: g @ ff2_w + b + h -> h
    gemm128<64,3><<<dim3(Dd / 64, Mm / 128), 256, 0, stream>>>(
        g, FFf,
        ff2_w + (long)l * FFf * Dd, Dd,
        ff2_b + l * Dd, h,
        h, Dd, FFf);
  }

  ln_kernel<<<Mm, 256, 0, stream>>>(h, nullptr, norm_w, norm_b, hn);
  pool_score<<<Mm, 256, 0, stream>>>(hn, pool_w, pool_b, spool);
  pool_softmax<<<Bb, 256, 0, stream>>>(spool, wpool);
  pool_reduce<<<Bb, 256, 0, stream>>>(hn, wpool, pooled);
  fc_kernel<<<Bb, 256, 0, stream>>>(pooled, fc_w, fc_b, out);
}

// Round 9
// 3779.919 us; speedup vs baseline: 11.3158x; 1.0884x over previous
//
#include <hip/hip_runtime.h>
#include <hip/hip_bf16.h>
#include <cfloat>
#include <cmath>

typedef __bf16 bf16x8 __attribute__((ext_vector_type(8)));
typedef float  f32x4  __attribute__((ext_vector_type(4)));

static constexpr int Bb = 2, Nn = 1024, Dd = 768, Hh = 12, HDd = 64, FFf = 3072, NLl = 12, NCc = 1000;
static constexpr int Mm = Bb * Nn; // 2048
static constexpr float NEGF = -3.402823466e38f;

// ---------- reductions (256-thread blocks = 4 waves) ----------
__device__ __forceinline__ float block_reduce_sum(float v, volatile float* smem) {
  for (int o = 32; o; o >>= 1) v += __shfl_down(v, o);
  int lane = threadIdx.x & 63, w = threadIdx.x >> 6;
  __syncthreads();
  if (lane == 0) smem[w] = v;
  __syncthreads();
  return smem[0] + smem[1] + smem[2] + smem[3];
}

__device__ __forceinline__ float block_reduce_max(float v, volatile float* smem) {
  for (int o = 32; o; o >>= 1) v = fmaxf(v, __shfl_down(v, o));
  int lane = threadIdx.x & 63, w = threadIdx.x >> 6;
  __syncthreads();
  if (lane == 0) smem[w] = v;
  __syncthreads();
  return fmaxf(fmaxf(smem[0], smem[1]), fmaxf(smem[2], smem[3]));
}

// ---------- mask dtype detection: 0=int32 1=bytes 2=f32 3=int64 4=bf16 ----------
__global__ void detect_mask(const unsigned char* __restrict__ m, int* __restrict__ flag) {
  __shared__ int s_nz1, s_nz2, s_nz3, s_nz84, s_pv;
  int tid = threadIdx.x;
  if (tid == 0) { s_nz1 = 0; s_nz2 = 0; s_nz3 = 0; s_nz84 = 0; s_pv = 0; }
  __syncthreads();
  int nz1 = 0, nz2 = 0, nz3 = 0, nz84 = 0, pv = 0;
  for (int i = tid; i < 2048; i += 256) {
    unsigned char v = m[i];
    if (v) {
      int p4 = i & 3;
      if (p4 == 1) nz1 = 1;
      if (p4 == 2) nz2 = 1;
      if (p4 == 3) nz3 = 1;
      if ((i & 7) == 4) nz84 = 1;
      if ((i & 1) == 0) { if (v != 0x80) pv = 1; }
      else              { if (v != 0x3f) pv = 1; }
    }
  }
  if (nz1)  atomicOr(&s_nz1, 1);
  if (nz2)  atomicOr(&s_nz2, 1);
  if (nz3)  atomicOr(&s_nz3, 1);
  if (nz84) atomicOr(&s_nz84, 1);
  if (pv)   atomicOr(&s_pv, 1);
  __syncthreads();
  if (tid == 0) {
    int f;
    if (!s_nz1 && !s_nz2 && !s_nz3) f = s_nz84 ? 0 : 3;
    else if (!s_pv)                 f = s_nz1 ? 4 : 2;
    else                            f = 1;
    *flag = f;
  }
}

__device__ __forceinline__ bool mask_at(const void* mraw, int flag, int idx) {
  switch (flag) {
    case 0:  return ((const int*)mraw)[idx] != 0;
    case 1:  return ((const unsigned char*)mraw)[idx] != 0;
    case 2:  return ((const float*)mraw)[idx] != 0.f;
    case 3:  return ((const long long*)mraw)[idx] != 0;
    default: return ((const unsigned short*)mraw)[idx] != 0;
  }
}

// ---------- h = x + pe (pe broadcast over batch) ----------
__global__ __launch_bounds__(256) void add_pe_k(const float* __restrict__ x, const float* __restrict__ pe,
                                                float* __restrict__ h) {
  long i = (long)blockIdx.x * 256 + threadIdx.x;
  long nd = i % ((long)Nn * Dd);
  h[i] = x[i] + pe[nd];
}

// ---------- LayerNorm (optionally with residual input added first), row = 768 ----------
__global__ __launch_bounds__(256) void ln_kernel(const float* __restrict__ X, const float* __restrict__ R,
                                                 const float* __restrict__ w, const float* __restrict__ b,
                                                 float* __restrict__ Y) {
  __shared__ float smem[4];
  int row = blockIdx.x, tid = threadIdx.x;
  const float* x = X + (size_t)row * Dd;
  const bool hasR = (R != nullptr);
  const float* r = hasR ? R + (size_t)row * Dd : nullptr;
  float v[3];
  for (int j = 0; j < 3; ++j) {
    int c = tid + j * 256;
    v[j] = x[c] + (hasR ? r[c] : 0.f);
  }
  float s = v[0] + v[1] + v[2];
  s = block_reduce_sum(s, smem);
  float mean = s * (1.f / 768.f);
  float q = 0.f;
  for (int j = 0; j < 3; ++j) { float d = v[j] - mean; q += d * d; }
  q = block_reduce_sum(q, smem);
  float inv = rsqrtf(q * (1.f / 768.f) + 1e-5f);
  for (int j = 0; j < 3; ++j) {
    int c = tid + j * 256;
    Y[(size_t)row * Dd + c] = (v[j] - mean) * inv * w[c] + b[c];
  }
}

// ---------- split helpers: f32 -> bf16 hi + bf16 lo ----------
__device__ __forceinline__ void split8(const float* __restrict__ a, bf16x8& hi, bf16x8& lo) {
  float4 f0 = *reinterpret_cast<const float4*>(a);
  float4 f1 = *reinterpret_cast<const float4*>(a + 4);
  float v[8] = {f0.x, f0.y, f0.z, f0.w, f1.x, f1.y, f1.z, f1.w};
  for (int j = 0; j < 8; ++j) {
    __bf16 h = (__bf16)v[j];
    hi[j] = h;
    lo[j] = (__bf16)(v[j] - (float)h);
  }
}

__device__ __forceinline__ void split8v(const float* __restrict__ v, bf16x8& hi, bf16x8& lo) {
  for (int j = 0; j < 8; ++j) {
    __bf16 h = (__bf16)v[j];
    hi[j] = h;
    lo[j] = (__bf16)(v[j] - (float)h);
  }
}

// ---------- 128xBN split-precision MFMA GEMM with register prefetch pipeline ----------
// C = A*B (+bias/gelu/resid per EPI). A row-major M x K; B row-major K x N (transpose-staged
// via coalesced column reads). 4 waves in 2x2; each wave owns 64 x BN/2 (4 x BN/32 fragments).
// Pipeline: tile k0 held in registers; global loads for k0+32 issued before the MFMA phase so
// HBM latency hides under MFMA; compiler drains vmcnt at the next barrier.
// EPI: 0 none, 1 +bias, 2 +bias->exact gelu, 3 +bias +resid.
// grid: (Nsz/BN, Msz/128), block 256.
template<int BN, int EPI>
__global__ __launch_bounds__(256) void gemm128(
    const float* __restrict__ Ap, long lda,
    const float* __restrict__ Bp, long ldb,
    const float* __restrict__ bias, const float* __restrict__ resid,
    float* __restrict__ Cp, long ldc,
    int Ksize)
{
  constexpr int FN = BN / 32;      // B fragments per wave
  constexpr int KB = BN / 8;       // B elements staged per thread
  int tid = threadIdx.x;
  int m0 = blockIdx.y * 128, n0 = blockIdx.x * BN;

  __shared__ __align__(16) __bf16 Ah[128][40], Al[128][40];
  __shared__ __align__(16) __bf16 Bh[BN][40],  Bl[BN][40];

  f32x4 acc[4][FN];
  #pragma unroll
  for (int i = 0; i < 4; ++i)
    #pragma unroll
    for (int j = 0; j < FN; ++j)
      #pragma unroll
      for (int k = 0; k < 4; ++k) acc[i][j][k] = 0.f;

  int lane = tid & 63;
  int w = tid >> 6;
  int WR = (w >> 1) * 64, WC = (w & 1) * (BN / 2);
  int fr = lane & 15, kg = lane >> 4;

  const int ar = tid >> 1, acs = (tid & 1) * 16;  // A: row ar, 16 consecutive k
  const int bn = tid % BN;                         // B: col n0+bn (lane-coalesced)
  const int kb = (tid / BN) * KB;                  //    KB consecutive k rows

  const float* Abase = Ap + (long)(m0 + ar) * lda + acs;
  const float* Bbase = Bp + (long)kb * ldb + (n0 + bn);

  float pa[16], pb[KB];
  // prologue: load tile 0
  {
    const float* As = Abase;
    *reinterpret_cast<float4*>(&pa[0])  = *reinterpret_cast<const float4*>(As);
    *reinterpret_cast<float4*>(&pa[4])  = *reinterpret_cast<const float4*>(As + 4);
    *reinterpret_cast<float4*>(&pa[8])  = *reinterpret_cast<const float4*>(As + 8);
    *reinterpret_cast<float4*>(&pa[12]) = *reinterpret_cast<const float4*>(As + 12);
    #pragma unroll
    for (int j = 0; j < KB; ++j) pb[j] = Bbase[(long)j * ldb];
  }

  for (int k0 = 0; k0 < Ksize; k0 += 32) {
    __syncthreads();  // previous tile's MFMA reads complete
    { // convert + write LDS from registers (tile k0)
      bf16x8 th, tl;
      split8v(&pa[0], th, tl);
      *reinterpret_cast<bf16x8*>(&Ah[ar][acs]) = th;
      *reinterpret_cast<bf16x8*>(&Al[ar][acs]) = tl;
      split8v(&pa[8], th, tl);
      *reinterpret_cast<bf16x8*>(&Ah[ar][acs + 8]) = th;
      *reinterpret_cast<bf16x8*>(&Al[ar][acs + 8]) = tl;
      #pragma unroll
      for (int g8 = 0; g8 < KB / 8; ++g8) {
        bf16x8 bth, btl;
        split8v(&pb[g8 * 8], bth, btl);
        *reinterpret_cast<bf16x8*>(&Bh[bn][kb + g8 * 8]) = bth;
        *reinterpret_cast<bf16x8*>(&Bl[bn][kb + g8 * 8]) = btl;
      }
    }
    __syncthreads();  // LDS tile ready

    if (k0 + 32 < Ksize) { // issue next tile's loads; in flight during MFMA phase
      const float* As = Abase + (k0 + 32);
      *reinterpret_cast<float4*>(&pa[0])  = *reinterpret_cast<const float4*>(As);
      *reinterpret_cast<float4*>(&pa[4])  = *reinterpret_cast<const float4*>(As + 4);
      *reinterpret_cast<float4*>(&pa[8])  = *reinterpret_cast<const float4*>(As + 8);
      *reinterpret_cast<float4*>(&pa[12]) = *reinterpret_cast<const float4*>(As + 12);
      const float* Bs = Bbase + (long)(k0 + 32) * ldb;
      #pragma unroll
      for (int j = 0; j < KB; ++j) pb[j] = Bs[(long)j * ldb];
    }

    bf16x8 ah[4], al[4], bh[FN], bl[FN];
    #pragma unroll
    for (int fm = 0; fm < 4; ++fm) {
      ah[fm] = *reinterpret_cast<const bf16x8*>(&Ah[WR + fm * 16 + fr][kg * 8]);
      al[fm] = *reinterpret_cast<const bf16x8*>(&Al[WR + fm * 16 + fr][kg * 8]);
    }
    #pragma unroll
    for (int fn = 0; fn < FN; ++fn) {
      bh[fn] = *reinterpret_cast<const bf16x8*>(&Bh[WC + fn * 16 + fr][kg * 8]);
      bl[fn] = *reinterpret_cast<const bf16x8*>(&Bl[WC + fn * 16 + fr][kg * 8]);
    }
    #pragma unroll
    for (int fm = 0; fm < 4; ++fm)
      #pragma unroll
      for (int fn = 0; fn < FN; ++fn) {
        acc[fm][fn] = __builtin_amdgcn_mfma_f32_16x16x32_bf16(ah[fm], bh[fn], acc[fm][fn], 0, 0, 0);
        acc[fm][fn] = __builtin_amdgcn_mfma_f32_16x16x32_bf16(al[fm], bh[fn], acc[fm][fn], 0, 0, 0);
        acc[fm][fn] = __builtin_amdgcn_mfma_f32_16x16x32_bf16(ah[fm], bl[fn], acc[fm][fn], 0, 0, 0);
      }
  }

  #pragma unroll
  for (int fm = 0; fm < 4; ++fm)
    #pragma unroll
    for (int fn = 0; fn < FN; ++fn)
      #pragma unroll
      for (int i = 0; i < 4; ++i) {
        int rowg = m0 + WR + fm * 16 + kg * 4 + i;
        int coln = n0 + WC + fn * 16 + fr;
        float v = acc[fm][fn][i];
        if (EPI >= 1) v += bias[coln];
        if (EPI == 2) v = 0.5f * v * (1.f + erff(v * 0.70710678118654752f));
        if (EPI == 3) v += resid[(long)rowg * ldc + coln];
        Cp[(long)rowg * ldc + coln] = v;
      }
}

// ---------- MFMA flash attention (verified round 7) ----------
__global__ __launch_bounds__(256) void flash_attn_mfma(const float* __restrict__ qkvf,
                                                       const void* __restrict__ mraw,
                                                       const int* __restrict__ flagp,
                                                       float* __restrict__ o) {
  __shared__ __align__(16) __bf16 Qh[64][72], Ql[64][72];
  __shared__ __align__(16) __bf16 Kh[64][72], Kl[64][72];
  __shared__ __align__(16) __bf16 Vth[64][66], Vtl[64][66];  // V transposed: [d][key]
  __shared__ __align__(16) __bf16 Ph[64][72], Pl[64][72];
  __shared__ float kmf[64];
  __shared__ float qmf[64];

  int b = blockIdx.z, hh = blockIdx.y;
  int q0 = blockIdx.x * 64;
  int tid = threadIdx.x, lane = tid & 63, w = tid >> 6;
  int flag = *flagp;
  int fr = lane & 15, kg = lane >> 4;

  const int sr = tid >> 2;
  const int sc = (tid & 3) * 16;

  {
    const float* Qsrc = qkvf + ((long)(b * Nn + q0 + sr)) * (3 * Dd) + hh * HDd + sc;
    bf16x8 th, tl;
    split8(Qsrc, th, tl);
    *reinterpret_cast<bf16x8*>(&Qh[sr][sc]) = th;
    *reinterpret_cast<bf16x8*>(&Ql[sr][sc]) = tl;
    split8(Qsrc + 8, th, tl);
    *reinterpret_cast<bf16x8*>(&Qh[sr][sc + 8]) = th;
    *reinterpret_cast<bf16x8*>(&Ql[sr][sc + 8]) = tl;
    if (tid < 64) qmf[tid] = mask_at(mraw, flag, b * Nn + q0 + tid) ? 1.f : 0.f;
  }
  __syncthreads();

  float qm[4];
  #pragma unroll
  for (int i = 0; i < 4; ++i) qm[i] = qmf[16 * w + kg * 4 + i];

  bf16x8 qah[2], qal[2];
  #pragma unroll
  for (int ks = 0; ks < 2; ++ks) {
    qah[ks] = *reinterpret_cast<const bf16x8*>(&Qh[16 * w + fr][ks * 32 + kg * 8]);
    qal[ks] = *reinterpret_cast<const bf16x8*>(&Ql[16 * w + fr][ks * 32 + kg * 8]);
  }

  float mrow[4], lrow[4];
  f32x4 accO[4];
  #pragma unroll
  for (int i = 0; i < 4; ++i) { mrow[i] = -INFINITY; lrow[i] = 0.f; }
  #pragma unroll
  for (int t = 0; t < 4; ++t)
    for (int i = 0; i < 4; ++i) accO[t][i] = 0.f;

  for (int j0 = 0; j0 < Nn; j0 += 64) {
    __syncthreads();
    {
      const float* Ksrc = qkvf + ((long)(b * Nn + j0 + sr)) * (3 * Dd) + Dd + hh * HDd + sc;
      const float* Vsrc = Ksrc + Dd;
      bf16x8 th, tl;
      split8(Ksrc, th, tl);
      *reinterpret_cast<bf16x8*>(&Kh[sr][sc]) = th;
      *reinterpret_cast<bf16x8*>(&Kl[sr][sc]) = tl;
      split8(Ksrc + 8, th, tl);
      *reinterpret_cast<bf16x8*>(&Kh[sr][sc + 8]) = th;
      *reinterpret_cast<bf16x8*>(&Kl[sr][sc + 8]) = tl;
      #pragma unroll
      for (int j = 0; j < 16; ++j) {
        float vv = Vsrc[j];
        __bf16 vh = (__bf16)vv;
        Vth[sc + j][sr] = vh;
        Vtl[sc + j][sr] = (__bf16)(vv - (float)vh);
      }
      if (tid < 64) kmf[tid] = mask_at(mraw, flag, b * Nn + j0 + tid) ? 1.f : 0.f;
    }
    __syncthreads();

    f32x4 sacc[4];
    #pragma unroll
    for (int t = 0; t < 4; ++t)
      for (int i = 0; i < 4; ++i) sacc[t][i] = 0.f;
    #pragma unroll
    for (int ks = 0; ks < 2; ++ks) {
      #pragma unroll
      for (int t = 0; t < 4; ++t) {
        bf16x8 bh = *reinterpret_cast<const bf16x8*>(&Kh[16 * t + fr][ks * 32 + kg * 8]);
        bf16x8 bl = *reinterpret_cast<const bf16x8*>(&Kl[16 * t + fr][ks * 32 + kg * 8]);
        sacc[t] = __builtin_amdgcn_mfma_f32_16x16x32_bf16(qah[ks], bh, sacc[t], 0, 0, 0);
        sacc[t] = __builtin_amdgcn_mfma_f32_16x16x32_bf16(qal[ks], bh, sacc[t], 0, 0, 0);
        sacc[t] = __builtin_amdgcn_mfma_f32_16x16x32_bf16(qah[ks], bl, sacc[t], 0, 0, 0);
      }
    }

    float sv[4][4];
    float mt[4] = {-INFINITY, -INFINITY, -INFINITY, -INFINITY};
    #pragma unroll
    for (int t = 0; t < 4; ++t) {
      float km = kmf[16 * t + fr];
      #pragma unroll
      for (int i = 0; i < 4; ++i) {
        float s = (km > 0.f && qm[i] > 0.f) ? sacc[t][i] * 0.125f : NEGF;
        sv[t][i] = s;
        mt[i] = fmaxf(mt[i], s);
      }
    }
    #pragma unroll
    for (int off = 8; off; off >>= 1)
      #pragma unroll
      for (int i = 0; i < 4; ++i) mt[i] = fmaxf(mt[i], __shfl_xor(mt[i], off));

    float r[4], psum[4];
    #pragma unroll
    for (int i = 0; i < 4; ++i) {
      float mn = fmaxf(mrow[i], mt[i]);
      r[i] = expf(mrow[i] - mn);
      mrow[i] = mn;
      psum[i] = 0.f;
    }
    #pragma unroll
    for (int t = 0; t < 4; ++t) {
      #pragma unroll
      for (int i = 0; i < 4; ++i) {
        float p = expf(sv[t][i] - mrow[i]);
        psum[i] += p;
        __bf16 ph = (__bf16)p;
        Ph[16 * w + kg * 4 + i][16 * t + fr] = ph;
        Pl[16 * w + kg * 4 + i][16 * t + fr] = (__bf16)(p - (float)ph);
      }
    }
    #pragma unroll
    for (int off = 8; off; off >>= 1)
      #pragma unroll
      for (int i = 0; i < 4; ++i) psum[i] += __shfl_xor(psum[i], off);
    #pragma unroll
    for (int i = 0; i < 4; ++i) lrow[i] = lrow[i] * r[i] + psum[i];
    #pragma unroll
    for (int t = 0; t < 4; ++t)
      #pragma unroll
      for (int i = 0; i < 4; ++i) accO[t][i] *= r[i];

    __syncthreads();

    #pragma unroll
    for (int ks = 0; ks < 2; ++ks) {
      bf16x8 pah = *reinterpret_cast<const bf16x8*>(&Ph[16 * w + fr][ks * 32 + kg * 8]);
      bf16x8 pal = *reinterpret_cast<const bf16x8*>(&Pl[16 * w + fr][ks * 32 + kg * 8]);
      #pragma unroll
      for (int t2 = 0; t2 < 4; ++t2) {
        bf16x8 vbh = *reinterpret_cast<const bf16x8*>(&Vth[16 * t2 + fr][ks * 32 + kg * 8]);
        bf16x8 vbl = *reinterpret_cast<const bf16x8*>(&Vtl[16 * t2 + fr][ks * 32 + kg * 8]);
        accO[t2] = __builtin_amdgcn_mfma_f32_16x16x32_bf16(pah, vbh, accO[t2], 0, 0, 0);
        accO[t2] = __builtin_amdgcn_mfma_f32_16x16x32_bf16(pal, vbh, accO[t2], 0, 0, 0);
        accO[t2] = __builtin_amdgcn_mfma_f32_16x16x32_bf16(pah, vbl, accO[t2], 0, 0, 0);
      }
    }
  }

  #pragma unroll
  for (int t2 = 0; t2 < 4; ++t2)
    #pragma unroll
    for (int i = 0; i < 4; ++i) {
      int qrow = q0 + 16 * w + kg * 4 + i;
      int col = 16 * t2 + fr;
      o[((long)(b * Nn + qrow)) * Dd + hh * HDd + col] = accO[t2][i] / lrow[i];
    }
}

// ---------- seq-pool ----------
__global__ __launch_bounds__(256) void pool_score(const float* __restrict__ hn, const float* __restrict__ pw,
                                                  const float* __restrict__ pb, float* __restrict__ s) {
  __shared__ float smem[4];
  int row = blockIdx.x, tid = threadIdx.x;
  const float* x = hn + (size_t)row * Dd;
  float acc = 0.f;
  for (int j = 0; j < 3; ++j) { int c = tid + j * 256; acc += x[c] * pw[c]; }
  acc = block_reduce_sum(acc, smem);
  if (tid == 0) s[row] = acc + pb[0];
}

__global__ __launch_bounds__(256) void pool_softmax(const float* __restrict__ s, float* __restrict__ w) {
  __shared__ float smem[4];
  int b = blockIdx.x, tid = threadIdx.x;
  const float* x = s + b * Nn;
  float v[4];
  for (int j = 0; j < 4; ++j) v[j] = x[tid * 4 + j];
  float mx = fmaxf(fmaxf(v[0], v[1]), fmaxf(v[2], v[3]));
  mx = block_reduce_max(mx, smem);
  float e[4], sum = 0.f;
  for (int j = 0; j < 4; ++j) { e[j] = expf(v[j] - mx); sum += e[j]; }
  sum = block_reduce_sum(sum, smem);
  float inv = 1.f / sum;
  for (int j = 0; j < 4; ++j) w[b * Nn + tid * 4 + j] = e[j] * inv;
}

// stage 1: partial sums over 128-token chunks. grid (Dd/256, 8, Bb), block 256.
__global__ __launch_bounds__(256) void pool_reduce1(const float* __restrict__ hn, const float* __restrict__ w,
                                                    float* __restrict__ part) {
  int d = blockIdx.x * 256 + threadIdx.x;
  int ch = blockIdx.y, b = blockIdx.z;
  int n0 = ch * 128;
  float a0 = 0.f, a1 = 0.f;
  for (int n = n0; n < n0 + 128; n += 2) {
    a0 = fmaf(w[b * Nn + n],     hn[((size_t)(b * Nn + n))     * Dd + d], a0);
    a1 = fmaf(w[b * Nn + n + 1], hn[((size_t)(b * Nn + n + 1)) * Dd + d], a1);
  }
  part[((size_t)(b * 8 + ch)) * Dd + d] = a0 + a1;
}

// stage 2: sum 8 partials. grid (Dd/256, Bb), block 256.
__global__ __launch_bounds__(256) void pool_reduce2(const float* __restrict__ part, float* __restrict__ pooled) {
  int d = blockIdx.x * 256 + threadIdx.x;
  int b = blockIdx.y;
  float s = 0.f;
  #pragma unroll
  for (int ch = 0; ch < 8; ++ch) s += part[((size_t)(b * 8 + ch)) * Dd + d];
  pooled[b * Dd + d] = s;
}

// fc: one class per thread, coalesced over c. grid (4, Bb), block 256.
__global__ __launch_bounds__(256) void fc_kernel(const float* __restrict__ pooled, const float* __restrict__ fw,
                                                 const float* __restrict__ fb, float* __restrict__ out) {
  __shared__ float p[768];
  int b = blockIdx.y, tid = threadIdx.x;
  for (int j = 0; j < 3; ++j) p[tid + j * 256] = pooled[b * Dd + tid + j * 256];
  __syncthreads();
  int c = blockIdx.x * 256 + tid;
  if (c < NCc) {
    float a0 = 0.f, a1 = 0.f, a2 = 0.f, a3 = 0.f;
    #pragma unroll 4
    for (int d = 0; d < Dd; d += 4) {
      a0 = fmaf(p[d],     fw[(size_t)d       * NCc + c], a0);
      a1 = fmaf(p[d + 1], fw[(size_t)(d + 1) * NCc + c], a1);
      a2 = fmaf(p[d + 2], fw[(size_t)(d + 2) * NCc + c], a2);
      a3 = fmaf(p[d + 3], fw[(size_t)(d + 3) * NCc + c], a3);
    }
    out[b * NCc + c] = fb[c] + ((a0 + a1) + (a2 + a3));
  }
}

extern "C" void kernel_launch(void* const* d_in, const int* in_sizes, int n_in,
                              void* d_out, int out_size, void* d_ws, size_t ws_size,
                              hipStream_t stream) {
  const float* x      = (const float*)d_in[0];
  const void*  mask   = d_in[1];
  const float* pe     = (const float*)d_in[2];
  const float* ln0_w  = (const float*)d_in[3];
  const float* ln0_b  = (const float*)d_in[4];
  const float* qkv_w  = (const float*)d_in[5];
  const float* proj_w = (const float*)d_in[6];
  const float* proj_b = (const float*)d_in[7];
  const float* ln1_w  = (const float*)d_in[8];
  const float* ln1_b  = (const float*)d_in[9];
  const float* ff1_w  = (const float*)d_in[10];
  const float* ff1_b  = (const float*)d_in[11];
  const float* ff2_w  = (const float*)d_in[12];
  const float* ff2_b  = (const float*)d_in[13];
  const float* norm_w = (const float*)d_in[14];
  const float* norm_b = (const float*)d_in[15];
  const float* pool_w = (const float*)d_in[16];
  const float* pool_b = (const float*)d_in[17];
  const float* fc_w   = (const float*)d_in[18];
  const float* fc_b   = (const float*)d_in[19];
  float* out = (float*)d_out;

  // Compact workspace (~44 MB) — verified in round 5. Do NOT grow past this.
  float* ws = (float*)d_ws;
  float* h      = ws;                        // Mm*Dd
  float* y      = h + (long)Mm * Dd;         // Mm*Dd
  float* qkvf   = y + (long)Mm * Dd;         // Mm*3*Dd
  float* o      = qkvf + (long)Mm * 3 * Dd;  // Mm*Dd
  float* hn     = o + (long)Mm * Dd;         // Mm*Dd
  float* spool  = hn + (long)Mm * Dd;        // Mm
  float* wpool  = spool + Mm;                // Mm
  float* pooled = wpool + Mm;                // Bb*Dd
  float* ppart  = pooled + Bb * Dd;          // Bb*8*Dd
  int*   mflag  = (int*)(ppart + (long)Bb * 8 * Dd);
  float* po = y;      // alias: y dead after qkv gemm
  float* g  = qkvf;   // alias: ff1 out fits exactly in qkvf+o (dead after proj)

  detect_mask<<<1, 256, 0, stream>>>((const unsigned char*)mask, mflag);
  add_pe_k<<<(Mm * Dd) / 256, 256, 0, stream>>>(x, pe, h);

  for (int l = 0; l < NLl; ++l) {
    ln_kernel<<<Mm, 256, 0, stream>>>(h, nullptr, ln0_w + l * Dd, ln0_b + l * Dd, y);

    // qkv: (Mm x 768) @ (768 x 2304) -> qkvf
    gemm128<64,0><<<dim3(3 * Dd / 64, Mm / 128), 256, 0, stream>>>(
        y, Dd,
        qkv_w + (long)l * Dd * 3 * Dd, 3 * Dd,
        nullptr, nullptr,
        qkvf, 3 * Dd, Dd);

    // fused attention: o = softmax(mask(QK^T/8)) @ V   (MFMA flash)
    flash_attn_mfma<<<dim3(Nn / 64, Hh, Bb), 256, 0, stream>>>(qkvf, mask, mflag, o);

    // proj: o @ proj_w + b -> po (=y)
    gemm128<64,1><<<dim3(Dd / 64, Mm / 128), 256, 0, stream>>>(
        o, Dd,
        proj_w + (long)l * Dd * Dd, Dd,
        proj_b + l * Dd, nullptr,
        po, Dd, Dd);

    ln_kernel<<<Mm, 256, 0, stream>>>(h, po, ln1_w + l * Dd, ln1_b + l * Dd, h);

    // ff1: h @ ff1_w + b -> gelu -> g
    gemm128<64,2><<<dim3(FFf / 64, Mm / 128), 256, 0, stream>>>(
        h, Dd,
        ff1_w + (long)l * Dd * FFf, FFf,
        ff1_b + l * FFf, nullptr,
        g, FFf, Dd);

    // ff2: g @ ff2_w + b + h -> h
    gemm128<64,3><<<dim3(Dd / 64, Mm / 128), 256, 0, stream>>>(
        g, FFf,
        ff2_w + (long)l * FFf * Dd, Dd,
        ff2_b + l * Dd, h,
        h, Dd, FFf);
  }

  ln_kernel<<<Mm, 256, 0, stream>>>(h, nullptr, norm_w, norm_b, hn);
  pool_score<<<Mm, 256, 0, stream>>>(hn, pool_w, pool_b, spool);
  pool_softmax<<<Bb, 256, 0, stream>>>(spool, wpool);
  pool_reduce1<<<dim3(Dd / 256, 8, Bb), 256, 0, stream>>>(hn, wpool, ppart);
  pool_reduce2<<<dim3(Dd / 256, Bb), 256, 0, stream>>>(ppart, pooled);
  fc_kernel<<<dim3(4, Bb), 256, 0, stream>>>(pooled, fc_w, fc_b, out);
}

// Round 10
// 3224.434 us; speedup vs baseline: 13.2652x; 1.1723x over previous
//
#include <hip/hip_runtime.h>
#include <hip/hip_bf16.h>
#include <cfloat>
#include <cmath>

typedef __bf16 bf16x8 __attribute__((ext_vector_type(8)));
typedef float  f32x4  __attribute__((ext_vector_type(4)));

static constexpr int Bb = 2, Nn = 1024, Dd = 768, Hh = 12, HDd = 64, FFf = 3072, NLl = 12, NCc = 1000;
static constexpr int Mm = Bb * Nn; // 2048
static constexpr float NEGF = -3.402823466e38f;

// ---------- reductions (256-thread blocks = 4 waves) ----------
__device__ __forceinline__ float block_reduce_sum(float v, volatile float* smem) {
  for (int o = 32; o; o >>= 1) v += __shfl_down(v, o);
  int lane = threadIdx.x & 63, w = threadIdx.x >> 6;
  __syncthreads();
  if (lane == 0) smem[w] = v;
  __syncthreads();
  return smem[0] + smem[1] + smem[2] + smem[3];
}

__device__ __forceinline__ float block_reduce_max(float v, volatile float* smem) {
  for (int o = 32; o; o >>= 1) v = fmaxf(v, __shfl_down(v, o));
  int lane = threadIdx.x & 63, w = threadIdx.x >> 6;
  __syncthreads();
  if (lane == 0) smem[w] = v;
  __syncthreads();
  return fmaxf(fmaxf(smem[0], smem[1]), fmaxf(smem[2], smem[3]));
}

// ---------- mask dtype detection: 0=int32 1=bytes 2=f32 3=int64 4=bf16 ----------
__global__ void detect_mask(const unsigned char* __restrict__ m, int* __restrict__ flag) {
  __shared__ int s_nz1, s_nz2, s_nz3, s_nz84, s_pv;
  int tid = threadIdx.x;
  if (tid == 0) { s_nz1 = 0; s_nz2 = 0; s_nz3 = 0; s_nz84 = 0; s_pv = 0; }
  __syncthreads();
  int nz1 = 0, nz2 = 0, nz3 = 0, nz84 = 0, pv = 0;
  for (int i = tid; i < 2048; i += 256) {
    unsigned char v = m[i];
    if (v) {
      int p4 = i & 3;
      if (p4 == 1) nz1 = 1;
      if (p4 == 2) nz2 = 1;
      if (p4 == 3) nz3 = 1;
      if ((i & 7) == 4) nz84 = 1;
      if ((i & 1) == 0) { if (v != 0x80) pv = 1; }
      else              { if (v != 0x3f) pv = 1; }
    }
  }
  if (nz1)  atomicOr(&s_nz1, 1);
  if (nz2)  atomicOr(&s_nz2, 1);
  if (nz3)  atomicOr(&s_nz3, 1);
  if (nz84) atomicOr(&s_nz84, 1);
  if (pv)   atomicOr(&s_pv, 1);
  __syncthreads();
  if (tid == 0) {
    int f;
    if (!s_nz1 && !s_nz2 && !s_nz3) f = s_nz84 ? 0 : 3;
    else if (!s_pv)                 f = s_nz1 ? 4 : 2;
    else                            f = 1;
    *flag = f;
  }
}

__device__ __forceinline__ bool mask_at(const void* mraw, int flag, int idx) {
  switch (flag) {
    case 0:  return ((const int*)mraw)[idx] != 0;
    case 1:  return ((const unsigned char*)mraw)[idx] != 0;
    case 2:  return ((const float*)mraw)[idx] != 0.f;
    case 3:  return ((const long long*)mraw)[idx] != 0;
    default: return ((const unsigned short*)mraw)[idx] != 0;
  }
}

// ---------- h = x + pe (pe broadcast over batch) ----------
__global__ __launch_bounds__(256) void add_pe_k(const float* __restrict__ x, const float* __restrict__ pe,
                                                float* __restrict__ h) {
  long i = (long)blockIdx.x * 256 + threadIdx.x;
  long nd = i % ((long)Nn * Dd);
  h[i] = x[i] + pe[nd];
}

// ---------- LayerNorm (optionally with residual input added first), row = 768 ----------
__global__ __launch_bounds__(256) void ln_kernel(const float* __restrict__ X, const float* __restrict__ R,
                                                 const float* __restrict__ w, const float* __restrict__ b,
                                                 float* __restrict__ Y) {
  __shared__ float smem[4];
  int row = blockIdx.x, tid = threadIdx.x;
  const float* x = X + (size_t)row * Dd;
  const bool hasR = (R != nullptr);
  const float* r = hasR ? R + (size_t)row * Dd : nullptr;
  float v[3];
  for (int j = 0; j < 3; ++j) {
    int c = tid + j * 256;
    v[j] = x[c] + (hasR ? r[c] : 0.f);
  }
  float s = v[0] + v[1] + v[2];
  s = block_reduce_sum(s, smem);
  float mean = s * (1.f / 768.f);
  float q = 0.f;
  for (int j = 0; j < 3; ++j) { float d = v[j] - mean; q += d * d; }
  q = block_reduce_sum(q, smem);
  float inv = rsqrtf(q * (1.f / 768.f) + 1e-5f);
  for (int j = 0; j < 3; ++j) {
    int c = tid + j * 256;
    Y[(size_t)row * Dd + c] = (v[j] - mean) * inv * w[c] + b[c];
  }
}

// ---------- LayerNorm over (h + part0 + part1 + bias): fuses proj split-K reduction ----------
__global__ __launch_bounds__(256) void ln2res_kernel(const float* __restrict__ X,
                                                     const float* __restrict__ P0, const float* __restrict__ P1,
                                                     const float* __restrict__ pb,
                                                     const float* __restrict__ w, const float* __restrict__ b,
                                                     float* __restrict__ Y) {
  __shared__ float smem[4];
  int row = blockIdx.x, tid = threadIdx.x;
  const float* x  = X  + (size_t)row * Dd;
  const float* p0 = P0 + (size_t)row * Dd;
  const float* p1 = P1 + (size_t)row * Dd;
  float v[3];
  for (int j = 0; j < 3; ++j) {
    int c = tid + j * 256;
    v[j] = x[c] + (p0[c] + p1[c] + pb[c]);
  }
  float s = v[0] + v[1] + v[2];
  s = block_reduce_sum(s, smem);
  float mean = s * (1.f / 768.f);
  float q = 0.f;
  for (int j = 0; j < 3; ++j) { float d = v[j] - mean; q += d * d; }
  q = block_reduce_sum(q, smem);
  float inv = rsqrtf(q * (1.f / 768.f) + 1e-5f);
  for (int j = 0; j < 3; ++j) {
    int c = tid + j * 256;
    Y[(size_t)row * Dd + c] = (v[j] - mean) * inv * w[c] + b[c];
  }
}

// ---------- ff2 split-K reduction: h += p0 + p1 + bias (float4) ----------
__global__ __launch_bounds__(256) void reduce_ff2(float* __restrict__ h, const float* __restrict__ p0,
                                                  const float* __restrict__ p1, const float* __restrict__ bias) {
  long i4 = (long)blockIdx.x * 256 + threadIdx.x;
  int col4 = (int)(i4 % (Dd / 4));
  float4 hv = reinterpret_cast<const float4*>(h)[i4];
  float4 a  = reinterpret_cast<const float4*>(p0)[i4];
  float4 c  = reinterpret_cast<const float4*>(p1)[i4];
  float4 bb = reinterpret_cast<const float4*>(bias)[col4];
  hv.x += a.x + c.x + bb.x;
  hv.y += a.y + c.y + bb.y;
  hv.z += a.z + c.z + bb.z;
  hv.w += a.w + c.w + bb.w;
  reinterpret_cast<float4*>(h)[i4] = hv;
}

// ---------- split helpers: f32 -> bf16 hi + bf16 lo ----------
__device__ __forceinline__ void split8(const float* __restrict__ a, bf16x8& hi, bf16x8& lo) {
  float4 f0 = *reinterpret_cast<const float4*>(a);
  float4 f1 = *reinterpret_cast<const float4*>(a + 4);
  float v[8] = {f0.x, f0.y, f0.z, f0.w, f1.x, f1.y, f1.z, f1.w};
  for (int j = 0; j < 8; ++j) {
    __bf16 h = (__bf16)v[j];
    hi[j] = h;
    lo[j] = (__bf16)(v[j] - (float)h);
  }
}

__device__ __forceinline__ void split8v(const float* __restrict__ v, bf16x8& hi, bf16x8& lo) {
  for (int j = 0; j < 8; ++j) {
    __bf16 h = (__bf16)v[j];
    hi[j] = h;
    lo[j] = (__bf16)(v[j] - (float)h);
  }
}

// ---------- 128xBN split-precision MFMA GEMM, register prefetch pipeline, optional split-K ----------
// Per z-chunk: C_z = A[:, zK:zK+K] * B[zK:zK+K, :]; partial z written to Cp + z*czs.
// EPI: 0 none, 1 +bias, 2 +bias->exact gelu, 3 +bias +resid.   grid: (Nsz/BN, Msz/128, nchunks).
template<int BN, int EPI>
__global__ __launch_bounds__(256) void gemm128(
    const float* __restrict__ Ap, long lda,
    const float* __restrict__ Bp, long ldb,
    const float* __restrict__ bias, const float* __restrict__ resid,
    float* __restrict__ Cp, long ldc,
    int Ksize, long czs)
{
  constexpr int FN = BN / 32;      // B fragments per wave
  constexpr int KB = BN / 8;       // B elements staged per thread
  int tid = threadIdx.x;
  int m0 = blockIdx.y * 128, n0 = blockIdx.x * BN;
  int z = blockIdx.z;

  const float* Aq = Ap + (long)z * Ksize;
  const float* Bq = Bp + (long)z * Ksize * ldb;
  float* Cq = Cp + (long)z * czs;

  __shared__ __align__(16) __bf16 Ah[128][40], Al[128][40];
  __shared__ __align__(16) __bf16 Bh[BN][40],  Bl[BN][40];

  f32x4 acc[4][FN];
  #pragma unroll
  for (int i = 0; i < 4; ++i)
    #pragma unroll
    for (int j = 0; j < FN; ++j)
      #pragma unroll
      for (int k = 0; k < 4; ++k) acc[i][j][k] = 0.f;

  int lane = tid & 63;
  int w = tid >> 6;
  int WR = (w >> 1) * 64, WC = (w & 1) * (BN / 2);
  int fr = lane & 15, kg = lane >> 4;

  const int ar = tid >> 1, acs = (tid & 1) * 16;  // A: row ar, 16 consecutive k
  const int bn = tid % BN;                         // B: col n0+bn (lane-coalesced)
  const int kb = (tid / BN) * KB;                  //    KB consecutive k rows

  const float* Abase = Aq + (long)(m0 + ar) * lda + acs;
  const float* Bbase = Bq + (long)kb * ldb + (n0 + bn);

  float pa[16], pb[KB];
  {
    const float* As = Abase;
    *reinterpret_cast<float4*>(&pa[0])  = *reinterpret_cast<const float4*>(As);
    *reinterpret_cast<float4*>(&pa[4])  = *reinterpret_cast<const float4*>(As + 4);
    *reinterpret_cast<float4*>(&pa[8])  = *reinterpret_cast<const float4*>(As + 8);
    *reinterpret_cast<float4*>(&pa[12]) = *reinterpret_cast<const float4*>(As + 12);
    #pragma unroll
    for (int j = 0; j < KB; ++j) pb[j] = Bbase[(long)j * ldb];
  }

  for (int k0 = 0; k0 < Ksize; k0 += 32) {
    __syncthreads();  // previous tile's MFMA reads complete
    { // convert + write LDS from registers (tile k0)
      bf16x8 th, tl;
      split8v(&pa[0], th, tl);
      *reinterpret_cast<bf16x8*>(&Ah[ar][acs]) = th;
      *reinterpret_cast<bf16x8*>(&Al[ar][acs]) = tl;
      split8v(&pa[8], th, tl);
      *reinterpret_cast<bf16x8*>(&Ah[ar][acs + 8]) = th;
      *reinterpret_cast<bf16x8*>(&Al[ar][acs + 8]) = tl;
      #pragma unroll
      for (int g8 = 0; g8 < KB / 8; ++g8) {
        bf16x8 bth, btl;
        split8v(&pb[g8 * 8], bth, btl);
        *reinterpret_cast<bf16x8*>(&Bh[bn][kb + g8 * 8]) = bth;
        *reinterpret_cast<bf16x8*>(&Bl[bn][kb + g8 * 8]) = btl;
      }
    }
    __syncthreads();  // LDS tile ready

    if (k0 + 32 < Ksize) { // issue next tile's loads; in flight during MFMA phase
      const float* As = Abase + (k0 + 32);
      *reinterpret_cast<float4*>(&pa[0])  = *reinterpret_cast<const float4*>(As);
      *reinterpret_cast<float4*>(&pa[4])  = *reinterpret_cast<const float4*>(As + 4);
      *reinterpret_cast<float4*>(&pa[8])  = *reinterpret_cast<const float4*>(As + 8);
      *reinterpret_cast<float4*>(&pa[12]) = *reinterpret_cast<const float4*>(As + 12);
      const float* Bs = Bbase + (long)(k0 + 32) * ldb;
      #pragma unroll
      for (int j = 0; j < KB; ++j) pb[j] = Bs[(long)j * ldb];
    }

    bf16x8 ah[4], al[4], bh[FN], bl[FN];
    #pragma unroll
    for (int fm = 0; fm < 4; ++fm) {
      ah[fm] = *reinterpret_cast<const bf16x8*>(&Ah[WR + fm * 16 + fr][kg * 8]);
      al[fm] = *reinterpret_cast<const bf16x8*>(&Al[WR + fm * 16 + fr][kg * 8]);
    }
    #pragma unroll
    for (int fn = 0; fn < FN; ++fn) {
      bh[fn] = *reinterpret_cast<const bf16x8*>(&Bh[WC + fn * 16 + fr][kg * 8]);
      bl[fn] = *reinterpret_cast<const bf16x8*>(&Bl[WC + fn * 16 + fr][kg * 8]);
    }
    #pragma unroll
    for (int fm = 0; fm < 4; ++fm)
      #pragma unroll
      for (int fn = 0; fn < FN; ++fn) {
        acc[fm][fn] = __builtin_amdgcn_mfma_f32_16x16x32_bf16(ah[fm], bh[fn], acc[fm][fn], 0, 0, 0);
        acc[fm][fn] = __builtin_amdgcn_mfma_f32_16x16x32_bf16(al[fm], bh[fn], acc[fm][fn], 0, 0, 0);
        acc[fm][fn] = __builtin_amdgcn_mfma_f32_16x16x32_bf16(ah[fm], bl[fn], acc[fm][fn], 0, 0, 0);
      }
  }

  #pragma unroll
  for (int fm = 0; fm < 4; ++fm)
    #pragma unroll
    for (int fn = 0; fn < FN; ++fn)
      #pragma unroll
      for (int i = 0; i < 4; ++i) {
        int rowg = m0 + WR + fm * 16 + kg * 4 + i;
        int coln = n0 + WC + fn * 16 + fr;
        float v = acc[fm][fn][i];
        if (EPI >= 1) v += bias[coln];
        if (EPI == 2) v = 0.5f * v * (1.f + erff(v * 0.70710678118654752f));
        if (EPI == 3) v += resid[(long)rowg * ldc + coln];
        Cq[(long)rowg * ldc + coln] = v;
      }
}

// ---------- MFMA flash attention (verified round 7) ----------
__global__ __launch_bounds__(256) void flash_attn_mfma(const float* __restrict__ qkvf,
                                                       const void* __restrict__ mraw,
                                                       const int* __restrict__ flagp,
                                                       float* __restrict__ o) {
  __shared__ __align__(16) __bf16 Qh[64][72], Ql[64][72];
  __shared__ __align__(16) __bf16 Kh[64][72], Kl[64][72];
  __shared__ __align__(16) __bf16 Vth[64][66], Vtl[64][66];  // V transposed: [d][key]
  __shared__ __align__(16) __bf16 Ph[64][72], Pl[64][72];
  __shared__ float kmf[64];
  __shared__ float qmf[64];

  int b = blockIdx.z, hh = blockIdx.y;
  int q0 = blockIdx.x * 64;
  int tid = threadIdx.x, lane = tid & 63, w = tid >> 6;
  int flag = *flagp;
  int fr = lane & 15, kg = lane >> 4;

  const int sr = tid >> 2;
  const int sc = (tid & 3) * 16;

  {
    const float* Qsrc = qkvf + ((long)(b * Nn + q0 + sr)) * (3 * Dd) + hh * HDd + sc;
    bf16x8 th, tl;
    split8(Qsrc, th, tl);
    *reinterpret_cast<bf16x8*>(&Qh[sr][sc]) = th;
    *reinterpret_cast<bf16x8*>(&Ql[sr][sc]) = tl;
    split8(Qsrc + 8, th, tl);
    *reinterpret_cast<bf16x8*>(&Qh[sr][sc + 8]) = th;
    *reinterpret_cast<bf16x8*>(&Ql[sr][sc + 8]) = tl;
    if (tid < 64) qmf[tid] = mask_at(mraw, flag, b * Nn + q0 + tid) ? 1.f : 0.f;
  }
  __syncthreads();

  float qm[4];
  #pragma unroll
  for (int i = 0; i < 4; ++i) qm[i] = qmf[16 * w + kg * 4 + i];

  bf16x8 qah[2], qal[2];
  #pragma unroll
  for (int ks = 0; ks < 2; ++ks) {
    qah[ks] = *reinterpret_cast<const bf16x8*>(&Qh[16 * w + fr][ks * 32 + kg * 8]);
    qal[ks] = *reinterpret_cast<const bf16x8*>(&Ql[16 * w + fr][ks * 32 + kg * 8]);
  }

  float mrow[4], lrow[4];
  f32x4 accO[4];
  #pragma unroll
  for (int i = 0; i < 4; ++i) { mrow[i] = -INFINITY; lrow[i] = 0.f; }
  #pragma unroll
  for (int t = 0; t < 4; ++t)
    for (int i = 0; i < 4; ++i) accO[t][i] = 0.f;

  for (int j0 = 0; j0 < Nn; j0 += 64) {
    __syncthreads();
    {
      const float* Ksrc = qkvf + ((long)(b * Nn + j0 + sr)) * (3 * Dd) + Dd + hh * HDd + sc;
      const float* Vsrc = Ksrc + Dd;
      bf16x8 th, tl;
      split8(Ksrc, th, tl);
      *reinterpret_cast<bf16x8*>(&Kh[sr][sc]) = th;
      *reinterpret_cast<bf16x8*>(&Kl[sr][sc]) = tl;
      split8(Ksrc + 8, th, tl);
      *reinterpret_cast<bf16x8*>(&Kh[sr][sc + 8]) = th;
      *reinterpret_cast<bf16x8*>(&Kl[sr][sc + 8]) = tl;
      #pragma unroll
      for (int j = 0; j < 16; ++j) {
        float vv = Vsrc[j];
        __bf16 vh = (__bf16)vv;
        Vth[sc + j][sr] = vh;
        Vtl[sc + j][sr] = (__bf16)(vv - (float)vh);
      }
      if (tid < 64) kmf[tid] = mask_at(mraw, flag, b * Nn + j0 + tid) ? 1.f : 0.f;
    }
    __syncthreads();

    f32x4 sacc[4];
    #pragma unroll
    for (int t = 0; t < 4; ++t)
      for (int i = 0; i < 4; ++i) sacc[t][i] = 0.f;
    #pragma unroll
    for (int ks = 0; ks < 2; ++ks) {
      #pragma unroll
      for (int t = 0; t < 4; ++t) {
        bf16x8 bh = *reinterpret_cast<const bf16x8*>(&Kh[16 * t + fr][ks * 32 + kg * 8]);
        bf16x8 bl = *reinterpret_cast<const bf16x8*>(&Kl[16 * t + fr][ks * 32 + kg * 8]);
        sacc[t] = __builtin_amdgcn_mfma_f32_16x16x32_bf16(qah[ks], bh, sacc[t], 0, 0, 0);
        sacc[t] = __builtin_amdgcn_mfma_f32_16x16x32_bf16(qal[ks], bh, sacc[t], 0, 0, 0);
        sacc[t] = __builtin_amdgcn_mfma_f32_16x16x32_bf16(qah[ks], bl, sacc[t], 0, 0, 0);
      }
    }

    float sv[4][4];
    float mt[4] = {-INFINITY, -INFINITY, -INFINITY, -INFINITY};
    #pragma unroll
    for (int t = 0; t < 4; ++t) {
      float km = kmf[16 * t + fr];
      #pragma unroll
      for (int i = 0; i < 4; ++i) {
        float s = (km > 0.f && qm[i] > 0.f) ? sacc[t][i] * 0.125f : NEGF;
        sv[t][i] = s;
        mt[i] = fmaxf(mt[i], s);
      }
    }
    #pragma unroll
    for (int off = 8; off; off >>= 1)
      #pragma unroll
      for (int i = 0; i < 4; ++i) mt[i] = fmaxf(mt[i], __shfl_xor(mt[i], off));

    float r[4], psum[4];
    #pragma unroll
    for (int i = 0; i < 4; ++i) {
      float mn = fmaxf(mrow[i], mt[i]);
      r[i] = expf(mrow[i] - mn);
      mrow[i] = mn;
      psum[i] = 0.f;
    }
    #pragma unroll
    for (int t = 0; t < 4; ++t) {
      #pragma unroll
      for (int i = 0; i < 4; ++i) {
        float p = expf(sv[t][i] - mrow[i]);
        psum[i] += p;
        __bf16 ph = (__bf16)p;
        Ph[16 * w + kg * 4 + i][16 * t + fr] = ph;
        Pl[16 * w + kg * 4 + i][16 * t + fr] = (__bf16)(p - (float)ph);
      }
    }
    #pragma unroll
    for (int off = 8; off; off >>= 1)
      #pragma unroll
      for (int i = 0; i < 4; ++i) psum[i] += __shfl_xor(psum[i], off);
    #pragma unroll
    for (int i = 0; i < 4; ++i) lrow[i] = lrow[i] * r[i] + psum[i];
    #pragma unroll
    for (int t = 0; t < 4; ++t)
      #pragma unroll
      for (int i = 0; i < 4; ++i) accO[t][i] *= r[i];

    __syncthreads();

    #pragma unroll
    for (int ks = 0; ks < 2; ++ks) {
      bf16x8 pah = *reinterpret_cast<const bf16x8*>(&Ph[16 * w + fr][ks * 32 + kg * 8]);
      bf16x8 pal = *reinterpret_cast<const bf16x8*>(&Pl[16 * w + fr][ks * 32 + kg * 8]);
      #pragma unroll
      for (int t2 = 0; t2 < 4; ++t2) {
        bf16x8 vbh = *reinterpret_cast<const bf16x8*>(&Vth[16 * t2 + fr][ks * 32 + kg * 8]);
        bf16x8 vbl = *reinterpret_cast<const bf16x8*>(&Vtl[16 * t2 + fr][ks * 32 + kg * 8]);
        accO[t2] = __builtin_amdgcn_mfma_f32_16x16x32_bf16(pah, vbh, accO[t2], 0, 0, 0);
        accO[t2] = __builtin_amdgcn_mfma_f32_16x16x32_bf16(pal, vbh, accO[t2], 0, 0, 0);
        accO[t2] = __builtin_amdgcn_mfma_f32_16x16x32_bf16(pah, vbl, accO[t2], 0, 0, 0);
      }
    }
  }

  #pragma unroll
  for (int t2 = 0; t2 < 4; ++t2)
    #pragma unroll
    for (int i = 0; i < 4; ++i) {
      int qrow = q0 + 16 * w + kg * 4 + i;
      int col = 16 * t2 + fr;
      o[((long)(b * Nn + qrow)) * Dd + hh * HDd + col] = accO[t2][i] / lrow[i];
    }
}

// ---------- seq-pool ----------
__global__ __launch_bounds__(256) void pool_score(const float* __restrict__ hn, const float* __restrict__ pw,
                                                  const float* __restrict__ pb, float* __restrict__ s) {
  __shared__ float smem[4];
  int row = blockIdx.x, tid = threadIdx.x;
  const float* x = hn + (size_t)row * Dd;
  float acc = 0.f;
  for (int j = 0; j < 3; ++j) { int c = tid + j * 256; acc += x[c] * pw[c]; }
  acc = block_reduce_sum(acc, smem);
  if (tid == 0) s[row] = acc + pb[0];
}

__global__ __launch_bounds__(256) void pool_softmax(const float* __restrict__ s, float* __restrict__ w) {
  __shared__ float smem[4];
  int b = blockIdx.x, tid = threadIdx.x;
  const float* x = s + b * Nn;
  float v[4];
  for (int j = 0; j < 4; ++j) v[j] = x[tid * 4 + j];
  float mx = fmaxf(fmaxf(v[0], v[1]), fmaxf(v[2], v[3]));
  mx = block_reduce_max(mx, smem);
  float e[4], sum = 0.f;
  for (int j = 0; j < 4; ++j) { e[j] = expf(v[j] - mx); sum += e[j]; }
  sum = block_reduce_sum(sum, smem);
  float inv = 1.f / sum;
  for (int j = 0; j < 4; ++j) w[b * Nn + tid * 4 + j] = e[j] * inv;
}

// stage 1: partial sums over 128-token chunks. grid (Dd/256, 8, Bb), block 256.
__global__ __launch_bounds__(256) void pool_reduce1(const float* __restrict__ hn, const float* __restrict__ w,
                                                    float* __restrict__ part) {
  int d = blockIdx.x * 256 + threadIdx.x;
  int ch = blockIdx.y, b = blockIdx.z;
  int n0 = ch * 128;
  float a0 = 0.f, a1 = 0.f;
  for (int n = n0; n < n0 + 128; n += 2) {
    a0 = fmaf(w[b * Nn + n],     hn[((size_t)(b * Nn + n))     * Dd + d], a0);
    a1 = fmaf(w[b * Nn + n + 1], hn[((size_t)(b * Nn + n + 1)) * Dd + d], a1);
  }
  part[((size_t)(b * 8 + ch)) * Dd + d] = a0 + a1;
}

// stage 2: sum 8 partials. grid (Dd/256, Bb), block 256.
__global__ __launch_bounds__(256) void pool_reduce2(const float* __restrict__ part, float* __restrict__ pooled) {
  int d = blockIdx.x * 256 + threadIdx.x;
  int b = blockIdx.y;
  float s = 0.f;
  #pragma unroll
  for (int ch = 0; ch < 8; ++ch) s += part[((size_t)(b * 8 + ch)) * Dd + d];
  pooled[b * Dd + d] = s;
}

// fc: one class per thread, coalesced over c. grid (4, Bb), block 256.
__global__ __launch_bounds__(256) void fc_kernel(const float* __restrict__ pooled, const float* __restrict__ fw,
                                                 const float* __restrict__ fb, float* __restrict__ out) {
  __shared__ float p[768];
  int b = blockIdx.y, tid = threadIdx.x;
  for (int j = 0; j < 3; ++j) p[tid + j * 256] = pooled[b * Dd + tid + j * 256];
  __syncthreads();
  int c = blockIdx.x * 256 + tid;
  if (c < NCc) {
    float a0 = 0.f, a1 = 0.f, a2 = 0.f, a3 = 0.f;
    #pragma unroll 4
    for (int d = 0; d < Dd; d += 4) {
      a0 = fmaf(p[d],     fw[(size_t)d       * NCc + c], a0);
      a1 = fmaf(p[d + 1], fw[(size_t)(d + 1) * NCc + c], a1);
      a2 = fmaf(p[d + 2], fw[(size_t)(d + 2) * NCc + c], a2);
      a3 = fmaf(p[d + 3], fw[(size_t)(d + 3) * NCc + c], a3);
    }
    out[b * NCc + c] = fb[c] + ((a0 + a1) + (a2 + a3));
  }
}

extern "C" void kernel_launch(void* const* d_in, const int* in_sizes, int n_in,
                              void* d_out, int out_size, void* d_ws, size_t ws_size,
                              hipStream_t stream) {
  const float* x      = (const float*)d_in[0];
  const void*  mask   = d_in[1];
  const float* pe     = (const float*)d_in[2];
  const float* ln0_w  = (const float*)d_in[3];
  const float* ln0_b  = (const float*)d_in[4];
  const float* qkv_w  = (const float*)d_in[5];
  const float* proj_w = (const float*)d_in[6];
  const float* proj_b = (const float*)d_in[7];
  const float* ln1_w  = (const float*)d_in[8];
  const float* ln1_b  = (const float*)d_in[9];
  const float* ff1_w  = (const float*)d_in[10];
  const float* ff1_b  = (const float*)d_in[11];
  const float* ff2_w  = (const float*)d_in[12];
  const float* ff2_b  = (const float*)d_in[13];
  const float* norm_w = (const float*)d_in[14];
  const float* norm_b = (const float*)d_in[15];
  const float* pool_w = (const float*)d_in[16];
  const float* pool_b = (const float*)d_in[17];
  const float* fc_w   = (const float*)d_in[18];
  const float* fc_b   = (const float*)d_in[19];
  float* out = (float*)d_out;

  // Compact workspace (~44 MB) — verified in round 5. Do NOT grow past this.
  // Layout (units of Mm*Dd): h=0, y=1, qkvf=2..4, o=5, hn=6, +small tails.
  float* ws = (float*)d_ws;
  float* h      = ws;                        // Mm*Dd
  float* y      = h + (long)Mm * Dd;         // Mm*Dd
  float* qkvf   = y + (long)Mm * Dd;         // Mm*3*Dd
  float* o      = qkvf + (long)Mm * 3 * Dd;  // Mm*Dd
  float* hn     = o + (long)Mm * Dd;         // Mm*Dd
  float* spool  = hn + (long)Mm * Dd;        // Mm
  float* wpool  = spool + Mm;                // Mm
  float* pooled = wpool + Mm;                // Bb*Dd
  float* ppart  = pooled + Bb * Dd;          // Bb*8*Dd
  int*   mflag  = (int*)(ppart + (long)Bb * 8 * Dd);
  float* g  = qkvf;   // alias: ff1 out (25.2 MB) spans qkvf+o (both dead after flash/proj reads)
  // split-K partials (dead buffers at those points in the dataflow):
  //   proj: part0 = hn, part1 = qkvf        (qkvf dead after flash_attn)
  //   ff2:  part0 = y,  part1 = hn          (y dead after qkv gemm; hn dead after ln2res)

  detect_mask<<<1, 256, 0, stream>>>((const unsigned char*)mask, mflag);
  add_pe_k<<<(Mm * Dd) / 256, 256, 0, stream>>>(x, pe, h);

  for (int l = 0; l < NLl; ++l) {
    ln_kernel<<<Mm, 256, 0, stream>>>(h, nullptr, ln0_w + l * Dd, ln0_b + l * Dd, y);

    // qkv: (Mm x 768) @ (768 x 2304) -> qkvf
    gemm128<64,0><<<dim3(3 * Dd / 64, Mm / 128, 1), 256, 0, stream>>>(
        y, Dd,
        qkv_w + (long)l * Dd * 3 * Dd, 3 * Dd,
        nullptr, nullptr,
        qkvf, 3 * Dd, Dd, 0);

    // fused attention: o = softmax(mask(QK^T/8)) @ V   (MFMA flash)
    flash_attn_mfma<<<dim3(Nn / 64, Hh, Bb), 256, 0, stream>>>(qkvf, mask, mflag, o);

    // proj split-K x2: partials -> hn (z=0), qkvf (z=1); K chunk = 384
    gemm128<64,0><<<dim3(Dd / 64, Mm / 128, 2), 256, 0, stream>>>(
        o, Dd,
        proj_w + (long)l * Dd * Dd, Dd,
        nullptr, nullptr,
        hn, Dd, Dd / 2, (long)(qkvf - hn));

    // ln1 fused with proj reduction: h = LN(h + hn + qkvf + proj_b)
    ln2res_kernel<<<Mm, 256, 0, stream>>>(h, hn, qkvf, proj_b + l * Dd,
                                          ln1_w + l * Dd, ln1_b + l * Dd, h);

    // ff1: h @ ff1_w + b -> gelu -> g
    gemm128<64,2><<<dim3(FFf / 64, Mm / 128, 1), 256, 0, stream>>>(
        h, Dd,
        ff1_w + (long)l * Dd * FFf, FFf,
        ff1_b + l * FFf, nullptr,
        g, FFf, Dd, 0);

    // ff2 split-K x2: partials -> y (z=0), hn (z=1); K chunk = 1536
    gemm128<64,0><<<dim3(Dd / 64, Mm / 128, 2), 256, 0, stream>>>(
        g, FFf,
        ff2_w + (long)l * FFf * Dd, Dd,
        nullptr, nullptr,
        y, Dd, FFf / 2, (long)(hn - y));

    // h += y + hn + ff2_b
    reduce_ff2<<<(Mm * Dd / 4) / 256, 256, 0, stream>>>(h, y, hn, ff2_b + l * Dd);
  }

  ln_kernel<<<Mm, 256, 0, stream>>>(h, nullptr, norm_w, norm_b, hn);
  pool_score<<<Mm, 256, 0, stream>>>(hn, pool_w, pool_b, spool);
  pool_softmax<<<Bb, 256, 0, stream>>>(spool, wpool);
  pool_reduce1<<<dim3(Dd / 256, 8, Bb), 256, 0, stream>>>(hn, wpool, ppart);
  pool_reduce2<<<dim3(Dd / 256, Bb), 256, 0, stream>>>(ppart, pooled);
  fc_kernel<<<dim3(4, Bb), 256, 0, stream>>>(pooled, fc_w, fc_b, out);
}

// Round 11
// 2965.891 us; speedup vs baseline: 14.4215x; 1.0872x over previous
//
#include <hip/hip_runtime.h>
#include <hip/hip_bf16.h>
#include <cfloat>
#include <cmath>

typedef __bf16 bf16x8 __attribute__((ext_vector_type(8)));
typedef float  f32x4  __attribute__((ext_vector_type(4)));

static constexpr int Bb = 2, Nn = 1024, Dd = 768, Hh = 12, HDd = 64, FFf = 3072, NLl = 12, NCc = 1000;
static constexpr int Mm = Bb * Nn; // 2048
static constexpr float NEGF = -3.402823466e38f;

// ---------- reductions (256-thread blocks = 4 waves) ----------
__device__ __forceinline__ float block_reduce_sum(float v, volatile float* smem) {
  for (int o = 32; o; o >>= 1) v += __shfl_down(v, o);
  int lane = threadIdx.x & 63, w = threadIdx.x >> 6;
  __syncthreads();
  if (lane == 0) smem[w] = v;
  __syncthreads();
  return smem[0] + smem[1] + smem[2] + smem[3];
}

__device__ __forceinline__ float block_reduce_max(float v, volatile float* smem) {
  for (int o = 32; o; o >>= 1) v = fmaxf(v, __shfl_down(v, o));
  int lane = threadIdx.x & 63, w = threadIdx.x >> 6;
  __syncthreads();
  if (lane == 0) smem[w] = v;
  __syncthreads();
  return fmaxf(fmaxf(smem[0], smem[1]), fmaxf(smem[2], smem[3]));
}

// ---------- mask dtype detection: 0=int32 1=bytes 2=f32 3=int64 4=bf16 ----------
__global__ void detect_mask(const unsigned char* __restrict__ m, int* __restrict__ flag) {
  __shared__ int s_nz1, s_nz2, s_nz3, s_nz84, s_pv;
  int tid = threadIdx.x;
  if (tid == 0) { s_nz1 = 0; s_nz2 = 0; s_nz3 = 0; s_nz84 = 0; s_pv = 0; }
  __syncthreads();
  int nz1 = 0, nz2 = 0, nz3 = 0, nz84 = 0, pv = 0;
  for (int i = tid; i < 2048; i += 256) {
    unsigned char v = m[i];
    if (v) {
      int p4 = i & 3;
      if (p4 == 1) nz1 = 1;
      if (p4 == 2) nz2 = 1;
      if (p4 == 3) nz3 = 1;
      if ((i & 7) == 4) nz84 = 1;
      if ((i & 1) == 0) { if (v != 0x80) pv = 1; }
      else              { if (v != 0x3f) pv = 1; }
    }
  }
  if (nz1)  atomicOr(&s_nz1, 1);
  if (nz2)  atomicOr(&s_nz2, 1);
  if (nz3)  atomicOr(&s_nz3, 1);
  if (nz84) atomicOr(&s_nz84, 1);
  if (pv)   atomicOr(&s_pv, 1);
  __syncthreads();
  if (tid == 0) {
    int f;
    if (!s_nz1 && !s_nz2 && !s_nz3) f = s_nz84 ? 0 : 3;
    else if (!s_pv)                 f = s_nz1 ? 4 : 2;
    else                            f = 1;
    *flag = f;
  }
}

__device__ __forceinline__ bool mask_at(const void* mraw, int flag, int idx) {
  switch (flag) {
    case 0:  return ((const int*)mraw)[idx] != 0;
    case 1:  return ((const unsigned char*)mraw)[idx] != 0;
    case 2:  return ((const float*)mraw)[idx] != 0.f;
    case 3:  return ((const long long*)mraw)[idx] != 0;
    default: return ((const unsigned short*)mraw)[idx] != 0;
  }
}

// ---------- h = x + pe (pe broadcast over batch) ----------
__global__ __launch_bounds__(256) void add_pe_k(const float* __restrict__ x, const float* __restrict__ pe,
                                                float* __restrict__ h) {
  long i = (long)blockIdx.x * 256 + threadIdx.x;
  long nd = i % ((long)Nn * Dd);
  h[i] = x[i] + pe[nd];
}

// ---------- LayerNorm (optionally with residual input added first), row = 768 ----------
__global__ __launch_bounds__(256) void ln_kernel(const float* __restrict__ X, const float* __restrict__ R,
                                                 const float* __restrict__ w, const float* __restrict__ b,
                                                 float* __restrict__ Y) {
  __shared__ float smem[4];
  int row = blockIdx.x, tid = threadIdx.x;
  const float* x = X + (size_t)row * Dd;
  const bool hasR = (R != nullptr);
  const float* r = hasR ? R + (size_t)row * Dd : nullptr;
  float v[3];
  for (int j = 0; j < 3; ++j) {
    int c = tid + j * 256;
    v[j] = x[c] + (hasR ? r[c] : 0.f);
  }
  float s = v[0] + v[1] + v[2];
  s = block_reduce_sum(s, smem);
  float mean = s * (1.f / 768.f);
  float q = 0.f;
  for (int j = 0; j < 3; ++j) { float d = v[j] - mean; q += d * d; }
  q = block_reduce_sum(q, smem);
  float inv = rsqrtf(q * (1.f / 768.f) + 1e-5f);
  for (int j = 0; j < 3; ++j) {
    int c = tid + j * 256;
    Y[(size_t)row * Dd + c] = (v[j] - mean) * inv * w[c] + b[c];
  }
}

// ---------- LayerNorm over (h + part0 + part1 + bias): fuses proj split-K reduction ----------
__global__ __launch_bounds__(256) void ln2res_kernel(const float* __restrict__ X,
                                                     const float* __restrict__ P0, const float* __restrict__ P1,
                                                     const float* __restrict__ pb,
                                                     const float* __restrict__ w, const float* __restrict__ b,
                                                     float* __restrict__ Y) {
  __shared__ float smem[4];
  int row = blockIdx.x, tid = threadIdx.x;
  const float* x  = X  + (size_t)row * Dd;
  const float* p0 = P0 + (size_t)row * Dd;
  const float* p1 = P1 + (size_t)row * Dd;
  float v[3];
  for (int j = 0; j < 3; ++j) {
    int c = tid + j * 256;
    v[j] = x[c] + (p0[c] + p1[c] + pb[c]);
  }
  float s = v[0] + v[1] + v[2];
  s = block_reduce_sum(s, smem);
  float mean = s * (1.f / 768.f);
  float q = 0.f;
  for (int j = 0; j < 3; ++j) { float d = v[j] - mean; q += d * d; }
  q = block_reduce_sum(q, smem);
  float inv = rsqrtf(q * (1.f / 768.f) + 1e-5f);
  for (int j = 0; j < 3; ++j) {
    int c = tid + j * 256;
    Y[(size_t)row * Dd + c] = (v[j] - mean) * inv * w[c] + b[c];
  }
}

// ---------- ff2 split-K reduction: h += p0 + p1 + bias (float4) ----------
__global__ __launch_bounds__(256) void reduce_ff2(float* __restrict__ h, const float* __restrict__ p0,
                                                  const float* __restrict__ p1, const float* __restrict__ bias) {
  long i4 = (long)blockIdx.x * 256 + threadIdx.x;
  int col4 = (int)(i4 % (Dd / 4));
  float4 hv = reinterpret_cast<const float4*>(h)[i4];
  float4 a  = reinterpret_cast<const float4*>(p0)[i4];
  float4 c  = reinterpret_cast<const float4*>(p1)[i4];
  float4 bb = reinterpret_cast<const float4*>(bias)[col4];
  hv.x += a.x + c.x + bb.x;
  hv.y += a.y + c.y + bb.y;
  hv.z += a.z + c.z + bb.z;
  hv.w += a.w + c.w + bb.w;
  reinterpret_cast<float4*>(h)[i4] = hv;
}

// ---------- split helpers: f32 -> bf16 hi + bf16 lo ----------
__device__ __forceinline__ void split8(const float* __restrict__ a, bf16x8& hi, bf16x8& lo) {
  float4 f0 = *reinterpret_cast<const float4*>(a);
  float4 f1 = *reinterpret_cast<const float4*>(a + 4);
  float v[8] = {f0.x, f0.y, f0.z, f0.w, f1.x, f1.y, f1.z, f1.w};
  for (int j = 0; j < 8; ++j) {
    __bf16 h = (__bf16)v[j];
    hi[j] = h;
    lo[j] = (__bf16)(v[j] - (float)h);
  }
}

__device__ __forceinline__ void split8v(const float* __restrict__ v, bf16x8& hi, bf16x8& lo) {
  for (int j = 0; j < 8; ++j) {
    __bf16 h = (__bf16)v[j];
    hi[j] = h;
    lo[j] = (__bf16)(v[j] - (float)h);
  }
}

__device__ __forceinline__ void cvt8(const float* __restrict__ a, bf16x8& hi) {
  float4 f0 = *reinterpret_cast<const float4*>(a);
  float4 f1 = *reinterpret_cast<const float4*>(a + 4);
  hi[0] = (__bf16)f0.x; hi[1] = (__bf16)f0.y; hi[2] = (__bf16)f0.z; hi[3] = (__bf16)f0.w;
  hi[4] = (__bf16)f1.x; hi[5] = (__bf16)f1.y; hi[6] = (__bf16)f1.z; hi[7] = (__bf16)f1.w;
}

// ---------- 128xBN split-precision MFMA GEMM, register prefetch pipeline, optional split-K ----------
// Per z-chunk: C_z = A[:, zK:zK+K] * B[zK:zK+K, :]; partial z written to Cp + z*czs.
// EPI: 0 none, 1 +bias, 2 +bias->exact gelu, 3 +bias +resid.   grid: (Nsz/BN, Msz/128, nchunks).
template<int BN, int EPI>
__global__ __launch_bounds__(256) void gemm128(
    const float* __restrict__ Ap, long lda,
    const float* __restrict__ Bp, long ldb,
    const float* __restrict__ bias, const float* __restrict__ resid,
    float* __restrict__ Cp, long ldc,
    int Ksize, long czs)
{
  constexpr int FN = BN / 32;      // B fragments per wave
  constexpr int KB = BN / 8;       // B elements staged per thread
  int tid = threadIdx.x;
  int m0 = blockIdx.y * 128, n0 = blockIdx.x * BN;
  int z = blockIdx.z;

  const float* Aq = Ap + (long)z * Ksize;
  const float* Bq = Bp + (long)z * Ksize * ldb;
  float* Cq = Cp + (long)z * czs;

  __shared__ __align__(16) __bf16 Ah[128][40], Al[128][40];
  __shared__ __align__(16) __bf16 Bh[BN][40],  Bl[BN][40];

  f32x4 acc[4][FN];
  #pragma unroll
  for (int i = 0; i < 4; ++i)
    #pragma unroll
    for (int j = 0; j < FN; ++j)
      #pragma unroll
      for (int k = 0; k < 4; ++k) acc[i][j][k] = 0.f;

  int lane = tid & 63;
  int w = tid >> 6;
  int WR = (w >> 1) * 64, WC = (w & 1) * (BN / 2);
  int fr = lane & 15, kg = lane >> 4;

  const int ar = tid >> 1, acs = (tid & 1) * 16;  // A: row ar, 16 consecutive k
  const int bn = tid % BN;                         // B: col n0+bn (lane-coalesced)
  const int kb = (tid / BN) * KB;                  //    KB consecutive k rows

  const float* Abase = Aq + (long)(m0 + ar) * lda + acs;
  const float* Bbase = Bq + (long)kb * ldb + (n0 + bn);

  float pa[16], pb[KB];
  {
    const float* As = Abase;
    *reinterpret_cast<float4*>(&pa[0])  = *reinterpret_cast<const float4*>(As);
    *reinterpret_cast<float4*>(&pa[4])  = *reinterpret_cast<const float4*>(As + 4);
    *reinterpret_cast<float4*>(&pa[8])  = *reinterpret_cast<const float4*>(As + 8);
    *reinterpret_cast<float4*>(&pa[12]) = *reinterpret_cast<const float4*>(As + 12);
    #pragma unroll
    for (int j = 0; j < KB; ++j) pb[j] = Bbase[(long)j * ldb];
  }

  for (int k0 = 0; k0 < Ksize; k0 += 32) {
    __syncthreads();  // previous tile's MFMA reads complete
    { // convert + write LDS from registers (tile k0)
      bf16x8 th, tl;
      split8v(&pa[0], th, tl);
      *reinterpret_cast<bf16x8*>(&Ah[ar][acs]) = th;
      *reinterpret_cast<bf16x8*>(&Al[ar][acs]) = tl;
      split8v(&pa[8], th, tl);
      *reinterpret_cast<bf16x8*>(&Ah[ar][acs + 8]) = th;
      *reinterpret_cast<bf16x8*>(&Al[ar][acs + 8]) = tl;
      #pragma unroll
      for (int g8 = 0; g8 < KB / 8; ++g8) {
        bf16x8 bth, btl;
        split8v(&pb[g8 * 8], bth, btl);
        *reinterpret_cast<bf16x8*>(&Bh[bn][kb + g8 * 8]) = bth;
        *reinterpret_cast<bf16x8*>(&Bl[bn][kb + g8 * 8]) = btl;
      }
    }
    __syncthreads();  // LDS tile ready

    if (k0 + 32 < Ksize) { // issue next tile's loads; in flight during MFMA phase
      const float* As = Abase + (k0 + 32);
      *reinterpret_cast<float4*>(&pa[0])  = *reinterpret_cast<const float4*>(As);
      *reinterpret_cast<float4*>(&pa[4])  = *reinterpret_cast<const float4*>(As + 4);
      *reinterpret_cast<float4*>(&pa[8])  = *reinterpret_cast<const float4*>(As + 8);
      *reinterpret_cast<float4*>(&pa[12]) = *reinterpret_cast<const float4*>(As + 12);
      const float* Bs = Bbase + (long)(k0 + 32) * ldb;
      #pragma unroll
      for (int j = 0; j < KB; ++j) pb[j] = Bs[(long)j * ldb];
    }

    bf16x8 ah[4], al[4], bh[FN], bl[FN];
    #pragma unroll
    for (int fm = 0; fm < 4; ++fm) {
      ah[fm] = *reinterpret_cast<const bf16x8*>(&Ah[WR + fm * 16 + fr][kg * 8]);
      al[fm] = *reinterpret_cast<const bf16x8*>(&Al[WR + fm * 16 + fr][kg * 8]);
    }
    #pragma unroll
    for (int fn = 0; fn < FN; ++fn) {
      bh[fn] = *reinterpret_cast<const bf16x8*>(&Bh[WC + fn * 16 + fr][kg * 8]);
      bl[fn] = *reinterpret_cast<const bf16x8*>(&Bl[WC + fn * 16 + fr][kg * 8]);
    }
    #pragma unroll
    for (int fm = 0; fm < 4; ++fm)
      #pragma unroll
      for (int fn = 0; fn < FN; ++fn) {
        acc[fm][fn] = __builtin_amdgcn_mfma_f32_16x16x32_bf16(ah[fm], bh[fn], acc[fm][fn], 0, 0, 0);
        acc[fm][fn] = __builtin_amdgcn_mfma_f32_16x16x32_bf16(al[fm], bh[fn], acc[fm][fn], 0, 0, 0);
        acc[fm][fn] = __builtin_amdgcn_mfma_f32_16x16x32_bf16(ah[fm], bl[fn], acc[fm][fn], 0, 0, 0);
      }
  }

  #pragma unroll
  for (int fm = 0; fm < 4; ++fm)
    #pragma unroll
    for (int fn = 0; fn < FN; ++fn)
      #pragma unroll
      for (int i = 0; i < 4; ++i) {
        int rowg = m0 + WR + fm * 16 + kg * 4 + i;
        int coln = n0 + WC + fn * 16 + fr;
        float v = acc[fm][fn][i];
        if (EPI >= 1) v += bias[coln];
        if (EPI == 2) v = 0.5f * v * (1.f + erff(v * 0.70710678118654752f));
        if (EPI == 3) v += resid[(long)rowg * ldc + coln];
        Cq[(long)rowg * ldc + coln] = v;
      }
}

// ---------- MFMA flash attention, plain bf16 operands (f32 softmax state + accumulators) ----------
// grid: (Nn/64, Hh, Bb), block 256 (4 waves; wave w owns Q rows 16w..16w+15).
// Fragment layouts (HW-verified): A[row=fr][k=kg*8+j], B[col=fr][k], C[row=kg*4+i][col=fr].
__global__ __launch_bounds__(256) void flash_attn_mfma(const float* __restrict__ qkvf,
                                                       const void* __restrict__ mraw,
                                                       const int* __restrict__ flagp,
                                                       float* __restrict__ o) {
  __shared__ __align__(16) __bf16 Qs[64][72];
  __shared__ __align__(16) __bf16 Ks[64][72];
  __shared__ __align__(16) __bf16 Vt[64][66];  // V transposed: [d][key]
  __shared__ __align__(16) __bf16 Ps[64][72];
  __shared__ float kmf[64];
  __shared__ float qmf[64];

  int b = blockIdx.z, hh = blockIdx.y;
  int q0 = blockIdx.x * 64;
  int tid = threadIdx.x, lane = tid & 63, w = tid >> 6;
  int flag = *flagp;
  int fr = lane & 15, kg = lane >> 4;

  const int sr = tid >> 2;
  const int sc = (tid & 3) * 16;

  {
    const float* Qsrc = qkvf + ((long)(b * Nn + q0 + sr)) * (3 * Dd) + hh * HDd + sc;
    bf16x8 t;
    cvt8(Qsrc, t);
    *reinterpret_cast<bf16x8*>(&Qs[sr][sc]) = t;
    cvt8(Qsrc + 8, t);
    *reinterpret_cast<bf16x8*>(&Qs[sr][sc + 8]) = t;
    if (tid < 64) qmf[tid] = mask_at(mraw, flag, b * Nn + q0 + tid) ? 1.f : 0.f;
  }
  __syncthreads();

  float qm[4];
  #pragma unroll
  for (int i = 0; i < 4; ++i) qm[i] = qmf[16 * w + kg * 4 + i];

  bf16x8 qa[2];
  #pragma unroll
  for (int ks = 0; ks < 2; ++ks)
    qa[ks] = *reinterpret_cast<const bf16x8*>(&Qs[16 * w + fr][ks * 32 + kg * 8]);

  float mrow[4], lrow[4];
  f32x4 accO[4];
  #pragma unroll
  for (int i = 0; i < 4; ++i) { mrow[i] = -INFINITY; lrow[i] = 0.f; }
  #pragma unroll
  for (int t = 0; t < 4; ++t)
    for (int i = 0; i < 4; ++i) accO[t][i] = 0.f;

  for (int j0 = 0; j0 < Nn; j0 += 64) {
    __syncthreads();
    {
      const float* Ksrc = qkvf + ((long)(b * Nn + j0 + sr)) * (3 * Dd) + Dd + hh * HDd + sc;
      const float* Vsrc = Ksrc + Dd;
      bf16x8 t;
      cvt8(Ksrc, t);
      *reinterpret_cast<bf16x8*>(&Ks[sr][sc]) = t;
      cvt8(Ksrc + 8, t);
      *reinterpret_cast<bf16x8*>(&Ks[sr][sc + 8]) = t;
      #pragma unroll
      for (int j = 0; j < 16; ++j) Vt[sc + j][sr] = (__bf16)Vsrc[j];
      if (tid < 64) kmf[tid] = mask_at(mraw, flag, b * Nn + j0 + tid) ? 1.f : 0.f;
    }
    __syncthreads();

    f32x4 sacc[4];
    #pragma unroll
    for (int t = 0; t < 4; ++t)
      for (int i = 0; i < 4; ++i) sacc[t][i] = 0.f;
    #pragma unroll
    for (int ks = 0; ks < 2; ++ks) {
      #pragma unroll
      for (int t = 0; t < 4; ++t) {
        bf16x8 bh = *reinterpret_cast<const bf16x8*>(&Ks[16 * t + fr][ks * 32 + kg * 8]);
        sacc[t] = __builtin_amdgcn_mfma_f32_16x16x32_bf16(qa[ks], bh, sacc[t], 0, 0, 0);
      }
    }

    float sv[4][4];
    float mt[4] = {-INFINITY, -INFINITY, -INFINITY, -INFINITY};
    #pragma unroll
    for (int t = 0; t < 4; ++t) {
      float km = kmf[16 * t + fr];
      #pragma unroll
      for (int i = 0; i < 4; ++i) {
        float s = (km > 0.f && qm[i] > 0.f) ? sacc[t][i] * 0.125f : NEGF;
        sv[t][i] = s;
        mt[i] = fmaxf(mt[i], s);
      }
    }
    #pragma unroll
    for (int off = 8; off; off >>= 1)
      #pragma unroll
      for (int i = 0; i < 4; ++i) mt[i] = fmaxf(mt[i], __shfl_xor(mt[i], off));

    float r[4], psum[4];
    #pragma unroll
    for (int i = 0; i < 4; ++i) {
      float mn = fmaxf(mrow[i], mt[i]);
      r[i] = expf(mrow[i] - mn);
      mrow[i] = mn;
      psum[i] = 0.f;
    }
    #pragma unroll
    for (int t = 0; t < 4; ++t) {
      #pragma unroll
      for (int i = 0; i < 4; ++i) {
        float p = expf(sv[t][i] - mrow[i]);
        psum[i] += p;
        Ps[16 * w + kg * 4 + i][16 * t + fr] = (__bf16)p;
      }
    }
    #pragma unroll
    for (int off = 8; off; off >>= 1)
      #pragma unroll
      for (int i = 0; i < 4; ++i) psum[i] += __shfl_xor(psum[i], off);
    #pragma unroll
    for (int i = 0; i < 4; ++i) lrow[i] = lrow[i] * r[i] + psum[i];
    #pragma unroll
    for (int t = 0; t < 4; ++t)
      #pragma unroll
      for (int i = 0; i < 4; ++i) accO[t][i] *= r[i];

    __syncthreads();

    #pragma unroll
    for (int ks = 0; ks < 2; ++ks) {
      bf16x8 pa = *reinterpret_cast<const bf16x8*>(&Ps[16 * w + fr][ks * 32 + kg * 8]);
      #pragma unroll
      for (int t2 = 0; t2 < 4; ++t2) {
        bf16x8 vb = *reinterpret_cast<const bf16x8*>(&Vt[16 * t2 + fr][ks * 32 + kg * 8]);
        accO[t2] = __builtin_amdgcn_mfma_f32_16x16x32_bf16(pa, vb, accO[t2], 0, 0, 0);
      }
    }
  }

  #pragma unroll
  for (int t2 = 0; t2 < 4; ++t2)
    #pragma unroll
    for (int i = 0; i < 4; ++i) {
      int qrow = q0 + 16 * w + kg * 4 + i;
      int col = 16 * t2 + fr;
      o[((long)(b * Nn + qrow)) * Dd + hh * HDd + col] = accO[t2][i] / lrow[i];
    }
}

// ---------- seq-pool ----------
__global__ __launch_bounds__(256) void pool_score(const float* __restrict__ hn, const float* __restrict__ pw,
                                                  const float* __restrict__ pb, float* __restrict__ s) {
  __shared__ float smem[4];
  int row = blockIdx.x, tid = threadIdx.x;
  const float* x = hn + (size_t)row * Dd;
  float acc = 0.f;
  for (int j = 0; j < 3; ++j) { int c = tid + j * 256; acc += x[c] * pw[c]; }
  acc = block_reduce_sum(acc, smem);
  if (tid == 0) s[row] = acc + pb[0];
}

__global__ __launch_bounds__(256) void pool_softmax(const float* __restrict__ s, float* __restrict__ w) {
  __shared__ float smem[4];
  int b = blockIdx.x, tid = threadIdx.x;
  const float* x = s + b * Nn;
  float v[4];
  for (int j = 0; j < 4; ++j) v[j] = x[tid * 4 + j];
  float mx = fmaxf(fmaxf(v[0], v[1]), fmaxf(v[2], v[3]));
  mx = block_reduce_max(mx, smem);
  float e[4], sum = 0.f;
  for (int j = 0; j < 4; ++j) { e[j] = expf(v[j] - mx); sum += e[j]; }
  sum = block_reduce_sum(sum, smem);
  float inv = 1.f / sum;
  for (int j = 0; j < 4; ++j) w[b * Nn + tid * 4 + j] = e[j] * inv;
}

// stage 1: partial sums over 128-token chunks. grid (Dd/256, 8, Bb), block 256.
__global__ __launch_bounds__(256) void pool_reduce1(const float* __restrict__ hn, const float* __restrict__ w,
                                                    float* __restrict__ part) {
  int d = blockIdx.x * 256 + threadIdx.x;
  int ch = blockIdx.y, b = blockIdx.z;
  int n0 = ch * 128;
  float a0 = 0.f, a1 = 0.f;
  for (int n = n0; n < n0 + 128; n += 2) {
    a0 = fmaf(w[b * Nn + n],     hn[((size_t)(b * Nn + n))     * Dd + d], a0);
    a1 = fmaf(w[b * Nn + n + 1], hn[((size_t)(b * Nn + n + 1)) * Dd + d], a1);
  }
  part[((size_t)(b * 8 + ch)) * Dd + d] = a0 + a1;
}

// stage 2: sum 8 partials. grid (Dd/256, Bb), block 256.
__global__ __launch_bounds__(256) void pool_reduce2(const float* __restrict__ part, float* __restrict__ pooled) {
  int d = blockIdx.x * 256 + threadIdx.x;
  int b = blockIdx.y;
  float s = 0.f;
  #pragma unroll
  for (int ch = 0; ch < 8; ++ch) s += part[((size_t)(b * 8 + ch)) * Dd + d];
  pooled[b * Dd + d] = s;
}

// fc: one class per thread, coalesced over c. grid (4, Bb), block 256.
__global__ __launch_bounds__(256) void fc_kernel(const float* __restrict__ pooled, const float* __restrict__ fw,
                                                 const float* __restrict__ fb, float* __restrict__ out) {
  __shared__ float p[768];
  int b = blockIdx.y, tid = threadIdx.x;
  for (int j = 0; j < 3; ++j) p[tid + j * 256] = pooled[b * Dd + tid + j * 256];
  __syncthreads();
  int c = blockIdx.x * 256 + tid;
  if (c < NCc) {
    float a0 = 0.f, a1 = 0.f, a2 = 0.f, a3 = 0.f;
    #pragma unroll 4
    for (int d = 0; d < Dd; d += 4) {
      a0 = fmaf(p[d],     fw[(size_t)d       * NCc + c], a0);
      a1 = fmaf(p[d + 1], fw[(size_t)(d + 1) * NCc + c], a1);
      a2 = fmaf(p[d + 2], fw[(size_t)(d + 2) * NCc + c], a2);
      a3 = fmaf(p[d + 3], fw[(size_t)(d + 3) * NCc + c], a3);
    }
    out[b * NCc + c] = fb[c] + ((a0 + a1) + (a2 + a3));
  }
}

extern "C" void kernel_launch(void* const* d_in, const int* in_sizes, int n_in,
                              void* d_out, int out_size, void* d_ws, size_t ws_size,
                              hipStream_t stream) {
  const float* x      = (const float*)d_in[0];
  const void*  mask   = d_in[1];
  const float* pe     = (const float*)d_in[2];
  const float* ln0_w  = (const float*)d_in[3];
  const float* ln0_b  = (const float*)d_in[4];
  const float* qkv_w  = (const float*)d_in[5];
  const float* proj_w = (const float*)d_in[6];
  const float* proj_b = (const float*)d_in[7];
  const float* ln1_w  = (const float*)d_in[8];
  const float* ln1_b  = (const float*)d_in[9];
  const float* ff1_w  = (const float*)d_in[10];
  const float* ff1_b  = (const float*)d_in[11];
  const float* ff2_w  = (const float*)d_in[12];
  const float* ff2_b  = (const float*)d_in[13];
  const float* norm_w = (const float*)d_in[14];
  const float* norm_b = (const float*)d_in[15];
  const float* pool_w = (const float*)d_in[16];
  const float* pool_b = (const float*)d_in[17];
  const float* fc_w   = (const float*)d_in[18];
  const float* fc_b   = (const float*)d_in[19];
  float* out = (float*)d_out;

  // Compact workspace (~44 MB) — verified in round 5. Do NOT grow past this.
  float* ws = (float*)d_ws;
  float* h      = ws;                        // Mm*Dd
  float* y      = h + (long)Mm * Dd;         // Mm*Dd
  float* qkvf   = y + (long)Mm * Dd;         // Mm*3*Dd
  float* o      = qkvf + (long)Mm * 3 * Dd;  // Mm*Dd
  float* hn     = o + (long)Mm * Dd;         // Mm*Dd
  float* spool  = hn + (long)Mm * Dd;        // Mm
  float* wpool  = spool + Mm;                // Mm
  float* pooled = wpool + Mm;                // Bb*Dd
  float* ppart  = pooled + Bb * Dd;          // Bb*8*Dd
  int*   mflag  = (int*)(ppart + (long)Bb * 8 * Dd);
  float* g  = qkvf;   // alias: ff1 out spans qkvf+o (both dead after flash/proj reads)
  // split-K partials: proj -> hn,qkvf; ff2 -> y,hn (dead buffers at those points)

  detect_mask<<<1, 256, 0, stream>>>((const unsigned char*)mask, mflag);
  add_pe_k<<<(Mm * Dd) / 256, 256, 0, stream>>>(x, pe, h);

  for (int l = 0; l < NLl; ++l) {
    ln_kernel<<<Mm, 256, 0, stream>>>(h, nullptr, ln0_w + l * Dd, ln0_b + l * Dd, y);

    // qkv: (Mm x 768) @ (768 x 2304) -> qkvf
    gemm128<64,0><<<dim3(3 * Dd / 64, Mm / 128, 1), 256, 0, stream>>>(
        y, Dd,
        qkv_w + (long)l * Dd * 3 * Dd, 3 * Dd,
        nullptr, nullptr,
        qkvf, 3 * Dd, Dd, 0);

    // fused attention: o = softmax(mask(QK^T/8)) @ V   (MFMA flash, bf16)
    flash_attn_mfma<<<dim3(Nn / 64, Hh, Bb), 256, 0, stream>>>(qkvf, mask, mflag, o);

    // proj split-K x2: partials -> hn (z=0), qkvf (z=1); K chunk = 384
    gemm128<64,0><<<dim3(Dd / 64, Mm / 128, 2), 256, 0, stream>>>(
        o, Dd,
        proj_w + (long)l * Dd * Dd, Dd,
        nullptr, nullptr,
        hn, Dd, Dd / 2, (long)(qkvf - hn));

    // ln1 fused with proj reduction: h = LN(h + hn + qkvf + proj_b)
    ln2res_kernel<<<Mm, 256, 0, stream>>>(h, hn, qkvf, proj_b + l * Dd,
                                          ln1_w + l * Dd, ln1_b + l * Dd, h);

    // ff1: h @ ff1_w + b -> gelu -> g
    gemm128<64,2><<<dim3(FFf / 64, Mm / 128, 1), 256, 0, stream>>>(
        h, Dd,
        ff1_w + (long)l * Dd * FFf, FFf,
        ff1_b + l * FFf, nullptr,
        g, FFf, Dd, 0);

    // ff2 split-K x2: partials -> y (z=0), hn (z=1); K chunk = 1536
    gemm128<64,0><<<dim3(Dd / 64, Mm / 128, 2), 256, 0, stream>>>(
        g, FFf,
        ff2_w + (long)l * FFf * Dd, Dd,
        nullptr, nullptr,
        y, Dd, FFf / 2, (long)(hn - y));

    // h += y + hn + ff2_b
    reduce_ff2<<<(Mm * Dd / 4) / 256, 256, 0, stream>>>(h, y, hn, ff2_b + l * Dd);
  }

  ln_kernel<<<Mm, 256, 0, stream>>>(h, nullptr, norm_w, norm_b, hn);
  pool_score<<<Mm, 256, 0, stream>>>(hn, pool_w, pool_b, spool);
  pool_softmax<<<Bb, 256, 0, stream>>>(spool, wpool);
  pool_reduce1<<<dim3(Dd / 256, 8, Bb), 256, 0, stream>>>(hn, wpool, ppart);
  pool_reduce2<<<dim3(Dd / 256, Bb), 256, 0, stream>>>(ppart, pooled);
  fc_kernel<<<dim3(4, Bb), 256, 0, stream>>>(pooled, fc_w, fc_b, out);
}

// Round 12
// 2718.807 us; speedup vs baseline: 15.7322x; 1.0909x over previous
//
#include <hip/hip_runtime.h>
#include <hip/hip_bf16.h>
#include <cfloat>
#include <cmath>

typedef __bf16 bf16x8 __attribute__((ext_vector_type(8)));
typedef float  f32x4  __attribute__((ext_vector_type(4)));

static constexpr int Bb = 2, Nn = 1024, Dd = 768, Hh = 12, HDd = 64, FFf = 3072, NLl = 12, NCc = 1000;
static constexpr int Mm = Bb * Nn; // 2048
static constexpr float NEGF = -3.402823466e38f;

// ---------- reductions (256-thread blocks = 4 waves) ----------
__device__ __forceinline__ float block_reduce_sum(float v, volatile float* smem) {
  for (int o = 32; o; o >>= 1) v += __shfl_down(v, o);
  int lane = threadIdx.x & 63, w = threadIdx.x >> 6;
  __syncthreads();
  if (lane == 0) smem[w] = v;
  __syncthreads();
  return smem[0] + smem[1] + smem[2] + smem[3];
}

__device__ __forceinline__ float block_reduce_max(float v, volatile float* smem) {
  for (int o = 32; o; o >>= 1) v = fmaxf(v, __shfl_down(v, o));
  int lane = threadIdx.x & 63, w = threadIdx.x >> 6;
  __syncthreads();
  if (lane == 0) smem[w] = v;
  __syncthreads();
  return fmaxf(fmaxf(smem[0], smem[1]), fmaxf(smem[2], smem[3]));
}

// ---------- mask dtype detection: 0=int32 1=bytes 2=f32 3=int64 4=bf16 ----------
__global__ void detect_mask(const unsigned char* __restrict__ m, int* __restrict__ flag) {
  __shared__ int s_nz1, s_nz2, s_nz3, s_nz84, s_pv;
  int tid = threadIdx.x;
  if (tid == 0) { s_nz1 = 0; s_nz2 = 0; s_nz3 = 0; s_nz84 = 0; s_pv = 0; }
  __syncthreads();
  int nz1 = 0, nz2 = 0, nz3 = 0, nz84 = 0, pv = 0;
  for (int i = tid; i < 2048; i += 256) {
    unsigned char v = m[i];
    if (v) {
      int p4 = i & 3;
      if (p4 == 1) nz1 = 1;
      if (p4 == 2) nz2 = 1;
      if (p4 == 3) nz3 = 1;
      if ((i & 7) == 4) nz84 = 1;
      if ((i & 1) == 0) { if (v != 0x80) pv = 1; }
      else              { if (v != 0x3f) pv = 1; }
    }
  }
  if (nz1)  atomicOr(&s_nz1, 1);
  if (nz2)  atomicOr(&s_nz2, 1);
  if (nz3)  atomicOr(&s_nz3, 1);
  if (nz84) atomicOr(&s_nz84, 1);
  if (pv)   atomicOr(&s_pv, 1);
  __syncthreads();
  if (tid == 0) {
    int f;
    if (!s_nz1 && !s_nz2 && !s_nz3) f = s_nz84 ? 0 : 3;
    else if (!s_pv)                 f = s_nz1 ? 4 : 2;
    else                            f = 1;
    *flag = f;
  }
}

__device__ __forceinline__ bool mask_at(const void* mraw, int flag, int idx) {
  switch (flag) {
    case 0:  return ((const int*)mraw)[idx] != 0;
    case 1:  return ((const unsigned char*)mraw)[idx] != 0;
    case 2:  return ((const float*)mraw)[idx] != 0.f;
    case 3:  return ((const long long*)mraw)[idx] != 0;
    default: return ((const unsigned short*)mraw)[idx] != 0;
  }
}

// ---------- h = x + pe (pe broadcast over batch) ----------
__global__ __launch_bounds__(256) void add_pe_k(const float* __restrict__ x, const float* __restrict__ pe,
                                                float* __restrict__ h) {
  long i = (long)blockIdx.x * 256 + threadIdx.x;
  long nd = i % ((long)Nn * Dd);
  h[i] = x[i] + pe[nd];
}

// ---------- LayerNorm (optionally with residual input added first), row = 768 ----------
__global__ __launch_bounds__(256) void ln_kernel(const float* __restrict__ X, const float* __restrict__ R,
                                                 const float* __restrict__ w, const float* __restrict__ b,
                                                 float* __restrict__ Y) {
  __shared__ float smem[4];
  int row = blockIdx.x, tid = threadIdx.x;
  const float* x = X + (size_t)row * Dd;
  const bool hasR = (R != nullptr);
  const float* r = hasR ? R + (size_t)row * Dd : nullptr;
  float v[3];
  for (int j = 0; j < 3; ++j) {
    int c = tid + j * 256;
    v[j] = x[c] + (hasR ? r[c] : 0.f);
  }
  float s = v[0] + v[1] + v[2];
  s = block_reduce_sum(s, smem);
  float mean = s * (1.f / 768.f);
  float q = 0.f;
  for (int j = 0; j < 3; ++j) { float d = v[j] - mean; q += d * d; }
  q = block_reduce_sum(q, smem);
  float inv = rsqrtf(q * (1.f / 768.f) + 1e-5f);
  for (int j = 0; j < 3; ++j) {
    int c = tid + j * 256;
    Y[(size_t)row * Dd + c] = (v[j] - mean) * inv * w[c] + b[c];
  }
}

// ---------- LayerNorm over (h + part0 + part1 + bias): fuses proj split-K reduction ----------
__global__ __launch_bounds__(256) void ln2res_kernel(const float* __restrict__ X,
                                                     const float* __restrict__ P0, const float* __restrict__ P1,
                                                     const float* __restrict__ pb,
                                                     const float* __restrict__ w, const float* __restrict__ b,
                                                     float* __restrict__ Y) {
  __shared__ float smem[4];
  int row = blockIdx.x, tid = threadIdx.x;
  const float* x  = X  + (size_t)row * Dd;
  const float* p0 = P0 + (size_t)row * Dd;
  const float* p1 = P1 + (size_t)row * Dd;
  float v[3];
  for (int j = 0; j < 3; ++j) {
    int c = tid + j * 256;
    v[j] = x[c] + (p0[c] + p1[c] + pb[c]);
  }
  float s = v[0] + v[1] + v[2];
  s = block_reduce_sum(s, smem);
  float mean = s * (1.f / 768.f);
  float q = 0.f;
  for (int j = 0; j < 3; ++j) { float d = v[j] - mean; q += d * d; }
  q = block_reduce_sum(q, smem);
  float inv = rsqrtf(q * (1.f / 768.f) + 1e-5f);
  for (int j = 0; j < 3; ++j) {
    int c = tid + j * 256;
    Y[(size_t)row * Dd + c] = (v[j] - mean) * inv * w[c] + b[c];
  }
}

// ---------- ff2 split-K reduction: h += p0 + p1 + bias (float4) ----------
__global__ __launch_bounds__(256) void reduce_ff2(float* __restrict__ h, const float* __restrict__ p0,
                                                  const float* __restrict__ p1, const float* __restrict__ bias) {
  long i4 = (long)blockIdx.x * 256 + threadIdx.x;
  int col4 = (int)(i4 % (Dd / 4));
  float4 hv = reinterpret_cast<const float4*>(h)[i4];
  float4 a  = reinterpret_cast<const float4*>(p0)[i4];
  float4 c  = reinterpret_cast<const float4*>(p1)[i4];
  float4 bb = reinterpret_cast<const float4*>(bias)[col4];
  hv.x += a.x + c.x + bb.x;
  hv.y += a.y + c.y + bb.y;
  hv.z += a.z + c.z + bb.z;
  hv.w += a.w + c.w + bb.w;
  reinterpret_cast<float4*>(h)[i4] = hv;
}

// ---------- split helpers ----------
__device__ __forceinline__ void split8v(const float* __restrict__ v, bf16x8& hi, bf16x8& lo) {
  for (int j = 0; j < 8; ++j) {
    __bf16 h = (__bf16)v[j];
    hi[j] = h;
    lo[j] = (__bf16)(v[j] - (float)h);
  }
}

__device__ __forceinline__ void cvt8(const float* __restrict__ a, bf16x8& hi) {
  float4 f0 = *reinterpret_cast<const float4*>(a);
  float4 f1 = *reinterpret_cast<const float4*>(a + 4);
  hi[0] = (__bf16)f0.x; hi[1] = (__bf16)f0.y; hi[2] = (__bf16)f0.z; hi[3] = (__bf16)f0.w;
  hi[4] = (__bf16)f1.x; hi[5] = (__bf16)f1.y; hi[6] = (__bf16)f1.z; hi[7] = (__bf16)f1.w;
}

__device__ __forceinline__ void cvt8v(const float* __restrict__ v, bf16x8& hi) {
  for (int j = 0; j < 8; ++j) hi[j] = (__bf16)v[j];
}

// ---------- 128xBN split-precision MFMA GEMM, register prefetch pipeline, optional split-K ----------
template<int BN, int EPI>
__global__ __launch_bounds__(256) void gemm128(
    const float* __restrict__ Ap, long lda,
    const float* __restrict__ Bp, long ldb,
    const float* __restrict__ bias, const float* __restrict__ resid,
    float* __restrict__ Cp, long ldc,
    int Ksize, long czs)
{
  constexpr int FN = BN / 32;
  constexpr int KB = BN / 8;
  int tid = threadIdx.x;
  int m0 = blockIdx.y * 128, n0 = blockIdx.x * BN;
  int z = blockIdx.z;

  const float* Aq = Ap + (long)z * Ksize;
  const float* Bq = Bp + (long)z * Ksize * ldb;
  float* Cq = Cp + (long)z * czs;

  __shared__ __align__(16) __bf16 Ah[128][40], Al[128][40];
  __shared__ __align__(16) __bf16 Bh[BN][40],  Bl[BN][40];

  f32x4 acc[4][FN];
  #pragma unroll
  for (int i = 0; i < 4; ++i)
    #pragma unroll
    for (int j = 0; j < FN; ++j)
      #pragma unroll
      for (int k = 0; k < 4; ++k) acc[i][j][k] = 0.f;

  int lane = tid & 63;
  int w = tid >> 6;
  int WR = (w >> 1) * 64, WC = (w & 1) * (BN / 2);
  int fr = lane & 15, kg = lane >> 4;

  const int ar = tid >> 1, acs = (tid & 1) * 16;
  const int bn = tid % BN;
  const int kb = (tid / BN) * KB;

  const float* Abase = Aq + (long)(m0 + ar) * lda + acs;
  const float* Bbase = Bq + (long)kb * ldb + (n0 + bn);

  float pa[16], pb[KB];
  {
    const float* As = Abase;
    *reinterpret_cast<float4*>(&pa[0])  = *reinterpret_cast<const float4*>(As);
    *reinterpret_cast<float4*>(&pa[4])  = *reinterpret_cast<const float4*>(As + 4);
    *reinterpret_cast<float4*>(&pa[8])  = *reinterpret_cast<const float4*>(As + 8);
    *reinterpret_cast<float4*>(&pa[12]) = *reinterpret_cast<const float4*>(As + 12);
    #pragma unroll
    for (int j = 0; j < KB; ++j) pb[j] = Bbase[(long)j * ldb];
  }

  for (int k0 = 0; k0 < Ksize; k0 += 32) {
    __syncthreads();
    {
      bf16x8 th, tl;
      split8v(&pa[0], th, tl);
      *reinterpret_cast<bf16x8*>(&Ah[ar][acs]) = th;
      *reinterpret_cast<bf16x8*>(&Al[ar][acs]) = tl;
      split8v(&pa[8], th, tl);
      *reinterpret_cast<bf16x8*>(&Ah[ar][acs + 8]) = th;
      *reinterpret_cast<bf16x8*>(&Al[ar][acs + 8]) = tl;
      #pragma unroll
      for (int g8 = 0; g8 < KB / 8; ++g8) {
        bf16x8 bth, btl;
        split8v(&pb[g8 * 8], bth, btl);
        *reinterpret_cast<bf16x8*>(&Bh[bn][kb + g8 * 8]) = bth;
        *reinterpret_cast<bf16x8*>(&Bl[bn][kb + g8 * 8]) = btl;
      }
    }
    __syncthreads();

    if (k0 + 32 < Ksize) {
      const float* As = Abase + (k0 + 32);
      *reinterpret_cast<float4*>(&pa[0])  = *reinterpret_cast<const float4*>(As);
      *reinterpret_cast<float4*>(&pa[4])  = *reinterpret_cast<const float4*>(As + 4);
      *reinterpret_cast<float4*>(&pa[8])  = *reinterpret_cast<const float4*>(As + 8);
      *reinterpret_cast<float4*>(&pa[12]) = *reinterpret_cast<const float4*>(As + 12);
      const float* Bs = Bbase + (long)(k0 + 32) * ldb;
      #pragma unroll
      for (int j = 0; j < KB; ++j) pb[j] = Bs[(long)j * ldb];
    }

    bf16x8 ah[4], al[4], bh[FN], bl[FN];
    #pragma unroll
    for (int fm = 0; fm < 4; ++fm) {
      ah[fm] = *reinterpret_cast<const bf16x8*>(&Ah[WR + fm * 16 + fr][kg * 8]);
      al[fm] = *reinterpret_cast<const bf16x8*>(&Al[WR + fm * 16 + fr][kg * 8]);
    }
    #pragma unroll
    for (int fn = 0; fn < FN; ++fn) {
      bh[fn] = *reinterpret_cast<const bf16x8*>(&Bh[WC + fn * 16 + fr][kg * 8]);
      bl[fn] = *reinterpret_cast<const bf16x8*>(&Bl[WC + fn * 16 + fr][kg * 8]);
    }
    #pragma unroll
    for (int fm = 0; fm < 4; ++fm)
      #pragma unroll
      for (int fn = 0; fn < FN; ++fn) {
        acc[fm][fn] = __builtin_amdgcn_mfma_f32_16x16x32_bf16(ah[fm], bh[fn], acc[fm][fn], 0, 0, 0);
        acc[fm][fn] = __builtin_amdgcn_mfma_f32_16x16x32_bf16(al[fm], bh[fn], acc[fm][fn], 0, 0, 0);
        acc[fm][fn] = __builtin_amdgcn_mfma_f32_16x16x32_bf16(ah[fm], bl[fn], acc[fm][fn], 0, 0, 0);
      }
  }

  #pragma unroll
  for (int fm = 0; fm < 4; ++fm)
    #pragma unroll
    for (int fn = 0; fn < FN; ++fn)
      #pragma unroll
      for (int i = 0; i < 4; ++i) {
        int rowg = m0 + WR + fm * 16 + kg * 4 + i;
        int coln = n0 + WC + fn * 16 + fr;
        float v = acc[fm][fn][i];
        if (EPI >= 1) v += bias[coln];
        if (EPI == 2) v = 0.5f * v * (1.f + erff(v * 0.70710678118654752f));
        if (EPI == 3) v += resid[(long)rowg * ldc + coln];
        Cq[(long)rowg * ldc + coln] = v;
      }
}

// ---------- MFMA flash attention, KV-split x2, bf16 operands, register prefetch ----------
// grid: (Nn/64, Hh, Bb*2); s = z&1 handles keys [s*512, s*512+512).
// Writes UNNORMALIZED accO to (s ? p1 : p0) and per-row (m,l) to ml[((s*Bb+b)*Hh+hh)*Nn + row].
__global__ __launch_bounds__(256) void flash_attn_split(const float* __restrict__ qkvf,
                                                        const void* __restrict__ mraw,
                                                        const int* __restrict__ flagp,
                                                        float* __restrict__ p0, float* __restrict__ p1,
                                                        float2* __restrict__ ml) {
  __shared__ __align__(16) __bf16 Qs[64][72];
  __shared__ __align__(16) __bf16 Ks[64][72];
  __shared__ __align__(16) __bf16 Vt[64][66];  // V transposed: [d][key]
  __shared__ __align__(16) __bf16 Ps[64][72];
  __shared__ float kmf[64];
  __shared__ float qmf[64];

  int s = blockIdx.z & 1, b = blockIdx.z >> 1;
  int hh = blockIdx.y;
  int q0 = blockIdx.x * 64;
  int tid = threadIdx.x, lane = tid & 63, w = tid >> 6;
  int flag = *flagp;
  int fr = lane & 15, kg = lane >> 4;

  const int sr = tid >> 2;
  const int sc = (tid & 3) * 16;

  {
    const float* Qsrc = qkvf + ((long)(b * Nn + q0 + sr)) * (3 * Dd) + hh * HDd + sc;
    bf16x8 t;
    cvt8(Qsrc, t);
    *reinterpret_cast<bf16x8*>(&Qs[sr][sc]) = t;
    cvt8(Qsrc + 8, t);
    *reinterpret_cast<bf16x8*>(&Qs[sr][sc + 8]) = t;
    if (tid < 64) qmf[tid] = mask_at(mraw, flag, b * Nn + q0 + tid) ? 1.f : 0.f;
  }
  __syncthreads();

  float qm[4];
  #pragma unroll
  for (int i = 0; i < 4; ++i) qm[i] = qmf[16 * w + kg * 4 + i];

  bf16x8 qa[2];
  #pragma unroll
  for (int ks = 0; ks < 2; ++ks)
    qa[ks] = *reinterpret_cast<const bf16x8*>(&Qs[16 * w + fr][ks * 32 + kg * 8]);

  float mrow[4], lrow[4];
  f32x4 accO[4];
  #pragma unroll
  for (int i = 0; i < 4; ++i) { mrow[i] = -INFINITY; lrow[i] = 0.f; }
  #pragma unroll
  for (int t = 0; t < 4; ++t)
    for (int i = 0; i < 4; ++i) accO[t][i] = 0.f;

  const int jbeg = s * (Nn / 2), jend = jbeg + (Nn / 2);

  // register prefetch of K/V tile
  float rk[16], rv[16];
  {
    const float* Ksrc = qkvf + ((long)(b * Nn + jbeg + sr)) * (3 * Dd) + Dd + hh * HDd + sc;
    const float* Vsrc = Ksrc + Dd;
    *reinterpret_cast<float4*>(&rk[0])  = *reinterpret_cast<const float4*>(Ksrc);
    *reinterpret_cast<float4*>(&rk[4])  = *reinterpret_cast<const float4*>(Ksrc + 4);
    *reinterpret_cast<float4*>(&rk[8])  = *reinterpret_cast<const float4*>(Ksrc + 8);
    *reinterpret_cast<float4*>(&rk[12]) = *reinterpret_cast<const float4*>(Ksrc + 12);
    *reinterpret_cast<float4*>(&rv[0])  = *reinterpret_cast<const float4*>(Vsrc);
    *reinterpret_cast<float4*>(&rv[4])  = *reinterpret_cast<const float4*>(Vsrc + 4);
    *reinterpret_cast<float4*>(&rv[8])  = *reinterpret_cast<const float4*>(Vsrc + 8);
    *reinterpret_cast<float4*>(&rv[12]) = *reinterpret_cast<const float4*>(Vsrc + 12);
  }

  for (int j0 = jbeg; j0 < jend; j0 += 64) {
    __syncthreads();  // previous tile fully consumed
    {
      bf16x8 t;
      cvt8v(&rk[0], t);
      *reinterpret_cast<bf16x8*>(&Ks[sr][sc]) = t;
      cvt8v(&rk[8], t);
      *reinterpret_cast<bf16x8*>(&Ks[sr][sc + 8]) = t;
      #pragma unroll
      for (int j = 0; j < 16; ++j) Vt[sc + j][sr] = (__bf16)rv[j];
      if (tid < 64) kmf[tid] = mask_at(mraw, flag, b * Nn + j0 + tid) ? 1.f : 0.f;
    }
    __syncthreads();

    if (j0 + 64 < jend) {  // issue next tile's loads; in flight during compute
      const float* Ksrc = qkvf + ((long)(b * Nn + j0 + 64 + sr)) * (3 * Dd) + Dd + hh * HDd + sc;
      const float* Vsrc = Ksrc + Dd;
      *reinterpret_cast<float4*>(&rk[0])  = *reinterpret_cast<const float4*>(Ksrc);
      *reinterpret_cast<float4*>(&rk[4])  = *reinterpret_cast<const float4*>(Ksrc + 4);
      *reinterpret_cast<float4*>(&rk[8])  = *reinterpret_cast<const float4*>(Ksrc + 8);
      *reinterpret_cast<float4*>(&rk[12]) = *reinterpret_cast<const float4*>(Ksrc + 12);
      *reinterpret_cast<float4*>(&rv[0])  = *reinterpret_cast<const float4*>(Vsrc);
      *reinterpret_cast<float4*>(&rv[4])  = *reinterpret_cast<const float4*>(Vsrc + 4);
      *reinterpret_cast<float4*>(&rv[8])  = *reinterpret_cast<const float4*>(Vsrc + 8);
      *reinterpret_cast<float4*>(&rv[12]) = *reinterpret_cast<const float4*>(Vsrc + 12);
    }

    f32x4 sacc[4];
    #pragma unroll
    for (int t = 0; t < 4; ++t)
      for (int i = 0; i < 4; ++i) sacc[t][i] = 0.f;
    #pragma unroll
    for (int ks = 0; ks < 2; ++ks) {
      #pragma unroll
      for (int t = 0; t < 4; ++t) {
        bf16x8 bh = *reinterpret_cast<const bf16x8*>(&Ks[16 * t + fr][ks * 32 + kg * 8]);
        sacc[t] = __builtin_amdgcn_mfma_f32_16x16x32_bf16(qa[ks], bh, sacc[t], 0, 0, 0);
      }
    }

    float sv[4][4];
    float mt[4] = {-INFINITY, -INFINITY, -INFINITY, -INFINITY};
    #pragma unroll
    for (int t = 0; t < 4; ++t) {
      float km = kmf[16 * t + fr];
      #pragma unroll
      for (int i = 0; i < 4; ++i) {
        float sx = (km > 0.f && qm[i] > 0.f) ? sacc[t][i] * 0.125f : NEGF;
        sv[t][i] = sx;
        mt[i] = fmaxf(mt[i], sx);
      }
    }
    #pragma unroll
    for (int off = 8; off; off >>= 1)
      #pragma unroll
      for (int i = 0; i < 4; ++i) mt[i] = fmaxf(mt[i], __shfl_xor(mt[i], off));

    float r[4], psum[4];
    #pragma unroll
    for (int i = 0; i < 4; ++i) {
      float mn = fmaxf(mrow[i], mt[i]);
      r[i] = __expf(mrow[i] - mn);
      mrow[i] = mn;
      psum[i] = 0.f;
    }
    #pragma unroll
    for (int t = 0; t < 4; ++t) {
      #pragma unroll
      for (int i = 0; i < 4; ++i) {
        float p = __expf(sv[t][i] - mrow[i]);
        psum[i] += p;
        Ps[16 * w + kg * 4 + i][16 * t + fr] = (__bf16)p;
      }
    }
    #pragma unroll
    for (int off = 8; off; off >>= 1)
      #pragma unroll
      for (int i = 0; i < 4; ++i) psum[i] += __shfl_xor(psum[i], off);
    #pragma unroll
    for (int i = 0; i < 4; ++i) lrow[i] = lrow[i] * r[i] + psum[i];
    #pragma unroll
    for (int t = 0; t < 4; ++t)
      #pragma unroll
      for (int i = 0; i < 4; ++i) accO[t][i] *= r[i];

    __syncthreads();

    #pragma unroll
    for (int ks = 0; ks < 2; ++ks) {
      bf16x8 pa = *reinterpret_cast<const bf16x8*>(&Ps[16 * w + fr][ks * 32 + kg * 8]);
      #pragma unroll
      for (int t2 = 0; t2 < 4; ++t2) {
        bf16x8 vb = *reinterpret_cast<const bf16x8*>(&Vt[16 * t2 + fr][ks * 32 + kg * 8]);
        accO[t2] = __builtin_amdgcn_mfma_f32_16x16x32_bf16(pa, vb, accO[t2], 0, 0, 0);
      }
    }
  }

  float* op = s ? p1 : p0;
  #pragma unroll
  for (int t2 = 0; t2 < 4; ++t2)
    #pragma unroll
    for (int i = 0; i < 4; ++i) {
      int qrow = q0 + 16 * w + kg * 4 + i;
      int col = 16 * t2 + fr;
      op[((long)(b * Nn + qrow)) * Dd + hh * HDd + col] = accO[t2][i];  // unnormalized
    }
  if (fr == 0) {
    #pragma unroll
    for (int i = 0; i < 4; ++i) {
      int qrow = q0 + 16 * w + kg * 4 + i;
      ml[((long)(s * Bb + b) * Hh + hh) * Nn + qrow] = make_float2(mrow[i], lrow[i]);
    }
  }
}

// ---------- combine the two KV-splits: o = (w0*p0 + w1*p1) / (w0*l0 + w1*l1) ----------
__global__ __launch_bounds__(256) void flash_combine(const float* __restrict__ p0, const float* __restrict__ p1,
                                                     const float2* __restrict__ ml, float* __restrict__ o) {
  long i4 = (long)blockIdx.x * 256 + threadIdx.x;
  long i = i4 * 4;
  int d = (int)(i % Dd);
  long row = i / Dd;
  int b = (int)(row >> 10), n = (int)(row & (Nn - 1));
  int hh = d >> 6;
  float2 a = ml[((long)b * Hh + hh) * Nn + n];
  float2 c = ml[(((long)Bb + b) * Hh + hh) * Nn + n];
  float M = fmaxf(a.x, c.x);
  float w0 = __expf(a.x - M), w1 = __expf(c.x - M);
  float inv = 1.f / (w0 * a.y + w1 * c.y);
  float4 v0 = reinterpret_cast<const float4*>(p0)[i4];
  float4 v1 = reinterpret_cast<const float4*>(p1)[i4];
  float4 r;
  r.x = (w0 * v0.x + w1 * v1.x) * inv;
  r.y = (w0 * v0.y + w1 * v1.y) * inv;
  r.z = (w0 * v0.z + w1 * v1.z) * inv;
  r.w = (w0 * v0.w + w1 * v1.w) * inv;
  reinterpret_cast<float4*>(o)[i4] = r;
}

// ---------- seq-pool ----------
__global__ __launch_bounds__(256) void pool_score(const float* __restrict__ hn, const float* __restrict__ pw,
                                                  const float* __restrict__ pb, float* __restrict__ s) {
  __shared__ float smem[4];
  int row = blockIdx.x, tid = threadIdx.x;
  const float* x = hn + (size_t)row * Dd;
  float acc = 0.f;
  for (int j = 0; j < 3; ++j) { int c = tid + j * 256; acc += x[c] * pw[c]; }
  acc = block_reduce_sum(acc, smem);
  if (tid == 0) s[row] = acc + pb[0];
}

__global__ __launch_bounds__(256) void pool_softmax(const float* __restrict__ s, float* __restrict__ w) {
  __shared__ float smem[4];
  int b = blockIdx.x, tid = threadIdx.x;
  const float* x = s + b * Nn;
  float v[4];
  for (int j = 0; j < 4; ++j) v[j] = x[tid * 4 + j];
  float mx = fmaxf(fmaxf(v[0], v[1]), fmaxf(v[2], v[3]));
  mx = block_reduce_max(mx, smem);
  float e[4], sum = 0.f;
  for (int j = 0; j < 4; ++j) { e[j] = expf(v[j] - mx); sum += e[j]; }
  sum = block_reduce_sum(sum, smem);
  float inv = 1.f / sum;
  for (int j = 0; j < 4; ++j) w[b * Nn + tid * 4 + j] = e[j] * inv;
}

// stage 1: partial sums over 128-token chunks. grid (Dd/256, 8, Bb), block 256.
__global__ __launch_bounds__(256) void pool_reduce1(const float* __restrict__ hn, const float* __restrict__ w,
                                                    float* __restrict__ part) {
  int d = blockIdx.x * 256 + threadIdx.x;
  int ch = blockIdx.y, b = blockIdx.z;
  int n0 = ch * 128;
  float a0 = 0.f, a1 = 0.f;
  for (int n = n0; n < n0 + 128; n += 2) {
    a0 = fmaf(w[b * Nn + n],     hn[((size_t)(b * Nn + n))     * Dd + d], a0);
    a1 = fmaf(w[b * Nn + n + 1], hn[((size_t)(b * Nn + n + 1)) * Dd + d], a1);
  }
  part[((size_t)(b * 8 + ch)) * Dd + d] = a0 + a1;
}

// stage 2: sum 8 partials. grid (Dd/256, Bb), block 256.
__global__ __launch_bounds__(256) void pool_reduce2(const float* __restrict__ part, float* __restrict__ pooled) {
  int d = blockIdx.x * 256 + threadIdx.x;
  int b = blockIdx.y;
  float s = 0.f;
  #pragma unroll
  for (int ch = 0; ch < 8; ++ch) s += part[((size_t)(b * 8 + ch)) * Dd + d];
  pooled[b * Dd + d] = s;
}

// fc: one class per thread, coalesced over c. grid (4, Bb), block 256.
__global__ __launch_bounds__(256) void fc_kernel(const float* __restrict__ pooled, const float* __restrict__ fw,
                                                 const float* __restrict__ fb, float* __restrict__ out) {
  __shared__ float p[768];
  int b = blockIdx.y, tid = threadIdx.x;
  for (int j = 0; j < 3; ++j) p[tid + j * 256] = pooled[b * Dd + tid + j * 256];
  __syncthreads();
  int c = blockIdx.x * 256 + tid;
  if (c < NCc) {
    float a0 = 0.f, a1 = 0.f, a2 = 0.f, a3 = 0.f;
    #pragma unroll 4
    for (int d = 0; d < Dd; d += 4) {
      a0 = fmaf(p[d],     fw[(size_t)d       * NCc + c], a0);
      a1 = fmaf(p[d + 1], fw[(size_t)(d + 1) * NCc + c], a1);
      a2 = fmaf(p[d + 2], fw[(size_t)(d + 2) * NCc + c], a2);
      a3 = fmaf(p[d + 3], fw[(size_t)(d + 3) * NCc + c], a3);
    }
    out[b * NCc + c] = fb[c] + ((a0 + a1) + (a2 + a3));
  }
}

extern "C" void kernel_launch(void* const* d_in, const int* in_sizes, int n_in,
                              void* d_out, int out_size, void* d_ws, size_t ws_size,
                              hipStream_t stream) {
  const float* x      = (const float*)d_in[0];
  const void*  mask   = d_in[1];
  const float* pe     = (const float*)d_in[2];
  const float* ln0_w  = (const float*)d_in[3];
  const float* ln0_b  = (const float*)d_in[4];
  const float* qkv_w  = (const float*)d_in[5];
  const float* proj_w = (const float*)d_in[6];
  const float* proj_b = (const float*)d_in[7];
  const float* ln1_w  = (const float*)d_in[8];
  const float* ln1_b  = (const float*)d_in[9];
  const float* ff1_w  = (const float*)d_in[10];
  const float* ff1_b  = (const float*)d_in[11];
  const float* ff2_w  = (const float*)d_in[12];
  const float* ff2_b  = (const float*)d_in[13];
  const float* norm_w = (const float*)d_in[14];
  const float* norm_b = (const float*)d_in[15];
  const float* pool_w = (const float*)d_in[16];
  const float* pool_b = (const float*)d_in[17];
  const float* fc_w   = (const float*)d_in[18];
  const float* fc_b   = (const float*)d_in[19];
  float* out = (float*)d_out;

  // Compact workspace (~44.5 MB) — base layout verified in round 5.
  float* ws = (float*)d_ws;
  float* h      = ws;                        // Mm*Dd
  float* y      = h + (long)Mm * Dd;         // Mm*Dd
  float* qkvf   = y + (long)Mm * Dd;         // Mm*3*Dd
  float* o      = qkvf + (long)Mm * 3 * Dd;  // Mm*Dd
  float* hn     = o + (long)Mm * Dd;         // Mm*Dd
  float* spool  = hn + (long)Mm * Dd;        // Mm
  float* wpool  = spool + Mm;                // Mm
  float* pooled = wpool + Mm;                // Bb*Dd
  float* ppart  = pooled + Bb * Dd;          // Bb*8*Dd
  float* mlbuf  = ppart + (long)Bb * 8 * Dd; // 2*Bb*Hh*Nn float2 = 393KB
  int*   mflag  = (int*)(mlbuf + (long)2 * 2 * Bb * Hh * Nn);
  float* g  = qkvf;   // alias: ff1 out spans qkvf+o (both dead after flash/proj reads)
  // flash partials: p0 = y, p1 = hn (both dead during attention)
  // split-K partials: proj -> hn,qkvf; ff2 -> y,hn (dead buffers at those points)

  detect_mask<<<1, 256, 0, stream>>>((const unsigned char*)mask, mflag);
  add_pe_k<<<(Mm * Dd) / 256, 256, 0, stream>>>(x, pe, h);

  for (int l = 0; l < NLl; ++l) {
    ln_kernel<<<Mm, 256, 0, stream>>>(h, nullptr, ln0_w + l * Dd, ln0_b + l * Dd, y);

    // qkv: (Mm x 768) @ (768 x 2304) -> qkvf
    gemm128<64,0><<<dim3(3 * Dd / 64, Mm / 128, 1), 256, 0, stream>>>(
        y, Dd,
        qkv_w + (long)l * Dd * 3 * Dd, 3 * Dd,
        nullptr, nullptr,
        qkvf, 3 * Dd, Dd, 0);

    // fused attention, KV-split x2: partials -> y, hn + (m,l) -> mlbuf; combine -> o
    flash_attn_split<<<dim3(Nn / 64, Hh, Bb * 2), 256, 0, stream>>>(
        qkvf, mask, mflag, y, hn, (float2*)mlbuf);
    flash_combine<<<(Mm * Dd / 4) / 256, 256, 0, stream>>>(y, hn, (const float2*)mlbuf, o);

    // proj split-K x2: partials -> hn (z=0), qkvf (z=1); K chunk = 384
    gemm128<64,0><<<dim3(Dd / 64, Mm / 128, 2), 256, 0, stream>>>(
        o, Dd,
        proj_w + (long)l * Dd * Dd, Dd,
        nullptr, nullptr,
        hn, Dd, Dd / 2, (long)(qkvf - hn));

    // ln1 fused with proj reduction: h = LN(h + hn + qkvf + proj_b)
    ln2res_kernel<<<Mm, 256, 0, stream>>>(h, hn, qkvf, proj_b + l * Dd,
                                          ln1_w + l * Dd, ln1_b + l * Dd, h);

    // ff1: h @ ff1_w + b -> gelu -> g
    gemm128<64,2><<<dim3(FFf / 64, Mm / 128, 1), 256, 0, stream>>>(
        h, Dd,
        ff1_w + (long)l * Dd * FFf, FFf,
        ff1_b + l * FFf, nullptr,
        g, FFf, Dd, 0);

    // ff2 split-K x2: partials -> y (z=0), hn (z=1); K chunk = 1536
    gemm128<64,0><<<dim3(Dd / 64, Mm / 128, 2), 256, 0, stream>>>(
        g, FFf,
        ff2_w + (long)l * FFf * Dd, Dd,
        nullptr, nullptr,
        y, Dd, FFf / 2, (long)(hn - y));

    // h += y + hn + ff2_b
    reduce_ff2<<<(Mm * Dd / 4) / 256, 256, 0, stream>>>(h, y, hn, ff2_b + l * Dd);
  }

  ln_kernel<<<Mm, 256, 0, stream>>>(h, nullptr, norm_w, norm_b, hn);
  pool_score<<<Mm, 256, 0, stream>>>(hn, pool_w, pool_b, spool);
  pool_softmax<<<Bb, 256, 0, stream>>>(spool, wpool);
  pool_reduce1<<<dim3(Dd / 256, 8, Bb), 256, 0, stream>>>(hn, wpool, ppart);
  pool_reduce2<<<dim3(Dd / 256, Bb), 256, 0, stream>>>(ppart, pooled);
  fc_kernel<<<dim3(4, Bb), 256, 0, stream>>>(pooled, fc_w, fc_b, out);
}

// Round 13
// 2495.666 us; speedup vs baseline: 17.1388x; 1.0894x over previous
//
#include <hip/hip_runtime.h>
#include <hip/hip_bf16.h>
#include <cfloat>
#include <cmath>

typedef __bf16 bf16x8 __attribute__((ext_vector_type(8)));
typedef float  f32x4  __attribute__((ext_vector_type(4)));

static constexpr int Bb = 2, Nn = 1024, Dd = 768, Hh = 12, HDd = 64, FFf = 3072, NLl = 12, NCc = 1000;
static constexpr int Mm = Bb * Nn; // 2048
static constexpr float NEGF = -3.402823466e38f;

// ---------- reductions (256-thread blocks = 4 waves) ----------
__device__ __forceinline__ float block_reduce_sum(float v, volatile float* smem) {
  for (int o = 32; o; o >>= 1) v += __shfl_down(v, o);
  int lane = threadIdx.x & 63, w = threadIdx.x >> 6;
  __syncthreads();
  if (lane == 0) smem[w] = v;
  __syncthreads();
  return smem[0] + smem[1] + smem[2] + smem[3];
}

__device__ __forceinline__ float block_reduce_max(float v, volatile float* smem) {
  for (int o = 32; o; o >>= 1) v = fmaxf(v, __shfl_down(v, o));
  int lane = threadIdx.x & 63, w = threadIdx.x >> 6;
  __syncthreads();
  if (lane == 0) smem[w] = v;
  __syncthreads();
  return fmaxf(fmaxf(smem[0], smem[1]), fmaxf(smem[2], smem[3]));
}

// ---------- mask dtype detection: 0=int32 1=bytes 2=f32 3=int64 4=bf16 ----------
__global__ void detect_mask(const unsigned char* __restrict__ m, int* __restrict__ flag) {
  __shared__ int s_nz1, s_nz2, s_nz3, s_nz84, s_pv;
  int tid = threadIdx.x;
  if (tid == 0) { s_nz1 = 0; s_nz2 = 0; s_nz3 = 0; s_nz84 = 0; s_pv = 0; }
  __syncthreads();
  int nz1 = 0, nz2 = 0, nz3 = 0, nz84 = 0, pv = 0;
  for (int i = tid; i < 2048; i += 256) {
    unsigned char v = m[i];
    if (v) {
      int p4 = i & 3;
      if (p4 == 1) nz1 = 1;
      if (p4 == 2) nz2 = 1;
      if (p4 == 3) nz3 = 1;
      if ((i & 7) == 4) nz84 = 1;
      if ((i & 1) == 0) { if (v != 0x80) pv = 1; }
      else              { if (v != 0x3f) pv = 1; }
    }
  }
  if (nz1)  atomicOr(&s_nz1, 1);
  if (nz2)  atomicOr(&s_nz2, 1);
  if (nz3)  atomicOr(&s_nz3, 1);
  if (nz84) atomicOr(&s_nz84, 1);
  if (pv)   atomicOr(&s_pv, 1);
  __syncthreads();
  if (tid == 0) {
    int f;
    if (!s_nz1 && !s_nz2 && !s_nz3) f = s_nz84 ? 0 : 3;
    else if (!s_pv)                 f = s_nz1 ? 4 : 2;
    else                            f = 1;
    *flag = f;
  }
}

__device__ __forceinline__ bool mask_at(const void* mraw, int flag, int idx) {
  switch (flag) {
    case 0:  return ((const int*)mraw)[idx] != 0;
    case 1:  return ((const unsigned char*)mraw)[idx] != 0;
    case 2:  return ((const float*)mraw)[idx] != 0.f;
    case 3:  return ((const long long*)mraw)[idx] != 0;
    default: return ((const unsigned short*)mraw)[idx] != 0;
  }
}

// ---------- h = x + pe (pe broadcast over batch) ----------
__global__ __launch_bounds__(256) void add_pe_k(const float* __restrict__ x, const float* __restrict__ pe,
                                                float* __restrict__ h) {
  long i = (long)blockIdx.x * 256 + threadIdx.x;
  long nd = i % ((long)Nn * Dd);
  h[i] = x[i] + pe[nd];
}

// ---------- LayerNorm (optionally with residual input added first), row = 768 ----------
__global__ __launch_bounds__(256) void ln_kernel(const float* __restrict__ X, const float* __restrict__ R,
                                                 const float* __restrict__ w, const float* __restrict__ b,
                                                 float* __restrict__ Y) {
  __shared__ float smem[4];
  int row = blockIdx.x, tid = threadIdx.x;
  const float* x = X + (size_t)row * Dd;
  const bool hasR = (R != nullptr);
  const float* r = hasR ? R + (size_t)row * Dd : nullptr;
  float v[3];
  for (int j = 0; j < 3; ++j) {
    int c = tid + j * 256;
    v[j] = x[c] + (hasR ? r[c] : 0.f);
  }
  float s = v[0] + v[1] + v[2];
  s = block_reduce_sum(s, smem);
  float mean = s * (1.f / 768.f);
  float q = 0.f;
  for (int j = 0; j < 3; ++j) { float d = v[j] - mean; q += d * d; }
  q = block_reduce_sum(q, smem);
  float inv = rsqrtf(q * (1.f / 768.f) + 1e-5f);
  for (int j = 0; j < 3; ++j) {
    int c = tid + j * 256;
    Y[(size_t)row * Dd + c] = (v[j] - mean) * inv * w[c] + b[c];
  }
}

// ---------- LayerNorm over (h + part0 + part1 + bias): fuses proj split-K reduction ----------
__global__ __launch_bounds__(256) void ln2res_kernel(const float* __restrict__ X,
                                                     const float* __restrict__ P0, const float* __restrict__ P1,
                                                     const float* __restrict__ pb,
                                                     const float* __restrict__ w, const float* __restrict__ b,
                                                     float* __restrict__ Y) {
  __shared__ float smem[4];
  int row = blockIdx.x, tid = threadIdx.x;
  const float* x  = X  + (size_t)row * Dd;
  const float* p0 = P0 + (size_t)row * Dd;
  const float* p1 = P1 + (size_t)row * Dd;
  float v[3];
  for (int j = 0; j < 3; ++j) {
    int c = tid + j * 256;
    v[j] = x[c] + (p0[c] + p1[c] + pb[c]);
  }
  float s = v[0] + v[1] + v[2];
  s = block_reduce_sum(s, smem);
  float mean = s * (1.f / 768.f);
  float q = 0.f;
  for (int j = 0; j < 3; ++j) { float d = v[j] - mean; q += d * d; }
  q = block_reduce_sum(q, smem);
  float inv = rsqrtf(q * (1.f / 768.f) + 1e-5f);
  for (int j = 0; j < 3; ++j) {
    int c = tid + j * 256;
    Y[(size_t)row * Dd + c] = (v[j] - mean) * inv * w[c] + b[c];
  }
}

// ---------- ff2 split-K reduction: h += p0 + p1 + bias (float4) ----------
__global__ __launch_bounds__(256) void reduce_ff2(float* __restrict__ h, const float* __restrict__ p0,
                                                  const float* __restrict__ p1, const float* __restrict__ bias) {
  long i4 = (long)blockIdx.x * 256 + threadIdx.x;
  int col4 = (int)(i4 % (Dd / 4));
  float4 hv = reinterpret_cast<const float4*>(h)[i4];
  float4 a  = reinterpret_cast<const float4*>(p0)[i4];
  float4 c  = reinterpret_cast<const float4*>(p1)[i4];
  float4 bb = reinterpret_cast<const float4*>(bias)[col4];
  hv.x += a.x + c.x + bb.x;
  hv.y += a.y + c.y + bb.y;
  hv.z += a.z + c.z + bb.z;
  hv.w += a.w + c.w + bb.w;
  reinterpret_cast<float4*>(h)[i4] = hv;
}

// ---------- split helpers ----------
__device__ __forceinline__ void split8v(const float* __restrict__ v, bf16x8& hi, bf16x8& lo) {
  for (int j = 0; j < 8; ++j) {
    __bf16 h = (__bf16)v[j];
    hi[j] = h;
    lo[j] = (__bf16)(v[j] - (float)h);
  }
}

__device__ __forceinline__ void cvt8(const float* __restrict__ a, bf16x8& hi) {
  float4 f0 = *reinterpret_cast<const float4*>(a);
  float4 f1 = *reinterpret_cast<const float4*>(a + 4);
  hi[0] = (__bf16)f0.x; hi[1] = (__bf16)f0.y; hi[2] = (__bf16)f0.z; hi[3] = (__bf16)f0.w;
  hi[4] = (__bf16)f1.x; hi[5] = (__bf16)f1.y; hi[6] = (__bf16)f1.z; hi[7] = (__bf16)f1.w;
}

__device__ __forceinline__ void cvt8v(const float* __restrict__ v, bf16x8& hi) {
  for (int j = 0; j < 8; ++j) hi[j] = (__bf16)v[j];
}

// ---------- 128xBN MFMA GEMM: A plain bf16, B split hi/lo (~0.3% rel err), reg prefetch,
// ---------- XCD chunk swizzle, optional split-K ----------
// Per z-chunk: C_z = A[:, zK:zK+K] * B[zK:zK+K, :]; partial z written to Cp + z*czs.
// EPI: 0 none, 1 +bias, 2 +bias->exact gelu, 3 +bias +resid.   grid: (Nsz/BN, Msz/128, nchunks).
// Requires gridDim.x*gridDim.y % 8 == 0 (XCD swizzle).
template<int BN, int EPI>
__global__ __launch_bounds__(256) void gemm128(
    const float* __restrict__ Ap, long lda,
    const float* __restrict__ Bp, long ldb,
    const float* __restrict__ bias, const float* __restrict__ resid,
    float* __restrict__ Cp, long ldc,
    int Ksize, long czs)
{
  constexpr int FN = BN / 32;
  constexpr int KB = BN / 8;
  int tid = threadIdx.x;

  // XCD-aware chunk swizzle: XCD (bid&7) gets a contiguous logical range -> shared A/B panels stay in its L2.
  int nwg2 = gridDim.x * gridDim.y;
  int bid = blockIdx.y * gridDim.x + blockIdx.x;
  int swz = (bid & 7) * (nwg2 >> 3) + (bid >> 3);
  int bx = swz % gridDim.x, by = swz / gridDim.x;
  int m0 = by * 128, n0 = bx * BN;
  int z = blockIdx.z;

  const float* Aq = Ap + (long)z * Ksize;
  const float* Bq = Bp + (long)z * Ksize * ldb;
  float* Cq = Cp + (long)z * czs;

  __shared__ __align__(16) __bf16 Ah[128][40];
  __shared__ __align__(16) __bf16 Bh[BN][40], Bl[BN][40];

  f32x4 acc[4][FN];
  #pragma unroll
  for (int i = 0; i < 4; ++i)
    #pragma unroll
    for (int j = 0; j < FN; ++j)
      #pragma unroll
      for (int k = 0; k < 4; ++k) acc[i][j][k] = 0.f;

  int lane = tid & 63;
  int w = tid >> 6;
  int WR = (w >> 1) * 64, WC = (w & 1) * (BN / 2);
  int fr = lane & 15, kg = lane >> 4;

  const int ar = tid >> 1, acs = (tid & 1) * 16;
  const int bn = tid % BN;
  const int kb = (tid / BN) * KB;

  const float* Abase = Aq + (long)(m0 + ar) * lda + acs;
  const float* Bbase = Bq + (long)kb * ldb + (n0 + bn);

  float pa[16], pb[KB];
  {
    const float* As = Abase;
    *reinterpret_cast<float4*>(&pa[0])  = *reinterpret_cast<const float4*>(As);
    *reinterpret_cast<float4*>(&pa[4])  = *reinterpret_cast<const float4*>(As + 4);
    *reinterpret_cast<float4*>(&pa[8])  = *reinterpret_cast<const float4*>(As + 8);
    *reinterpret_cast<float4*>(&pa[12]) = *reinterpret_cast<const float4*>(As + 12);
    #pragma unroll
    for (int j = 0; j < KB; ++j) pb[j] = Bbase[(long)j * ldb];
  }

  for (int k0 = 0; k0 < Ksize; k0 += 32) {
    __syncthreads();
    {
      bf16x8 th;
      cvt8v(&pa[0], th);
      *reinterpret_cast<bf16x8*>(&Ah[ar][acs]) = th;
      cvt8v(&pa[8], th);
      *reinterpret_cast<bf16x8*>(&Ah[ar][acs + 8]) = th;
      #pragma unroll
      for (int g8 = 0; g8 < KB / 8; ++g8) {
        bf16x8 bth, btl;
        split8v(&pb[g8 * 8], bth, btl);
        *reinterpret_cast<bf16x8*>(&Bh[bn][kb + g8 * 8]) = bth;
        *reinterpret_cast<bf16x8*>(&Bl[bn][kb + g8 * 8]) = btl;
      }
    }
    __syncthreads();

    if (k0 + 32 < Ksize) {
      const float* As = Abase + (k0 + 32);
      *reinterpret_cast<float4*>(&pa[0])  = *reinterpret_cast<const float4*>(As);
      *reinterpret_cast<float4*>(&pa[4])  = *reinterpret_cast<const float4*>(As + 4);
      *reinterpret_cast<float4*>(&pa[8])  = *reinterpret_cast<const float4*>(As + 8);
      *reinterpret_cast<float4*>(&pa[12]) = *reinterpret_cast<const float4*>(As + 12);
      const float* Bs = Bbase + (long)(k0 + 32) * ldb;
      #pragma unroll
      for (int j = 0; j < KB; ++j) pb[j] = Bs[(long)j * ldb];
    }

    bf16x8 ah[4], bh[FN], bl[FN];
    #pragma unroll
    for (int fm = 0; fm < 4; ++fm)
      ah[fm] = *reinterpret_cast<const bf16x8*>(&Ah[WR + fm * 16 + fr][kg * 8]);
    #pragma unroll
    for (int fn = 0; fn < FN; ++fn) {
      bh[fn] = *reinterpret_cast<const bf16x8*>(&Bh[WC + fn * 16 + fr][kg * 8]);
      bl[fn] = *reinterpret_cast<const bf16x8*>(&Bl[WC + fn * 16 + fr][kg * 8]);
    }
    #pragma unroll
    for (int fm = 0; fm < 4; ++fm)
      #pragma unroll
      for (int fn = 0; fn < FN; ++fn) {
        acc[fm][fn] = __builtin_amdgcn_mfma_f32_16x16x32_bf16(ah[fm], bh[fn], acc[fm][fn], 0, 0, 0);
        acc[fm][fn] = __builtin_amdgcn_mfma_f32_16x16x32_bf16(ah[fm], bl[fn], acc[fm][fn], 0, 0, 0);
      }
  }

  #pragma unroll
  for (int fm = 0; fm < 4; ++fm)
    #pragma unroll
    for (int fn = 0; fn < FN; ++fn)
      #pragma unroll
      for (int i = 0; i < 4; ++i) {
        int rowg = m0 + WR + fm * 16 + kg * 4 + i;
        int coln = n0 + WC + fn * 16 + fr;
        float v = acc[fm][fn][i];
        if (EPI >= 1) v += bias[coln];
        if (EPI == 2) v = 0.5f * v * (1.f + erff(v * 0.70710678118654752f));
        if (EPI == 3) v += resid[(long)rowg * ldc + coln];
        Cq[(long)rowg * ldc + coln] = v;
      }
}

// ---------- MFMA flash attention, KV-split x2, bf16 operands, register prefetch ----------
__global__ __launch_bounds__(256) void flash_attn_split(const float* __restrict__ qkvf,
                                                        const void* __restrict__ mraw,
                                                        const int* __restrict__ flagp,
                                                        float* __restrict__ p0, float* __restrict__ p1,
                                                        float2* __restrict__ ml) {
  __shared__ __align__(16) __bf16 Qs[64][72];
  __shared__ __align__(16) __bf16 Ks[64][72];
  __shared__ __align__(16) __bf16 Vt[64][66];  // V transposed: [d][key]
  __shared__ __align__(16) __bf16 Ps[64][72];
  __shared__ float kmf[64];
  __shared__ float qmf[64];

  int s = blockIdx.z & 1, b = blockIdx.z >> 1;
  int hh = blockIdx.y;
  int q0 = blockIdx.x * 64;
  int tid = threadIdx.x, lane = tid & 63, w = tid >> 6;
  int flag = *flagp;
  int fr = lane & 15, kg = lane >> 4;

  const int sr = tid >> 2;
  const int sc = (tid & 3) * 16;

  {
    const float* Qsrc = qkvf + ((long)(b * Nn + q0 + sr)) * (3 * Dd) + hh * HDd + sc;
    bf16x8 t;
    cvt8(Qsrc, t);
    *reinterpret_cast<bf16x8*>(&Qs[sr][sc]) = t;
    cvt8(Qsrc + 8, t);
    *reinterpret_cast<bf16x8*>(&Qs[sr][sc + 8]) = t;
    if (tid < 64) qmf[tid] = mask_at(mraw, flag, b * Nn + q0 + tid) ? 1.f : 0.f;
  }
  __syncthreads();

  float qm[4];
  #pragma unroll
  for (int i = 0; i < 4; ++i) qm[i] = qmf[16 * w + kg * 4 + i];

  bf16x8 qa[2];
  #pragma unroll
  for (int ks = 0; ks < 2; ++ks)
    qa[ks] = *reinterpret_cast<const bf16x8*>(&Qs[16 * w + fr][ks * 32 + kg * 8]);

  float mrow[4], lrow[4];
  f32x4 accO[4];
  #pragma unroll
  for (int i = 0; i < 4; ++i) { mrow[i] = -INFINITY; lrow[i] = 0.f; }
  #pragma unroll
  for (int t = 0; t < 4; ++t)
    for (int i = 0; i < 4; ++i) accO[t][i] = 0.f;

  const int jbeg = s * (Nn / 2), jend = jbeg + (Nn / 2);

  float rk[16], rv[16];
  {
    const float* Ksrc = qkvf + ((long)(b * Nn + jbeg + sr)) * (3 * Dd) + Dd + hh * HDd + sc;
    const float* Vsrc = Ksrc + Dd;
    *reinterpret_cast<float4*>(&rk[0])  = *reinterpret_cast<const float4*>(Ksrc);
    *reinterpret_cast<float4*>(&rk[4])  = *reinterpret_cast<const float4*>(Ksrc + 4);
    *reinterpret_cast<float4*>(&rk[8])  = *reinterpret_cast<const float4*>(Ksrc + 8);
    *reinterpret_cast<float4*>(&rk[12]) = *reinterpret_cast<const float4*>(Ksrc + 12);
    *reinterpret_cast<float4*>(&rv[0])  = *reinterpret_cast<const float4*>(Vsrc);
    *reinterpret_cast<float4*>(&rv[4])  = *reinterpret_cast<const float4*>(Vsrc + 4);
    *reinterpret_cast<float4*>(&rv[8])  = *reinterpret_cast<const float4*>(Vsrc + 8);
    *reinterpret_cast<float4*>(&rv[12]) = *reinterpret_cast<const float4*>(Vsrc + 12);
  }

  for (int j0 = jbeg; j0 < jend; j0 += 64) {
    __syncthreads();
    {
      bf16x8 t;
      cvt8v(&rk[0], t);
      *reinterpret_cast<bf16x8*>(&Ks[sr][sc]) = t;
      cvt8v(&rk[8], t);
      *reinterpret_cast<bf16x8*>(&Ks[sr][sc + 8]) = t;
      #pragma unroll
      for (int j = 0; j < 16; ++j) Vt[sc + j][sr] = (__bf16)rv[j];
      if (tid < 64) kmf[tid] = mask_at(mraw, flag, b * Nn + j0 + tid) ? 1.f : 0.f;
    }
    __syncthreads();

    if (j0 + 64 < jend) {
      const float* Ksrc = qkvf + ((long)(b * Nn + j0 + 64 + sr)) * (3 * Dd) + Dd + hh * HDd + sc;
      const float* Vsrc = Ksrc + Dd;
      *reinterpret_cast<float4*>(&rk[0])  = *reinterpret_cast<const float4*>(Ksrc);
      *reinterpret_cast<float4*>(&rk[4])  = *reinterpret_cast<const float4*>(Ksrc + 4);
      *reinterpret_cast<float4*>(&rk[8])  = *reinterpret_cast<const float4*>(Ksrc + 8);
      *reinterpret_cast<float4*>(&rk[12]) = *reinterpret_cast<const float4*>(Ksrc + 12);
      *reinterpret_cast<float4*>(&rv[0])  = *reinterpret_cast<const float4*>(Vsrc);
      *reinterpret_cast<float4*>(&rv[4])  = *reinterpret_cast<const float4*>(Vsrc + 4);
      *reinterpret_cast<float4*>(&rv[8])  = *reinterpret_cast<const float4*>(Vsrc + 8);
      *reinterpret_cast<float4*>(&rv[12]) = *reinterpret_cast<const float4*>(Vsrc + 12);
    }

    f32x4 sacc[4];
    #pragma unroll
    for (int t = 0; t < 4; ++t)
      for (int i = 0; i < 4; ++i) sacc[t][i] = 0.f;
    #pragma unroll
    for (int ks = 0; ks < 2; ++ks) {
      #pragma unroll
      for (int t = 0; t < 4; ++t) {
        bf16x8 bh = *reinterpret_cast<const bf16x8*>(&Ks[16 * t + fr][ks * 32 + kg * 8]);
        sacc[t] = __builtin_amdgcn_mfma_f32_16x16x32_bf16(qa[ks], bh, sacc[t], 0, 0, 0);
      }
    }

    float sv[4][4];
    float mt[4] = {-INFINITY, -INFINITY, -INFINITY, -INFINITY};
    #pragma unroll
    for (int t = 0; t < 4; ++t) {
      float km = kmf[16 * t + fr];
      #pragma unroll
      for (int i = 0; i < 4; ++i) {
        float sx = (km > 0.f && qm[i] > 0.f) ? sacc[t][i] * 0.125f : NEGF;
        sv[t][i] = sx;
        mt[i] = fmaxf(mt[i], sx);
      }
    }
    #pragma unroll
    for (int off = 8; off; off >>= 1)
      #pragma unroll
      for (int i = 0; i < 4; ++i) mt[i] = fmaxf(mt[i], __shfl_xor(mt[i], off));

    float r[4], psum[4];
    #pragma unroll
    for (int i = 0; i < 4; ++i) {
      float mn = fmaxf(mrow[i], mt[i]);
      r[i] = __expf(mrow[i] - mn);
      mrow[i] = mn;
      psum[i] = 0.f;
    }
    #pragma unroll
    for (int t = 0; t < 4; ++t) {
      #pragma unroll
      for (int i = 0; i < 4; ++i) {
        float p = __expf(sv[t][i] - mrow[i]);
        psum[i] += p;
        Ps[16 * w + kg * 4 + i][16 * t + fr] = (__bf16)p;
      }
    }
    #pragma unroll
    for (int off = 8; off; off >>= 1)
      #pragma unroll
      for (int i = 0; i < 4; ++i) psum[i] += __shfl_xor(psum[i], off);
    #pragma unroll
    for (int i = 0; i < 4; ++i) lrow[i] = lrow[i] * r[i] + psum[i];
    #pragma unroll
    for (int t = 0; t < 4; ++t)
      #pragma unroll
      for (int i = 0; i < 4; ++i) accO[t][i] *= r[i];

    __syncthreads();

    #pragma unroll
    for (int ks = 0; ks < 2; ++ks) {
      bf16x8 pa = *reinterpret_cast<const bf16x8*>(&Ps[16 * w + fr][ks * 32 + kg * 8]);
      #pragma unroll
      for (int t2 = 0; t2 < 4; ++t2) {
        bf16x8 vb = *reinterpret_cast<const bf16x8*>(&Vt[16 * t2 + fr][ks * 32 + kg * 8]);
        accO[t2] = __builtin_amdgcn_mfma_f32_16x16x32_bf16(pa, vb, accO[t2], 0, 0, 0);
      }
    }
  }

  float* op = s ? p1 : p0;
  #pragma unroll
  for (int t2 = 0; t2 < 4; ++t2)
    #pragma unroll
    for (int i = 0; i < 4; ++i) {
      int qrow = q0 + 16 * w + kg * 4 + i;
      int col = 16 * t2 + fr;
      op[((long)(b * Nn + qrow)) * Dd + hh * HDd + col] = accO[t2][i];  // unnormalized
    }
  if (fr == 0) {
    #pragma unroll
    for (int i = 0; i < 4; ++i) {
      int qrow = q0 + 16 * w + kg * 4 + i;
      ml[((long)(s * Bb + b) * Hh + hh) * Nn + qrow] = make_float2(mrow[i], lrow[i]);
    }
  }
}

// ---------- combine the two KV-splits: o = (w0*p0 + w1*p1) / (w0*l0 + w1*l1) ----------
__global__ __launch_bounds__(256) void flash_combine(const float* __restrict__ p0, const float* __restrict__ p1,
                                                     const float2* __restrict__ ml, float* __restrict__ o) {
  long i4 = (long)blockIdx.x * 256 + threadIdx.x;
  long i = i4 * 4;
  int d = (int)(i % Dd);
  long row = i / Dd;
  int b = (int)(row >> 10), n = (int)(row & (Nn - 1));
  int hh = d >> 6;
  float2 a = ml[((long)b * Hh + hh) * Nn + n];
  float2 c = ml[(((long)Bb + b) * Hh + hh) * Nn + n];
  float M = fmaxf(a.x, c.x);
  float w0 = __expf(a.x - M), w1 = __expf(c.x - M);
  float inv = 1.f / (w0 * a.y + w1 * c.y);
  float4 v0 = reinterpret_cast<const float4*>(p0)[i4];
  float4 v1 = reinterpret_cast<const float4*>(p1)[i4];
  float4 r;
  r.x = (w0 * v0.x + w1 * v1.x) * inv;
  r.y = (w0 * v0.y + w1 * v1.y) * inv;
  r.z = (w0 * v0.z + w1 * v1.z) * inv;
  r.w = (w0 * v0.w + w1 * v1.w) * inv;
  reinterpret_cast<float4*>(o)[i4] = r;
}

// ---------- seq-pool ----------
__global__ __launch_bounds__(256) void pool_score(const float* __restrict__ hn, const float* __restrict__ pw,
                                                  const float* __restrict__ pb, float* __restrict__ s) {
  __shared__ float smem[4];
  int row = blockIdx.x, tid = threadIdx.x;
  const float* x = hn + (size_t)row * Dd;
  float acc = 0.f;
  for (int j = 0; j < 3; ++j) { int c = tid + j * 256; acc += x[c] * pw[c]; }
  acc = block_reduce_sum(acc, smem);
  if (tid == 0) s[row] = acc + pb[0];
}

__global__ __launch_bounds__(256) void pool_softmax(const float* __restrict__ s, float* __restrict__ w) {
  __shared__ float smem[4];
  int b = blockIdx.x, tid = threadIdx.x;
  const float* x = s + b * Nn;
  float v[4];
  for (int j = 0; j < 4; ++j) v[j] = x[tid * 4 + j];
  float mx = fmaxf(fmaxf(v[0], v[1]), fmaxf(v[2], v[3]));
  mx = block_reduce_max(mx, smem);
  float e[4], sum = 0.f;
  for (int j = 0; j < 4; ++j) { e[j] = expf(v[j] - mx); sum += e[j]; }
  sum = block_reduce_sum(sum, smem);
  float inv = 1.f / sum;
  for (int j = 0; j < 4; ++j) w[b * Nn + tid * 4 + j] = e[j] * inv;
}

// stage 1: partial sums over 128-token chunks. grid (Dd/256, 8, Bb), block 256.
__global__ __launch_bounds__(256) void pool_reduce1(const float* __restrict__ hn, const float* __restrict__ w,
                                                    float* __restrict__ part) {
  int d = blockIdx.x * 256 + threadIdx.x;
  int ch = blockIdx.y, b = blockIdx.z;
  int n0 = ch * 128;
  float a0 = 0.f, a1 = 0.f;
  for (int n = n0; n < n0 + 128; n += 2) {
    a0 = fmaf(w[b * Nn + n],     hn[((size_t)(b * Nn + n))     * Dd + d], a0);
    a1 = fmaf(w[b * Nn + n + 1], hn[((size_t)(b * Nn + n + 1)) * Dd + d], a1);
  }
  part[((size_t)(b * 8 + ch)) * Dd + d] = a0 + a1;
}

// stage 2: sum 8 partials. grid (Dd/256, Bb), block 256.
__global__ __launch_bounds__(256) void pool_reduce2(const float* __restrict__ part, float* __restrict__ pooled) {
  int d = blockIdx.x * 256 + threadIdx.x;
  int b = blockIdx.y;
  float s = 0.f;
  #pragma unroll
  for (int ch = 0; ch < 8; ++ch) s += part[((size_t)(b * 8 + ch)) * Dd + d];
  pooled[b * Dd + d] = s;
}

// fc: one class per thread, coalesced over c. grid (4, Bb), block 256.
__global__ __launch_bounds__(256) void fc_kernel(const float* __restrict__ pooled, const float* __restrict__ fw,
                                                 const float* __restrict__ fb, float* __restrict__ out) {
  __shared__ float p[768];
  int b = blockIdx.y, tid = threadIdx.x;
  for (int j = 0; j < 3; ++j) p[tid + j * 256] = pooled[b * Dd + tid + j * 256];
  __syncthreads();
  int c = blockIdx.x * 256 + tid;
  if (c < NCc) {
    float a0 = 0.f, a1 = 0.f, a2 = 0.f, a3 = 0.f;
    #pragma unroll 4
    for (int d = 0; d < Dd; d += 4) {
      a0 = fmaf(p[d],     fw[(size_t)d       * NCc + c], a0);
      a1 = fmaf(p[d + 1], fw[(size_t)(d + 1) * NCc + c], a1);
      a2 = fmaf(p[d + 2], fw[(size_t)(d + 2) * NCc + c], a2);
      a3 = fmaf(p[d + 3], fw[(size_t)(d + 3) * NCc + c], a3);
    }
    out[b * NCc + c] = fb[c] + ((a0 + a1) + (a2 + a3));
  }
}

extern "C" void kernel_launch(void* const* d_in, const int* in_sizes, int n_in,
                              void* d_out, int out_size, void* d_ws, size_t ws_size,
                              hipStream_t stream) {
  const float* x      = (const float*)d_in[0];
  const void*  mask   = d_in[1];
  const float* pe     = (const float*)d_in[2];
  const float* ln0_w  = (const float*)d_in[3];
  const float* ln0_b  = (const float*)d_in[4];
  const float* qkv_w  = (const float*)d_in[5];
  const float* proj_w = (const float*)d_in[6];
  const float* proj_b = (const float*)d_in[7];
  const float* ln1_w  = (const float*)d_in[8];
  const float* ln1_b  = (const float*)d_in[9];
  const float* ff1_w  = (const float*)d_in[10];
  const float* ff1_b  = (const float*)d_in[11];
  const float* ff2_w  = (const float*)d_in[12];
  const float* ff2_b  = (const float*)d_in[13];
  const float* norm_w = (const float*)d_in[14];
  const float* norm_b = (const float*)d_in[15];
  const float* pool_w = (const float*)d_in[16];
  const float* pool_b = (const float*)d_in[17];
  const float* fc_w   = (const float*)d_in[18];
  const float* fc_b   = (const float*)d_in[19];
  float* out = (float*)d_out;

  // Compact workspace (~44.5 MB) — base layout verified in round 5.
  float* ws = (float*)d_ws;
  float* h      = ws;                        // Mm*Dd
  float* y      = h + (long)Mm * Dd;         // Mm*Dd
  float* qkvf   = y + (long)Mm * Dd;         // Mm*3*Dd
  float* o      = qkvf + (long)Mm * 3 * Dd;  // Mm*Dd
  float* hn     = o + (long)Mm * Dd;         // Mm*Dd
  float* spool  = hn + (long)Mm * Dd;        // Mm
  float* wpool  = spool + Mm;                // Mm
  float* pooled = wpool + Mm;                // Bb*Dd
  float* ppart  = pooled + Bb * Dd;          // Bb*8*Dd
  float* mlbuf  = ppart + (long)Bb * 8 * Dd; // 2*Bb*Hh*Nn float2
  int*   mflag  = (int*)(mlbuf + (long)2 * 2 * Bb * Hh * Nn);
  float* g  = qkvf;   // alias: ff1 out spans qkvf+o (both dead after flash/proj reads)
  // flash partials: p0 = y, p1 = hn; split-K partials: proj -> hn,qkvf; ff2 -> y,hn

  detect_mask<<<1, 256, 0, stream>>>((const unsigned char*)mask, mflag);
  add_pe_k<<<(Mm * Dd) / 256, 256, 0, stream>>>(x, pe, h);

  for (int l = 0; l < NLl; ++l) {
    ln_kernel<<<Mm, 256, 0, stream>>>(h, nullptr, ln0_w + l * Dd, ln0_b + l * Dd, y);

    // qkv: (Mm x 768) @ (768 x 2304) -> qkvf
    gemm128<64,0><<<dim3(3 * Dd / 64, Mm / 128, 1), 256, 0, stream>>>(
        y, Dd,
        qkv_w + (long)l * Dd * 3 * Dd, 3 * Dd,
        nullptr, nullptr,
        qkvf, 3 * Dd, Dd, 0);

    // fused attention, KV-split x2: partials -> y, hn + (m,l) -> mlbuf; combine -> o
    flash_attn_split<<<dim3(Nn / 64, Hh, Bb * 2), 256, 0, stream>>>(
        qkvf, mask, mflag, y, hn, (float2*)mlbuf);
    flash_combine<<<(Mm * Dd / 4) / 256, 256, 0, stream>>>(y, hn, (const float2*)mlbuf, o);

    // proj split-K x2: partials -> hn (z=0), qkvf (z=1); K chunk = 384
    gemm128<64,0><<<dim3(Dd / 64, Mm / 128, 2), 256, 0, stream>>>(
        o, Dd,
        proj_w + (long)l * Dd * Dd, Dd,
        nullptr, nullptr,
        hn, Dd, Dd / 2, (long)(qkvf - hn));

    // ln1 fused with proj reduction: h = LN(h + hn + qkvf + proj_b)
    ln2res_kernel<<<Mm, 256, 0, stream>>>(h, hn, qkvf, proj_b + l * Dd,
                                          ln1_w + l * Dd, ln1_b + l * Dd, h);

    // ff1: h @ ff1_w + b -> gelu -> g
    gemm128<64,2><<<dim3(FFf / 64, Mm / 128, 1), 256, 0, stream>>>(
        h, Dd,
        ff1_w + (long)l * Dd * FFf, FFf,
        ff1_b + l * FFf, nullptr,
        g, FFf, Dd, 0);

    // ff2 split-K x2: partials -> y (z=0), hn (z=1); K chunk = 1536
    gemm128<64,0><<<dim3(Dd / 64, Mm / 128, 2), 256, 0, stream>>>(
        g, FFf,
        ff2_w + (long)l * FFf * Dd, Dd,
        nullptr, nullptr,
        y, Dd, FFf / 2, (long)(hn - y));

    // h += y + hn + ff2_b
    reduce_ff2<<<(Mm * Dd / 4) / 256, 256, 0, stream>>>(h, y, hn, ff2_b + l * Dd);
  }

  ln_kernel<<<Mm, 256, 0, stream>>>(h, nullptr, norm_w, norm_b, hn);
  pool_score<<<Mm, 256, 0, stream>>>(hn, pool_w, pool_b, spool);
  pool_softmax<<<Bb, 256, 0, stream>>>(spool, wpool);
  pool_reduce1<<<dim3(Dd / 256, 8, Bb), 256, 0, stream>>>(hn, wpool, ppart);
  pool_reduce2<<<dim3(Dd / 256, Bb), 256, 0, stream>>>(ppart, pooled);
  fc_kernel<<<dim3(4, Bb), 256, 0, stream>>>(pooled, fc_w, fc_b, out);
}

// Round 14
// 2245.448 us; speedup vs baseline: 19.0486x; 1.1114x over previous
//
#include <hip/hip_runtime.h>
#include <hip/hip_bf16.h>
#include <cfloat>
#include <cmath>

typedef __bf16 bf16x8 __attribute__((ext_vector_type(8)));
typedef __bf16 bf16x4 __attribute__((ext_vector_type(4)));
typedef float  f32x4  __attribute__((ext_vector_type(4)));

static constexpr int Bb = 2, Nn = 1024, Dd = 768, Hh = 12, HDd = 64, FFf = 3072, NLl = 12, NCc = 1000;
static constexpr int Mm = Bb * Nn; // 2048
static constexpr float NEGF = -3.402823466e38f;

// ---------- reductions (256-thread blocks = 4 waves) ----------
__device__ __forceinline__ float block_reduce_sum(float v, volatile float* smem) {
  for (int o = 32; o; o >>= 1) v += __shfl_down(v, o);
  int lane = threadIdx.x & 63, w = threadIdx.x >> 6;
  __syncthreads();
  if (lane == 0) smem[w] = v;
  __syncthreads();
  return smem[0] + smem[1] + smem[2] + smem[3];
}

__device__ __forceinline__ float block_reduce_max(float v, volatile float* smem) {
  for (int o = 32; o; o >>= 1) v = fmaxf(v, __shfl_down(v, o));
  int lane = threadIdx.x & 63, w = threadIdx.x >> 6;
  __syncthreads();
  if (lane == 0) smem[w] = v;
  __syncthreads();
  return fmaxf(fmaxf(smem[0], smem[1]), fmaxf(smem[2], smem[3]));
}

// ---------- mask dtype detection: 0=int32 1=bytes 2=f32 3=int64 4=bf16 ----------
__global__ void detect_mask(const unsigned char* __restrict__ m, int* __restrict__ flag) {
  __shared__ int s_nz1, s_nz2, s_nz3, s_nz84, s_pv;
  int tid = threadIdx.x;
  if (tid == 0) { s_nz1 = 0; s_nz2 = 0; s_nz3 = 0; s_nz84 = 0; s_pv = 0; }
  __syncthreads();
  int nz1 = 0, nz2 = 0, nz3 = 0, nz84 = 0, pv = 0;
  for (int i = tid; i < 2048; i += 256) {
    unsigned char v = m[i];
    if (v) {
      int p4 = i & 3;
      if (p4 == 1) nz1 = 1;
      if (p4 == 2) nz2 = 1;
      if (p4 == 3) nz3 = 1;
      if ((i & 7) == 4) nz84 = 1;
      if ((i & 1) == 0) { if (v != 0x80) pv = 1; }
      else              { if (v != 0x3f) pv = 1; }
    }
  }
  if (nz1)  atomicOr(&s_nz1, 1);
  if (nz2)  atomicOr(&s_nz2, 1);
  if (nz3)  atomicOr(&s_nz3, 1);
  if (nz84) atomicOr(&s_nz84, 1);
  if (pv)   atomicOr(&s_pv, 1);
  __syncthreads();
  if (tid == 0) {
    int f;
    if (!s_nz1 && !s_nz2 && !s_nz3) f = s_nz84 ? 0 : 3;
    else if (!s_pv)                 f = s_nz1 ? 4 : 2;
    else                            f = 1;
    *flag = f;
  }
}

__device__ __forceinline__ bool mask_at(const void* mraw, int flag, int idx) {
  switch (flag) {
    case 0:  return ((const int*)mraw)[idx] != 0;
    case 1:  return ((const unsigned char*)mraw)[idx] != 0;
    case 2:  return ((const float*)mraw)[idx] != 0.f;
    case 3:  return ((const long long*)mraw)[idx] != 0;
    default: return ((const unsigned short*)mraw)[idx] != 0;
  }
}

// ---------- h = x + pe (pe broadcast over batch) ----------
__global__ __launch_bounds__(256) void add_pe_k(const float* __restrict__ x, const float* __restrict__ pe,
                                                float* __restrict__ h) {
  long i = (long)blockIdx.x * 256 + threadIdx.x;
  long nd = i % ((long)Nn * Dd);
  h[i] = x[i] + pe[nd];
}

// ---------- LayerNorm; OBF=1 writes bf16 output ----------
template<int OBF>
__global__ __launch_bounds__(256) void ln_kernel(const float* __restrict__ X,
                                                 const float* __restrict__ w, const float* __restrict__ b,
                                                 void* __restrict__ Y) {
  __shared__ float smem[4];
  int row = blockIdx.x, tid = threadIdx.x;
  const float* x = X + (size_t)row * Dd;
  float v[3];
  for (int j = 0; j < 3; ++j) v[j] = x[tid + j * 256];
  float s = v[0] + v[1] + v[2];
  s = block_reduce_sum(s, smem);
  float mean = s * (1.f / 768.f);
  float q = 0.f;
  for (int j = 0; j < 3; ++j) { float d = v[j] - mean; q += d * d; }
  q = block_reduce_sum(q, smem);
  float inv = rsqrtf(q * (1.f / 768.f) + 1e-5f);
  for (int j = 0; j < 3; ++j) {
    int c = tid + j * 256;
    float r = (v[j] - mean) * inv * w[c] + b[c];
    if (OBF) ((__bf16*)Y)[(size_t)row * Dd + c] = (__bf16)r;
    else     ((float*)Y)[(size_t)row * Dd + c] = r;
  }
}

// ---------- LayerNorm over (h + p0 + p1 + bias): writes h (f32) and hb (bf16) ----------
__global__ __launch_bounds__(256) void ln2res_kernel(float* __restrict__ H,
                                                     const float* __restrict__ P0, const float* __restrict__ P1,
                                                     const float* __restrict__ pb,
                                                     const float* __restrict__ w, const float* __restrict__ b,
                                                     __bf16* __restrict__ Hb) {
  __shared__ float smem[4];
  int row = blockIdx.x, tid = threadIdx.x;
  float* x  = H  + (size_t)row * Dd;
  const float* p0 = P0 + (size_t)row * Dd;
  const float* p1 = P1 + (size_t)row * Dd;
  float v[3];
  for (int j = 0; j < 3; ++j) {
    int c = tid + j * 256;
    v[j] = x[c] + (p0[c] + p1[c] + pb[c]);
  }
  float s = v[0] + v[1] + v[2];
  s = block_reduce_sum(s, smem);
  float mean = s * (1.f / 768.f);
  float q = 0.f;
  for (int j = 0; j < 3; ++j) { float d = v[j] - mean; q += d * d; }
  q = block_reduce_sum(q, smem);
  float inv = rsqrtf(q * (1.f / 768.f) + 1e-5f);
  for (int j = 0; j < 3; ++j) {
    int c = tid + j * 256;
    float r = (v[j] - mean) * inv * w[c] + b[c];
    x[c] = r;
    Hb[(size_t)row * Dd + c] = (__bf16)r;
  }
}

// ---------- ff2 split-K reduction: h += p0 + p1 + bias (float4) ----------
__global__ __launch_bounds__(256) void reduce_ff2(float* __restrict__ h, const float* __restrict__ p0,
                                                  const float* __restrict__ p1, const float* __restrict__ bias) {
  long i4 = (long)blockIdx.x * 256 + threadIdx.x;
  int col4 = (int)(i4 % (Dd / 4));
  float4 hv = reinterpret_cast<const float4*>(h)[i4];
  float4 a  = reinterpret_cast<const float4*>(p0)[i4];
  float4 c  = reinterpret_cast<const float4*>(p1)[i4];
  float4 bb = reinterpret_cast<const float4*>(bias)[col4];
  hv.x += a.x + c.x + bb.x;
  hv.y += a.y + c.y + bb.y;
  hv.z += a.z + c.z + bb.z;
  hv.w += a.w + c.w + bb.w;
  reinterpret_cast<float4*>(h)[i4] = hv;
}

// ---------- split helper (B weights) ----------
__device__ __forceinline__ void split8v(const float* __restrict__ v, bf16x8& hi, bf16x8& lo) {
  for (int j = 0; j < 8; ++j) {
    __bf16 h = (__bf16)v[j];
    hi[j] = h;
    lo[j] = (__bf16)(v[j] - (float)h);
  }
}

// ---------- 128xBN MFMA GEMM: A bf16 (direct), B f32 split hi/lo, reg prefetch,
// ---------- XCD chunk swizzle, optional split-K, optional bf16 output ----------
// EPI: 0 none, 1 +bias, 2 +bias->exact gelu.  grid: (Nsz/BN, Msz/128, nchunks).
template<int BN, int EPI, int OBF>
__global__ __launch_bounds__(256) void gemm128(
    const __bf16* __restrict__ Ap, long lda,
    const float* __restrict__ Bp, long ldb,
    const float* __restrict__ bias,
    void* __restrict__ Cp, long ldc,
    int Ksize, long czs)
{
  constexpr int FN = BN / 32;
  constexpr int KB = BN / 8;
  int tid = threadIdx.x;

  int nwg2 = gridDim.x * gridDim.y;
  int bid = blockIdx.y * gridDim.x + blockIdx.x;
  int swz = (bid & 7) * (nwg2 >> 3) + (bid >> 3);
  int bx = swz % gridDim.x, by = swz / gridDim.x;
  int m0 = by * 128, n0 = bx * BN;
  int z = blockIdx.z;

  const __bf16* Aq = Ap + (long)z * Ksize;
  const float* Bq = Bp + (long)z * Ksize * ldb;

  __shared__ __align__(16) __bf16 Ah[128][40];
  __shared__ __align__(16) __bf16 Bh[BN][40], Bl[BN][40];

  f32x4 acc[4][FN];
  #pragma unroll
  for (int i = 0; i < 4; ++i)
    #pragma unroll
    for (int j = 0; j < FN; ++j)
      #pragma unroll
      for (int k = 0; k < 4; ++k) acc[i][j][k] = 0.f;

  int lane = tid & 63;
  int w = tid >> 6;
  int WR = (w >> 1) * 64, WC = (w & 1) * (BN / 2);
  int fr = lane & 15, kg = lane >> 4;

  const int ar = tid >> 1, acs = (tid & 1) * 16;
  const int bn = tid % BN;
  const int kb = (tid / BN) * KB;

  const __bf16* Abase = Aq + (long)(m0 + ar) * lda + acs;
  const float* Bbase = Bq + (long)kb * ldb + (n0 + bn);

  bf16x8 pa0, pa1;
  float pb[KB];
  {
    pa0 = *reinterpret_cast<const bf16x8*>(Abase);
    pa1 = *reinterpret_cast<const bf16x8*>(Abase + 8);
    #pragma unroll
    for (int j = 0; j < KB; ++j) pb[j] = Bbase[(long)j * ldb];
  }

  for (int k0 = 0; k0 < Ksize; k0 += 32) {
    __syncthreads();
    {
      *reinterpret_cast<bf16x8*>(&Ah[ar][acs]) = pa0;
      *reinterpret_cast<bf16x8*>(&Ah[ar][acs + 8]) = pa1;
      #pragma unroll
      for (int g8 = 0; g8 < KB / 8; ++g8) {
        bf16x8 bth, btl;
        split8v(&pb[g8 * 8], bth, btl);
        *reinterpret_cast<bf16x8*>(&Bh[bn][kb + g8 * 8]) = bth;
        *reinterpret_cast<bf16x8*>(&Bl[bn][kb + g8 * 8]) = btl;
      }
    }
    __syncthreads();

    if (k0 + 32 < Ksize) {
      const __bf16* As = Abase + (k0 + 32);
      pa0 = *reinterpret_cast<const bf16x8*>(As);
      pa1 = *reinterpret_cast<const bf16x8*>(As + 8);
      const float* Bs = Bbase + (long)(k0 + 32) * ldb;
      #pragma unroll
      for (int j = 0; j < KB; ++j) pb[j] = Bs[(long)j * ldb];
    }

    bf16x8 ah[4], bh[FN], bl[FN];
    #pragma unroll
    for (int fm = 0; fm < 4; ++fm)
      ah[fm] = *reinterpret_cast<const bf16x8*>(&Ah[WR + fm * 16 + fr][kg * 8]);
    #pragma unroll
    for (int fn = 0; fn < FN; ++fn) {
      bh[fn] = *reinterpret_cast<const bf16x8*>(&Bh[WC + fn * 16 + fr][kg * 8]);
      bl[fn] = *reinterpret_cast<const bf16x8*>(&Bl[WC + fn * 16 + fr][kg * 8]);
    }
    #pragma unroll
    for (int fm = 0; fm < 4; ++fm)
      #pragma unroll
      for (int fn = 0; fn < FN; ++fn) {
        acc[fm][fn] = __builtin_amdgcn_mfma_f32_16x16x32_bf16(ah[fm], bh[fn], acc[fm][fn], 0, 0, 0);
        acc[fm][fn] = __builtin_amdgcn_mfma_f32_16x16x32_bf16(ah[fm], bl[fn], acc[fm][fn], 0, 0, 0);
      }
  }

  #pragma unroll
  for (int fm = 0; fm < 4; ++fm)
    #pragma unroll
    for (int fn = 0; fn < FN; ++fn)
      #pragma unroll
      for (int i = 0; i < 4; ++i) {
        int rowg = m0 + WR + fm * 16 + kg * 4 + i;
        int coln = n0 + WC + fn * 16 + fr;
        float v = acc[fm][fn][i];
        if (EPI >= 1) v += bias[coln];
        if (EPI == 2) v = 0.5f * v * (1.f + erff(v * 0.70710678118654752f));
        long ci = (long)z * czs + (long)rowg * ldc + coln;
        if (OBF) ((__bf16*)Cp)[ci] = (__bf16)v;
        else     ((float*)Cp)[ci] = v;
      }
}

// ---------- MFMA flash attention, KV-split x2, bf16 qkv input, register prefetch ----------
__global__ __launch_bounds__(256) void flash_attn_split(const __bf16* __restrict__ qkvb,
                                                        const void* __restrict__ mraw,
                                                        const int* __restrict__ flagp,
                                                        float* __restrict__ p0, float* __restrict__ p1,
                                                        float2* __restrict__ ml) {
  __shared__ __align__(16) __bf16 Qs[64][72];
  __shared__ __align__(16) __bf16 Ks[64][72];
  __shared__ __align__(16) __bf16 Vt[64][66];  // V transposed: [d][key]
  __shared__ __align__(16) __bf16 Ps[64][72];
  __shared__ float kmf[64];
  __shared__ float qmf[64];

  int s = blockIdx.z & 1, b = blockIdx.z >> 1;
  int hh = blockIdx.y;
  int q0 = blockIdx.x * 64;
  int tid = threadIdx.x, lane = tid & 63, w = tid >> 6;
  int flag = *flagp;
  int fr = lane & 15, kg = lane >> 4;

  const int sr = tid >> 2;
  const int sc = (tid & 3) * 16;

  {
    const __bf16* Qsrc = qkvb + ((long)(b * Nn + q0 + sr)) * (3 * Dd) + hh * HDd + sc;
    *reinterpret_cast<bf16x8*>(&Qs[sr][sc])     = *reinterpret_cast<const bf16x8*>(Qsrc);
    *reinterpret_cast<bf16x8*>(&Qs[sr][sc + 8]) = *reinterpret_cast<const bf16x8*>(Qsrc + 8);
    if (tid < 64) qmf[tid] = mask_at(mraw, flag, b * Nn + q0 + tid) ? 1.f : 0.f;
  }
  __syncthreads();

  float qm[4];
  #pragma unroll
  for (int i = 0; i < 4; ++i) qm[i] = qmf[16 * w + kg * 4 + i];

  bf16x8 qa[2];
  #pragma unroll
  for (int ks = 0; ks < 2; ++ks)
    qa[ks] = *reinterpret_cast<const bf16x8*>(&Qs[16 * w + fr][ks * 32 + kg * 8]);

  float mrow[4], lrow[4];
  f32x4 accO[4];
  #pragma unroll
  for (int i = 0; i < 4; ++i) { mrow[i] = -INFINITY; lrow[i] = 0.f; }
  #pragma unroll
  for (int t = 0; t < 4; ++t)
    for (int i = 0; i < 4; ++i) accO[t][i] = 0.f;

  const int jbeg = s * (Nn / 2), jend = jbeg + (Nn / 2);

  bf16x8 rk0, rk1, rv0, rv1;
  {
    const __bf16* Ksrc = qkvb + ((long)(b * Nn + jbeg + sr)) * (3 * Dd) + Dd + hh * HDd + sc;
    const __bf16* Vsrc = Ksrc + Dd;
    rk0 = *reinterpret_cast<const bf16x8*>(Ksrc);
    rk1 = *reinterpret_cast<const bf16x8*>(Ksrc + 8);
    rv0 = *reinterpret_cast<const bf16x8*>(Vsrc);
    rv1 = *reinterpret_cast<const bf16x8*>(Vsrc + 8);
  }

  for (int j0 = jbeg; j0 < jend; j0 += 64) {
    __syncthreads();
    {
      *reinterpret_cast<bf16x8*>(&Ks[sr][sc])     = rk0;
      *reinterpret_cast<bf16x8*>(&Ks[sr][sc + 8]) = rk1;
      #pragma unroll
      for (int j = 0; j < 8; ++j) {
        Vt[sc + j][sr]     = rv0[j];
        Vt[sc + 8 + j][sr] = rv1[j];
      }
      if (tid < 64) kmf[tid] = mask_at(mraw, flag, b * Nn + j0 + tid) ? 1.f : 0.f;
    }
    __syncthreads();

    if (j0 + 64 < jend) {
      const __bf16* Ksrc = qkvb + ((long)(b * Nn + j0 + 64 + sr)) * (3 * Dd) + Dd + hh * HDd + sc;
      const __bf16* Vsrc = Ksrc + Dd;
      rk0 = *reinterpret_cast<const bf16x8*>(Ksrc);
      rk1 = *reinterpret_cast<const bf16x8*>(Ksrc + 8);
      rv0 = *reinterpret_cast<const bf16x8*>(Vsrc);
      rv1 = *reinterpret_cast<const bf16x8*>(Vsrc + 8);
    }

    f32x4 sacc[4];
    #pragma unroll
    for (int t = 0; t < 4; ++t)
      for (int i = 0; i < 4; ++i) sacc[t][i] = 0.f;
    #pragma unroll
    for (int ks = 0; ks < 2; ++ks) {
      #pragma unroll
      for (int t = 0; t < 4; ++t) {
        bf16x8 bh = *reinterpret_cast<const bf16x8*>(&Ks[16 * t + fr][ks * 32 + kg * 8]);
        sacc[t] = __builtin_amdgcn_mfma_f32_16x16x32_bf16(qa[ks], bh, sacc[t], 0, 0, 0);
      }
    }

    float sv[4][4];
    float mt[4] = {-INFINITY, -INFINITY, -INFINITY, -INFINITY};
    #pragma unroll
    for (int t = 0; t < 4; ++t) {
      float km = kmf[16 * t + fr];
      #pragma unroll
      for (int i = 0; i < 4; ++i) {
        float sx = (km > 0.f && qm[i] > 0.f) ? sacc[t][i] * 0.125f : NEGF;
        sv[t][i] = sx;
        mt[i] = fmaxf(mt[i], sx);
      }
    }
    #pragma unroll
    for (int off = 8; off; off >>= 1)
      #pragma unroll
      for (int i = 0; i < 4; ++i) mt[i] = fmaxf(mt[i], __shfl_xor(mt[i], off));

    float r[4], psum[4];
    #pragma unroll
    for (int i = 0; i < 4; ++i) {
      float mn = fmaxf(mrow[i], mt[i]);
      r[i] = __expf(mrow[i] - mn);
      mrow[i] = mn;
      psum[i] = 0.f;
    }
    #pragma unroll
    for (int t = 0; t < 4; ++t) {
      #pragma unroll
      for (int i = 0; i < 4; ++i) {
        float p = __expf(sv[t][i] - mrow[i]);
        psum[i] += p;
        Ps[16 * w + kg * 4 + i][16 * t + fr] = (__bf16)p;
      }
    }
    #pragma unroll
    for (int off = 8; off; off >>= 1)
      #pragma unroll
      for (int i = 0; i < 4; ++i) psum[i] += __shfl_xor(psum[i], off);
    #pragma unroll
    for (int i = 0; i < 4; ++i) lrow[i] = lrow[i] * r[i] + psum[i];
    #pragma unroll
    for (int t = 0; t < 4; ++t)
      #pragma unroll
      for (int i = 0; i < 4; ++i) accO[t][i] *= r[i];

    __syncthreads();

    #pragma unroll
    for (int ks = 0; ks < 2; ++ks) {
      bf16x8 pa = *reinterpret_cast<const bf16x8*>(&Ps[16 * w + fr][ks * 32 + kg * 8]);
      #pragma unroll
      for (int t2 = 0; t2 < 4; ++t2) {
        bf16x8 vb = *reinterpret_cast<const bf16x8*>(&Vt[16 * t2 + fr][ks * 32 + kg * 8]);
        accO[t2] = __builtin_amdgcn_mfma_f32_16x16x32_bf16(pa, vb, accO[t2], 0, 0, 0);
      }
    }
  }

  float* op = s ? p1 : p0;
  #pragma unroll
  for (int t2 = 0; t2 < 4; ++t2)
    #pragma unroll
    for (int i = 0; i < 4; ++i) {
      int qrow = q0 + 16 * w + kg * 4 + i;
      int col = 16 * t2 + fr;
      op[((long)(b * Nn + qrow)) * Dd + hh * HDd + col] = accO[t2][i];  // unnormalized
    }
  if (fr == 0) {
    #pragma unroll
    for (int i = 0; i < 4; ++i) {
      int qrow = q0 + 16 * w + kg * 4 + i;
      ml[((long)(s * Bb + b) * Hh + hh) * Nn + qrow] = make_float2(mrow[i], lrow[i]);
    }
  }
}

// ---------- combine two KV-splits -> bf16 attn output ----------
__global__ __launch_bounds__(256) void flash_combine(const float* __restrict__ p0, const float* __restrict__ p1,
                                                     const float2* __restrict__ ml, __bf16* __restrict__ ob) {
  long i4 = (long)blockIdx.x * 256 + threadIdx.x;
  long i = i4 * 4;
  int d = (int)(i % Dd);
  long row = i / Dd;
  int b = (int)(row >> 10), n = (int)(row & (Nn - 1));
  int hh = d >> 6;
  float2 a = ml[((long)b * Hh + hh) * Nn + n];
  float2 c = ml[(((long)Bb + b) * Hh + hh) * Nn + n];
  float M = fmaxf(a.x, c.x);
  float w0 = __expf(a.x - M), w1 = __expf(c.x - M);
  float inv = 1.f / (w0 * a.y + w1 * c.y);
  float4 v0 = reinterpret_cast<const float4*>(p0)[i4];
  float4 v1 = reinterpret_cast<const float4*>(p1)[i4];
  bf16x4 r;
  r[0] = (__bf16)((w0 * v0.x + w1 * v1.x) * inv);
  r[1] = (__bf16)((w0 * v0.y + w1 * v1.y) * inv);
  r[2] = (__bf16)((w0 * v0.z + w1 * v1.z) * inv);
  r[3] = (__bf16)((w0 * v0.w + w1 * v1.w) * inv);
  *reinterpret_cast<bf16x4*>(&ob[i]) = r;
}

// ---------- seq-pool ----------
__global__ __launch_bounds__(256) void pool_score(const float* __restrict__ hn, const float* __restrict__ pw,
                                                  const float* __restrict__ pb, float* __restrict__ s) {
  __shared__ float smem[4];
  int row = blockIdx.x, tid = threadIdx.x;
  const float* x = hn + (size_t)row * Dd;
  float acc = 0.f;
  for (int j = 0; j < 3; ++j) { int c = tid + j * 256; acc += x[c] * pw[c]; }
  acc = block_reduce_sum(acc, smem);
  if (tid == 0) s[row] = acc + pb[0];
}

__global__ __launch_bounds__(256) void pool_softmax(const float* __restrict__ s, float* __restrict__ w) {
  __shared__ float smem[4];
  int b = blockIdx.x, tid = threadIdx.x;
  const float* x = s + b * Nn;
  float v[4];
  for (int j = 0; j < 4; ++j) v[j] = x[tid * 4 + j];
  float mx = fmaxf(fmaxf(v[0], v[1]), fmaxf(v[2], v[3]));
  mx = block_reduce_max(mx, smem);
  float e[4], sum = 0.f;
  for (int j = 0; j < 4; ++j) { e[j] = expf(v[j] - mx); sum += e[j]; }
  sum = block_reduce_sum(sum, smem);
  float inv = 1.f / sum;
  for (int j = 0; j < 4; ++j) w[b * Nn + tid * 4 + j] = e[j] * inv;
}

// stage 1: partial sums over 128-token chunks. grid (Dd/256, 8, Bb), block 256.
__global__ __launch_bounds__(256) void pool_reduce1(const float* __restrict__ hn, const float* __restrict__ w,
                                                    float* __restrict__ part) {
  int d = blockIdx.x * 256 + threadIdx.x;
  int ch = blockIdx.y, b = blockIdx.z;
  int n0 = ch * 128;
  float a0 = 0.f, a1 = 0.f;
  for (int n = n0; n < n0 + 128; n += 2) {
    a0 = fmaf(w[b * Nn + n],     hn[((size_t)(b * Nn + n))     * Dd + d], a0);
    a1 = fmaf(w[b * Nn + n + 1], hn[((size_t)(b * Nn + n + 1)) * Dd + d], a1);
  }
  part[((size_t)(b * 8 + ch)) * Dd + d] = a0 + a1;
}

// stage 2: sum 8 partials. grid (Dd/256, Bb), block 256.
__global__ __launch_bounds__(256) void pool_reduce2(const float* __restrict__ part, float* __restrict__ pooled) {
  int d = blockIdx.x * 256 + threadIdx.x;
  int b = blockIdx.y;
  float s = 0.f;
  #pragma unroll
  for (int ch = 0; ch < 8; ++ch) s += part[((size_t)(b * 8 + ch)) * Dd + d];
  pooled[b * Dd + d] = s;
}

// fc: one class per thread, coalesced over c. grid (4, Bb), block 256.
__global__ __launch_bounds__(256) void fc_kernel(const float* __restrict__ pooled, const float* __restrict__ fw,
                                                 const float* __restrict__ fb, float* __restrict__ out) {
  __shared__ float p[768];
  int b = blockIdx.y, tid = threadIdx.x;
  for (int j = 0; j < 3; ++j) p[tid + j * 256] = pooled[b * Dd + tid + j * 256];
  __syncthreads();
  int c = blockIdx.x * 256 + tid;
  if (c < NCc) {
    float a0 = 0.f, a1 = 0.f, a2 = 0.f, a3 = 0.f;
    #pragma unroll 4
    for (int d = 0; d < Dd; d += 4) {
      a0 = fmaf(p[d],     fw[(size_t)d       * NCc + c], a0);
      a1 = fmaf(p[d + 1], fw[(size_t)(d + 1) * NCc + c], a1);
      a2 = fmaf(p[d + 2], fw[(size_t)(d + 2) * NCc + c], a2);
      a3 = fmaf(p[d + 3], fw[(size_t)(d + 3) * NCc + c], a3);
    }
    out[b * NCc + c] = fb[c] + ((a0 + a1) + (a2 + a3));
  }
}

extern "C" void kernel_launch(void* const* d_in, const int* in_sizes, int n_in,
                              void* d_out, int out_size, void* d_ws, size_t ws_size,
                              hipStream_t stream) {
  const float* x      = (const float*)d_in[0];
  const void*  mask   = d_in[1];
  const float* pe     = (const float*)d_in[2];
  const float* ln0_w  = (const float*)d_in[3];
  const float* ln0_b  = (const float*)d_in[4];
  const float* qkv_w  = (const float*)d_in[5];
  const float* proj_w = (const float*)d_in[6];
  const float* proj_b = (const float*)d_in[7];
  const float* ln1_w  = (const float*)d_in[8];
  const float* ln1_b  = (const float*)d_in[9];
  const float* ff1_w  = (const float*)d_in[10];
  const float* ff1_b  = (const float*)d_in[11];
  const float* ff2_w  = (const float*)d_in[12];
  const float* ff2_b  = (const float*)d_in[13];
  const float* norm_w = (const float*)d_in[14];
  const float* norm_b = (const float*)d_in[15];
  const float* pool_w = (const float*)d_in[16];
  const float* pool_b = (const float*)d_in[17];
  const float* fc_w   = (const float*)d_in[18];
  const float* fc_b   = (const float*)d_in[19];
  float* out = (float*)d_out;

  // Workspace ~35.4 MB (< 44.5 MB verified). bf16 activations, f32 residual + partials.
  float* ws = (float*)d_ws;
  float*  h     = ws;                            // Mm*Dd f32 (residual)
  float*  s0    = h + (long)Mm * Dd;             // Mm*Dd f32 scratch (flash/proj/ff2 partials)
  float*  s1    = s0 + (long)Mm * Dd;            // Mm*Dd f32 scratch
  __bf16* qkvb  = (__bf16*)(s1 + (long)Mm * Dd); // Mm*3*Dd bf16
  __bf16* ob    = qkvb + (long)Mm * 3 * Dd;      // Mm*Dd bf16 (attn out)
  __bf16* yb    = ob + (long)Mm * Dd;            // Mm*Dd bf16 (ln0 out; reused as ln1 out)
  float*  tail  = (float*)(yb + (long)Mm * Dd);
  float*  spool  = tail;                         // Mm
  float*  wpool  = spool + Mm;                   // Mm
  float*  pooled = wpool + Mm;                   // Bb*Dd
  float*  ppart  = pooled + Bb * Dd;             // Bb*8*Dd
  float*  mlbuf  = ppart + (long)Bb * 8 * Dd;    // 2*Bb*Hh*Nn float2
  int*    mflag  = (int*)(mlbuf + (long)2 * 2 * Bb * Hh * Nn);
  __bf16* gb = qkvb;     // alias: gelu out Mm*FFf bf16 == qkvb+ob region exactly
  float*  hn = s0;       // final LN out (after loop; s0 free)

  detect_mask<<<1, 256, 0, stream>>>((const unsigned char*)mask, mflag);
  add_pe_k<<<(Mm * Dd) / 256, 256, 0, stream>>>(x, pe, h);

  for (int l = 0; l < NLl; ++l) {
    ln_kernel<1><<<Mm, 256, 0, stream>>>(h, ln0_w + l * Dd, ln0_b + l * Dd, yb);

    // qkv: bf16(Mm x 768) @ f32split(768 x 2304) -> bf16 qkvb
    gemm128<64,0,1><<<dim3(3 * Dd / 64, Mm / 128, 1), 256, 0, stream>>>(
        yb, Dd,
        qkv_w + (long)l * Dd * 3 * Dd, 3 * Dd,
        nullptr,
        qkvb, 3 * Dd, Dd, 0);

    // fused attention, KV-split x2: partials -> s0, s1 + (m,l) -> mlbuf; combine -> ob (bf16)
    flash_attn_split<<<dim3(Nn / 64, Hh, Bb * 2), 256, 0, stream>>>(
        qkvb, mask, mflag, s0, s1, (float2*)mlbuf);
    flash_combine<<<(Mm * Dd / 4) / 256, 256, 0, stream>>>(s0, s1, (const float2*)mlbuf, ob);

    // proj split-K x2: bf16 ob @ f32split -> f32 partials s0 (z=0), s1 (z=1); K chunk = 384
    gemm128<64,0,0><<<dim3(Dd / 64, Mm / 128, 2), 256, 0, stream>>>(
        ob, Dd,
        proj_w + (long)l * Dd * Dd, Dd,
        nullptr,
        s0, Dd, Dd / 2, (long)(s1 - s0));

    // ln1 fused with proj reduction: h = LN(h + s0 + s1 + proj_b); also writes bf16 yb
    ln2res_kernel<<<Mm, 256, 0, stream>>>(h, s0, s1, proj_b + l * Dd,
                                          ln1_w + l * Dd, ln1_b + l * Dd, yb);

    // ff1: bf16 yb @ f32split + b -> gelu -> bf16 gb
    gemm128<64,2,1><<<dim3(FFf / 64, Mm / 128, 1), 256, 0, stream>>>(
        yb, Dd,
        ff1_w + (long)l * Dd * FFf, FFf,
        ff1_b + l * FFf,
        gb, FFf, Dd, 0);

    // ff2 split-K x2: bf16 gb @ f32split -> f32 partials s0 (z=0), s1 (z=1); K chunk = 1536
    gemm128<64,0,0><<<dim3(Dd / 64, Mm / 128, 2), 256, 0, stream>>>(
        gb, FFf,
        ff2_w + (long)l * FFf * Dd, Dd,
        nullptr,
        s0, Dd, FFf / 2, (long)(s1 - s0));

    // h += s0 + s1 + ff2_b
    reduce_ff2<<<(Mm * Dd / 4) / 256, 256, 0, stream>>>(h, s0, s1, ff2_b + l * Dd);
  }

  ln_kernel<0><<<Mm, 256, 0, stream>>>(h, norm_w, norm_b, hn);
  pool_score<<<Mm, 256, 0, stream>>>(hn, pool_w, pool_b, spool);
  pool_softmax<<<Bb, 256, 0, stream>>>(spool, wpool);
  pool_reduce1<<<dim3(Dd / 256, 8, Bb), 256, 0, stream>>>(hn, wpool, ppart);
  pool_reduce2<<<dim3(Dd / 256, Bb), 256, 0, stream>>>(ppart, pooled);
  fc_kernel<<<dim3(4, Bb), 256, 0, stream>>>(pooled, fc_w, fc_b, out);
}

// Round 16
// 2113.156 us; speedup vs baseline: 20.2412x; 1.0626x over previous
//
#include <hip/hip_runtime.h>
#include <hip/hip_bf16.h>
#include <cfloat>
#include <cmath>

typedef __bf16 bf16x8 __attribute__((ext_vector_type(8)));
typedef __bf16 bf16x4 __attribute__((ext_vector_type(4)));
typedef float  f32x4  __attribute__((ext_vector_type(4)));

static constexpr int Bb = 2, Nn = 1024, Dd = 768, Hh = 12, HDd = 64, FFf = 3072, NLl = 12, NCc = 1000;
static constexpr int Mm = Bb * Nn; // 2048
static constexpr float NEGF = -3.402823466e38f;

// ---------- reductions (256-thread blocks = 4 waves) ----------
__device__ __forceinline__ float block_reduce_sum(float v, volatile float* smem) {
  for (int o = 32; o; o >>= 1) v += __shfl_down(v, o);
  int lane = threadIdx.x & 63, w = threadIdx.x >> 6;
  __syncthreads();
  if (lane == 0) smem[w] = v;
  __syncthreads();
  return smem[0] + smem[1] + smem[2] + smem[3];
}

__device__ __forceinline__ float block_reduce_max(float v, volatile float* smem) {
  for (int o = 32; o; o >>= 1) v = fmaxf(v, __shfl_down(v, o));
  int lane = threadIdx.x & 63, w = threadIdx.x >> 6;
  __syncthreads();
  if (lane == 0) smem[w] = v;
  __syncthreads();
  return fmaxf(fmaxf(smem[0], smem[1]), fmaxf(smem[2], smem[3]));
}

// ---------- mask dtype detection: 0=int32 1=bytes 2=f32 3=int64 4=bf16 ----------
__global__ void detect_mask(const unsigned char* __restrict__ m, int* __restrict__ flag) {
  __shared__ int s_nz1, s_nz2, s_nz3, s_nz84, s_pv;
  int tid = threadIdx.x;
  if (tid == 0) { s_nz1 = 0; s_nz2 = 0; s_nz3 = 0; s_nz84 = 0; s_pv = 0; }
  __syncthreads();
  int nz1 = 0, nz2 = 0, nz3 = 0, nz84 = 0, pv = 0;
  for (int i = tid; i < 2048; i += 256) {
    unsigned char v = m[i];
    if (v) {
      int p4 = i & 3;
      if (p4 == 1) nz1 = 1;
      if (p4 == 2) nz2 = 1;
      if (p4 == 3) nz3 = 1;
      if ((i & 7) == 4) nz84 = 1;
      if ((i & 1) == 0) { if (v != 0x80) pv = 1; }
      else              { if (v != 0x3f) pv = 1; }
    }
  }
  if (nz1)  atomicOr(&s_nz1, 1);
  if (nz2)  atomicOr(&s_nz2, 1);
  if (nz3)  atomicOr(&s_nz3, 1);
  if (nz84) atomicOr(&s_nz84, 1);
  if (pv)   atomicOr(&s_pv, 1);
  __syncthreads();
  if (tid == 0) {
    int f;
    if (!s_nz1 && !s_nz2 && !s_nz3) f = s_nz84 ? 0 : 3;
    else if (!s_pv)                 f = s_nz1 ? 4 : 2;
    else                            f = 1;
    *flag = f;
  }
}

__device__ __forceinline__ bool mask_at(const void* mraw, int flag, int idx) {
  switch (flag) {
    case 0:  return ((const int*)mraw)[idx] != 0;
    case 1:  return ((const unsigned char*)mraw)[idx] != 0;
    case 2:  return ((const float*)mraw)[idx] != 0.f;
    case 3:  return ((const long long*)mraw)[idx] != 0;
    default: return ((const unsigned short*)mraw)[idx] != 0;
  }
}

// ---------- h = x + pe (pe broadcast over batch) ----------
__global__ __launch_bounds__(256) void add_pe_k(const float* __restrict__ x, const float* __restrict__ pe,
                                                float* __restrict__ h) {
  long i = (long)blockIdx.x * 256 + threadIdx.x;
  long nd = i % ((long)Nn * Dd);
  h[i] = x[i] + pe[nd];
}

// ---------- LayerNorm; OBF=1 writes bf16 output ----------
template<int OBF>
__global__ __launch_bounds__(256) void ln_kernel(const float* __restrict__ X,
                                                 const float* __restrict__ w, const float* __restrict__ b,
                                                 void* __restrict__ Y) {
  __shared__ float smem[4];
  int row = blockIdx.x, tid = threadIdx.x;
  const float* x = X + (size_t)row * Dd;
  float v[3];
  for (int j = 0; j < 3; ++j) v[j] = x[tid + j * 256];
  float s = v[0] + v[1] + v[2];
  s = block_reduce_sum(s, smem);
  float mean = s * (1.f / 768.f);
  float q = 0.f;
  for (int j = 0; j < 3; ++j) { float d = v[j] - mean; q += d * d; }
  q = block_reduce_sum(q, smem);
  float inv = rsqrtf(q * (1.f / 768.f) + 1e-5f);
  for (int j = 0; j < 3; ++j) {
    int c = tid + j * 256;
    float r = (v[j] - mean) * inv * w[c] + b[c];
    if (OBF) ((__bf16*)Y)[(size_t)row * Dd + c] = (__bf16)r;
    else     ((float*)Y)[(size_t)row * Dd + c] = r;
  }
}

// ---------- residual + LayerNorm: v = h + p0 + p1 + bias; Y = LN(v).
// HRES=0 (post-LN attn stage): h <- LN(v)   [reference: h = layernorm(h + o)]
// HRES=1 (ff2 stage / final):  h <- v       [reference: h = h + ff]
// OBF=1 -> bf16 Y.
template<int OBF, int HRES>
__global__ __launch_bounds__(256) void res_ln_kernel(float* __restrict__ H,
                                                     const float* __restrict__ P0, const float* __restrict__ P1,
                                                     const float* __restrict__ pb,
                                                     const float* __restrict__ w, const float* __restrict__ b,
                                                     void* __restrict__ Y) {
  __shared__ float smem[4];
  int row = blockIdx.x, tid = threadIdx.x;
  float* x  = H  + (size_t)row * Dd;
  const float* p0 = P0 + (size_t)row * Dd;
  const float* p1 = P1 + (size_t)row * Dd;
  float v[3];
  for (int j = 0; j < 3; ++j) {
    int c = tid + j * 256;
    v[j] = x[c] + (p0[c] + p1[c] + pb[c]);
  }
  float s = v[0] + v[1] + v[2];
  s = block_reduce_sum(s, smem);
  float mean = s * (1.f / 768.f);
  float q = 0.f;
  for (int j = 0; j < 3; ++j) { float d = v[j] - mean; q += d * d; }
  q = block_reduce_sum(q, smem);
  float inv = rsqrtf(q * (1.f / 768.f) + 1e-5f);
  for (int j = 0; j < 3; ++j) {
    int c = tid + j * 256;
    float r = (v[j] - mean) * inv * w[c] + b[c];
    x[c] = HRES ? v[j] : r;
    if (OBF) ((__bf16*)Y)[(size_t)row * Dd + c] = (__bf16)r;
    else     ((float*)Y)[(size_t)row * Dd + c] = r;
  }
}

// ---------- 128xBN MFMA GEMM: A bf16 direct, B f32->bf16 cvt, reg prefetch,
// ---------- XCD chunk swizzle, optional split-K, optional bf16 output ----------
// EPI: 0 none, 1 +bias, 2 +bias->exact gelu.  grid: (Nsz/BN, Msz/128, nchunks).
template<int BN, int EPI, int OBF>
__global__ __launch_bounds__(256) void gemm128(
    const __bf16* __restrict__ Ap, long lda,
    const float* __restrict__ Bp, long ldb,
    const float* __restrict__ bias,
    void* __restrict__ Cp, long ldc,
    int Ksize, long czs)
{
  constexpr int FN = BN / 32;
  constexpr int KB = BN / 8;
  int tid = threadIdx.x;

  int nwg2 = gridDim.x * gridDim.y;
  int bid = blockIdx.y * gridDim.x + blockIdx.x;
  int swz = (bid & 7) * (nwg2 >> 3) + (bid >> 3);
  int bx = swz % gridDim.x, by = swz / gridDim.x;
  int m0 = by * 128, n0 = bx * BN;
  int z = blockIdx.z;

  const __bf16* Aq = Ap + (long)z * Ksize;
  const float* Bq = Bp + (long)z * Ksize * ldb;

  __shared__ __align__(16) __bf16 Ah[128][40];
  __shared__ __align__(16) __bf16 Bh[BN][40];

  f32x4 acc[4][FN];
  #pragma unroll
  for (int i = 0; i < 4; ++i)
    #pragma unroll
    for (int j = 0; j < FN; ++j)
      #pragma unroll
      for (int k = 0; k < 4; ++k) acc[i][j][k] = 0.f;

  int lane = tid & 63;
  int w = tid >> 6;
  int WR = (w >> 1) * 64, WC = (w & 1) * (BN / 2);
  int fr = lane & 15, kg = lane >> 4;

  const int ar = tid >> 1, acs = (tid & 1) * 16;
  const int bn = tid % BN;
  const int kb = (tid / BN) * KB;

  const __bf16* Abase = Aq + (long)(m0 + ar) * lda + acs;
  const float* Bbase = Bq + (long)kb * ldb + (n0 + bn);

  bf16x8 pa0, pa1;
  float pb[KB];
  {
    pa0 = *reinterpret_cast<const bf16x8*>(Abase);
    pa1 = *reinterpret_cast<const bf16x8*>(Abase + 8);
    #pragma unroll
    for (int j = 0; j < KB; ++j) pb[j] = Bbase[(long)j * ldb];
  }

  for (int k0 = 0; k0 < Ksize; k0 += 32) {
    __syncthreads();
    {
      *reinterpret_cast<bf16x8*>(&Ah[ar][acs]) = pa0;
      *reinterpret_cast<bf16x8*>(&Ah[ar][acs + 8]) = pa1;
      #pragma unroll
      for (int g8 = 0; g8 < KB / 8; ++g8) {
        bf16x8 bth;
        #pragma unroll
        for (int j = 0; j < 8; ++j) bth[j] = (__bf16)pb[g8 * 8 + j];
        *reinterpret_cast<bf16x8*>(&Bh[bn][kb + g8 * 8]) = bth;
      }
    }
    __syncthreads();

    if (k0 + 32 < Ksize) {
      const __bf16* As = Abase + (k0 + 32);
      pa0 = *reinterpret_cast<const bf16x8*>(As);
      pa1 = *reinterpret_cast<const bf16x8*>(As + 8);
      const float* Bs = Bbase + (long)(k0 + 32) * ldb;
      #pragma unroll
      for (int j = 0; j < KB; ++j) pb[j] = Bs[(long)j * ldb];
    }

    bf16x8 ah[4], bh[FN];
    #pragma unroll
    for (int fm = 0; fm < 4; ++fm)
      ah[fm] = *reinterpret_cast<const bf16x8*>(&Ah[WR + fm * 16 + fr][kg * 8]);
    #pragma unroll
    for (int fn = 0; fn < FN; ++fn)
      bh[fn] = *reinterpret_cast<const bf16x8*>(&Bh[WC + fn * 16 + fr][kg * 8]);
    #pragma unroll
    for (int fm = 0; fm < 4; ++fm)
      #pragma unroll
      for (int fn = 0; fn < FN; ++fn)
        acc[fm][fn] = __builtin_amdgcn_mfma_f32_16x16x32_bf16(ah[fm], bh[fn], acc[fm][fn], 0, 0, 0);
  }

  #pragma unroll
  for (int fm = 0; fm < 4; ++fm)
    #pragma unroll
    for (int fn = 0; fn < FN; ++fn)
      #pragma unroll
      for (int i = 0; i < 4; ++i) {
        int rowg = m0 + WR + fm * 16 + kg * 4 + i;
        int coln = n0 + WC + fn * 16 + fr;
        float v = acc[fm][fn][i];
        if (EPI >= 1) v += bias[coln];
        if (EPI == 2) v = 0.5f * v * (1.f + erff(v * 0.70710678118654752f));
        long ci = (long)z * czs + (long)rowg * ldc + coln;
        if (OBF) ((__bf16*)Cp)[ci] = (__bf16)v;
        else     ((float*)Cp)[ci] = v;
      }
}

// ---------- MFMA flash attention, KV-split x2, bf16 qkv input, register prefetch ----------
__global__ __launch_bounds__(256) void flash_attn_split(const __bf16* __restrict__ qkvb,
                                                        const void* __restrict__ mraw,
                                                        const int* __restrict__ flagp,
                                                        float* __restrict__ p0, float* __restrict__ p1,
                                                        float2* __restrict__ ml) {
  __shared__ __align__(16) __bf16 Qs[64][72];
  __shared__ __align__(16) __bf16 Ks[64][72];
  __shared__ __align__(16) __bf16 Vt[64][66];  // V transposed: [d][key]
  __shared__ __align__(16) __bf16 Ps[64][72];
  __shared__ float kmf[64];
  __shared__ float qmf[64];

  int s = blockIdx.z & 1, b = blockIdx.z >> 1;
  int hh = blockIdx.y;
  int q0 = blockIdx.x * 64;
  int tid = threadIdx.x, lane = tid & 63, w = tid >> 6;
  int flag = *flagp;
  int fr = lane & 15, kg = lane >> 4;

  const int sr = tid >> 2;
  const int sc = (tid & 3) * 16;

  {
    const __bf16* Qsrc = qkvb + ((long)(b * Nn + q0 + sr)) * (3 * Dd) + hh * HDd + sc;
    *reinterpret_cast<bf16x8*>(&Qs[sr][sc])     = *reinterpret_cast<const bf16x8*>(Qsrc);
    *reinterpret_cast<bf16x8*>(&Qs[sr][sc + 8]) = *reinterpret_cast<const bf16x8*>(Qsrc + 8);
    if (tid < 64) qmf[tid] = mask_at(mraw, flag, b * Nn + q0 + tid) ? 1.f : 0.f;
  }
  __syncthreads();

  float qm[4];
  #pragma unroll
  for (int i = 0; i < 4; ++i) qm[i] = qmf[16 * w + kg * 4 + i];

  bf16x8 qa[2];
  #pragma unroll
  for (int ks = 0; ks < 2; ++ks)
    qa[ks] = *reinterpret_cast<const bf16x8*>(&Qs[16 * w + fr][ks * 32 + kg * 8]);

  float mrow[4], lrow[4];
  f32x4 accO[4];
  #pragma unroll
  for (int i = 0; i < 4; ++i) { mrow[i] = -INFINITY; lrow[i] = 0.f; }
  #pragma unroll
  for (int t = 0; t < 4; ++t)
    for (int i = 0; i < 4; ++i) accO[t][i] = 0.f;

  const int jbeg = s * (Nn / 2), jend = jbeg + (Nn / 2);

  bf16x8 rk0, rk1, rv0, rv1;
  {
    const __bf16* Ksrc = qkvb + ((long)(b * Nn + jbeg + sr)) * (3 * Dd) + Dd + hh * HDd + sc;
    const __bf16* Vsrc = Ksrc + Dd;
    rk0 = *reinterpret_cast<const bf16x8*>(Ksrc);
    rk1 = *reinterpret_cast<const bf16x8*>(Ksrc + 8);
    rv0 = *reinterpret_cast<const bf16x8*>(Vsrc);
    rv1 = *reinterpret_cast<const bf16x8*>(Vsrc + 8);
  }

  for (int j0 = jbeg; j0 < jend; j0 += 64) {
    __syncthreads();
    {
      *reinterpret_cast<bf16x8*>(&Ks[sr][sc])     = rk0;
      *reinterpret_cast<bf16x8*>(&Ks[sr][sc + 8]) = rk1;
      #pragma unroll
      for (int j = 0; j < 8; ++j) {
        Vt[sc + j][sr]     = rv0[j];
        Vt[sc + 8 + j][sr] = rv1[j];
      }
      if (tid < 64) kmf[tid] = mask_at(mraw, flag, b * Nn + j0 + tid) ? 1.f : 0.f;
    }
    __syncthreads();

    if (j0 + 64 < jend) {
      const __bf16* Ksrc = qkvb + ((long)(b * Nn + j0 + 64 + sr)) * (3 * Dd) + Dd + hh * HDd + sc;
      const __bf16* Vsrc = Ksrc + Dd;
      rk0 = *reinterpret_cast<const bf16x8*>(Ksrc);
      rk1 = *reinterpret_cast<const bf16x8*>(Ksrc + 8);
      rv0 = *reinterpret_cast<const bf16x8*>(Vsrc);
      rv1 = *reinterpret_cast<const bf16x8*>(Vsrc + 8);
    }

    f32x4 sacc[4];
    #pragma unroll
    for (int t = 0; t < 4; ++t)
      for (int i = 0; i < 4; ++i) sacc[t][i] = 0.f;
    #pragma unroll
    for (int ks = 0; ks < 2; ++ks) {
      #pragma unroll
      for (int t = 0; t < 4; ++t) {
        bf16x8 bh = *reinterpret_cast<const bf16x8*>(&Ks[16 * t + fr][ks * 32 + kg * 8]);
        sacc[t] = __builtin_amdgcn_mfma_f32_16x16x32_bf16(qa[ks], bh, sacc[t], 0, 0, 0);
      }
    }

    float sv[4][4];
    float mt[4] = {-INFINITY, -INFINITY, -INFINITY, -INFINITY};
    #pragma unroll
    for (int t = 0; t < 4; ++t) {
      float km = kmf[16 * t + fr];
      #pragma unroll
      for (int i = 0; i < 4; ++i) {
        float sx = (km > 0.f && qm[i] > 0.f) ? sacc[t][i] * 0.125f : NEGF;
        sv[t][i] = sx;
        mt[i] = fmaxf(mt[i], sx);
      }
    }
    #pragma unroll
    for (int off = 8; off; off >>= 1)
      #pragma unroll
      for (int i = 0; i < 4; ++i) mt[i] = fmaxf(mt[i], __shfl_xor(mt[i], off));

    float r[4], psum[4];
    #pragma unroll
    for (int i = 0; i < 4; ++i) {
      float mn = fmaxf(mrow[i], mt[i]);
      r[i] = __expf(mrow[i] - mn);
      mrow[i] = mn;
      psum[i] = 0.f;
    }
    #pragma unroll
    for (int t = 0; t < 4; ++t) {
      #pragma unroll
      for (int i = 0; i < 4; ++i) {
        float p = __expf(sv[t][i] - mrow[i]);
        psum[i] += p;
        Ps[16 * w + kg * 4 + i][16 * t + fr] = (__bf16)p;
      }
    }
    #pragma unroll
    for (int off = 8; off; off >>= 1)
      #pragma unroll
      for (int i = 0; i < 4; ++i) psum[i] += __shfl_xor(psum[i], off);
    #pragma unroll
    for (int i = 0; i < 4; ++i) lrow[i] = lrow[i] * r[i] + psum[i];
    #pragma unroll
    for (int t = 0; t < 4; ++t)
      #pragma unroll
      for (int i = 0; i < 4; ++i) accO[t][i] *= r[i];

    __syncthreads();

    #pragma unroll
    for (int ks = 0; ks < 2; ++ks) {
      bf16x8 pa = *reinterpret_cast<const bf16x8*>(&Ps[16 * w + fr][ks * 32 + kg * 8]);
      #pragma unroll
      for (int t2 = 0; t2 < 4; ++t2) {
        bf16x8 vb = *reinterpret_cast<const bf16x8*>(&Vt[16 * t2 + fr][ks * 32 + kg * 8]);
        accO[t2] = __builtin_amdgcn_mfma_f32_16x16x32_bf16(pa, vb, accO[t2], 0, 0, 0);
      }
    }
  }

  float* op = s ? p1 : p0;
  #pragma unroll
  for (int t2 = 0; t2 < 4; ++t2)
    #pragma unroll
    for (int i = 0; i < 4; ++i) {
      int qrow = q0 + 16 * w + kg * 4 + i;
      int col = 16 * t2 + fr;
      op[((long)(b * Nn + qrow)) * Dd + hh * HDd + col] = accO[t2][i];  // unnormalized
    }
  if (fr == 0) {
    #pragma unroll
    for (int i = 0; i < 4; ++i) {
      int qrow = q0 + 16 * w + kg * 4 + i;
      ml[((long)(s * Bb + b) * Hh + hh) * Nn + qrow] = make_float2(mrow[i], lrow[i]);
    }
  }
}

// ---------- combine two KV-splits -> bf16 attn output ----------
__global__ __launch_bounds__(256) void flash_combine(const float* __restrict__ p0, const float* __restrict__ p1,
                                                     const float2* __restrict__ ml, __bf16* __restrict__ ob) {
  long i4 = (long)blockIdx.x * 256 + threadIdx.x;
  long i = i4 * 4;
  int d = (int)(i % Dd);
  long row = i / Dd;
  int b = (int)(row >> 10), n = (int)(row & (Nn - 1));
  int hh = d >> 6;
  float2 a = ml[((long)b * Hh + hh) * Nn + n];
  float2 c = ml[(((long)Bb + b) * Hh + hh) * Nn + n];
  float M = fmaxf(a.x, c.x);
  float w0 = __expf(a.x - M), w1 = __expf(c.x - M);
  float inv = 1.f / (w0 * a.y + w1 * c.y);
  float4 v0 = reinterpret_cast<const float4*>(p0)[i4];
  float4 v1 = reinterpret_cast<const float4*>(p1)[i4];
  bf16x4 r;
  r[0] = (__bf16)((w0 * v0.x + w1 * v1.x) * inv);
  r[1] = (__bf16)((w0 * v0.y + w1 * v1.y) * inv);
  r[2] = (__bf16)((w0 * v0.z + w1 * v1.z) * inv);
  r[3] = (__bf16)((w0 * v0.w + w1 * v1.w) * inv);
  *reinterpret_cast<bf16x4*>(&ob[i]) = r;
}

// ---------- seq-pool ----------
__global__ __launch_bounds__(256) void pool_score(const float* __restrict__ hn, const float* __restrict__ pw,
                                                  const float* __restrict__ pb, float* __restrict__ s) {
  __shared__ float smem[4];
  int row = blockIdx.x, tid = threadIdx.x;
  const float* x = hn + (size_t)row * Dd;
  float acc = 0.f;
  for (int j = 0; j < 3; ++j) { int c = tid + j * 256; acc += x[c] * pw[c]; }
  acc = block_reduce_sum(acc, smem);
  if (tid == 0) s[row] = acc + pb[0];
}

__global__ __launch_bounds__(256) void pool_softmax(const float* __restrict__ s, float* __restrict__ w) {
  __shared__ float smem[4];
  int b = blockIdx.x, tid = threadIdx.x;
  const float* x = s + b * Nn;
  float v[4];
  for (int j = 0; j < 4; ++j) v[j] = x[tid * 4 + j];
  float mx = fmaxf(fmaxf(v[0], v[1]), fmaxf(v[2], v[3]));
  mx = block_reduce_max(mx, smem);
  float e[4], sum = 0.f;
  for (int j = 0; j < 4; ++j) { e[j] = expf(v[j] - mx); sum += e[j]; }
  sum = block_reduce_sum(sum, smem);
  float inv = 1.f / sum;
  for (int j = 0; j < 4; ++j) w[b * Nn + tid * 4 + j] = e[j] * inv;
}

// stage 1: partial sums over 128-token chunks. grid (Dd/256, 8, Bb), block 256.
__global__ __launch_bounds__(256) void pool_reduce1(const float* __restrict__ hn, const float* __restrict__ w,
                                                    float* __restrict__ part) {
  int d = blockIdx.x * 256 + threadIdx.x;
  int ch = blockIdx.y, b = blockIdx.z;
  int n0 = ch * 128;
  float a0 = 0.f, a1 = 0.f;
  for (int n = n0; n < n0 + 128; n += 2) {
    a0 = fmaf(w[b * Nn + n],     hn[((size_t)(b * Nn + n))     * Dd + d], a0);
    a1 = fmaf(w[b * Nn + n + 1], hn[((size_t)(b * Nn + n + 1)) * Dd + d], a1);
  }
  part[((size_t)(b * 8 + ch)) * Dd + d] = a0 + a1;
}

// stage 2: sum 8 partials. grid (Dd/256, Bb), block 256.
__global__ __launch_bounds__(256) void pool_reduce2(const float* __restrict__ part, float* __restrict__ pooled) {
  int d = blockIdx.x * 256 + threadIdx.x;
  int b = blockIdx.y;
  float s = 0.f;
  #pragma unroll
  for (int ch = 0; ch < 8; ++ch) s += part[((size_t)(b * 8 + ch)) * Dd + d];
  pooled[b * Dd + d] = s;
}

// fc: one class per thread, coalesced over c. grid (4, Bb), block 256.
__global__ __launch_bounds__(256) void fc_kernel(const float* __restrict__ pooled, const float* __restrict__ fw,
                                                 const float* __restrict__ fb, float* __restrict__ out) {
  __shared__ float p[768];
  int b = blockIdx.y, tid = threadIdx.x;
  for (int j = 0; j < 3; ++j) p[tid + j * 256] = pooled[b * Dd + tid + j * 256];
  __syncthreads();
  int c = blockIdx.x * 256 + tid;
  if (c < NCc) {
    float a0 = 0.f, a1 = 0.f, a2 = 0.f, a3 = 0.f;
    #pragma unroll 4
    for (int d = 0; d < Dd; d += 4) {
      a0 = fmaf(p[d],     fw[(size_t)d       * NCc + c], a0);
      a1 = fmaf(p[d + 1], fw[(size_t)(d + 1) * NCc + c], a1);
      a2 = fmaf(p[d + 2], fw[(size_t)(d + 2) * NCc + c], a2);
      a3 = fmaf(p[d + 3], fw[(size_t)(d + 3) * NCc + c], a3);
    }
    out[b * NCc + c] = fb[c] + ((a0 + a1) + (a2 + a3));
  }
}

extern "C" void kernel_launch(void* const* d_in, const int* in_sizes, int n_in,
                              void* d_out, int out_size, void* d_ws, size_t ws_size,
                              hipStream_t stream) {
  const float* x      = (const float*)d_in[0];
  const void*  mask   = d_in[1];
  const float* pe     = (const float*)d_in[2];
  const float* ln0_w  = (const float*)d_in[3];
  const float* ln0_b  = (const float*)d_in[4];
  const float* qkv_w  = (const float*)d_in[5];
  const float* proj_w = (const float*)d_in[6];
  const float* proj_b = (const float*)d_in[7];
  const float* ln1_w  = (const float*)d_in[8];
  const float* ln1_b  = (const float*)d_in[9];
  const float* ff1_w  = (const float*)d_in[10];
  const float* ff1_b  = (const float*)d_in[11];
  const float* ff2_w  = (const float*)d_in[12];
  const float* ff2_b  = (const float*)d_in[13];
  const float* norm_w = (const float*)d_in[14];
  const float* norm_b = (const float*)d_in[15];
  const float* pool_w = (const float*)d_in[16];
  const float* pool_b = (const float*)d_in[17];
  const float* fc_w   = (const float*)d_in[18];
  const float* fc_b   = (const float*)d_in[19];
  float* out = (float*)d_out;

  // Workspace ~35.4 MB (< 44.5 MB verified). bf16 activations, f32 residual + partials.
  float* ws = (float*)d_ws;
  float*  h     = ws;                            // Mm*Dd f32 (residual)
  float*  s0    = h + (long)Mm * Dd;             // Mm*Dd f32 scratch (flash/proj/ff2 partials)
  float*  s1    = s0 + (long)Mm * Dd;            // Mm*Dd f32 scratch
  __bf16* qkvb  = (__bf16*)(s1 + (long)Mm * Dd); // Mm*3*Dd bf16
  __bf16* ob    = qkvb + (long)Mm * 3 * Dd;      // Mm*Dd bf16 (attn out)
  __bf16* yb    = ob + (long)Mm * Dd;            // Mm*Dd bf16 (ln out)
  float*  tail  = (float*)(yb + (long)Mm * Dd);
  float*  spool  = tail;                         // Mm
  float*  wpool  = spool + Mm;                   // Mm
  float*  pooled = wpool + Mm;                   // Bb*Dd
  float*  ppart  = pooled + Bb * Dd;             // Bb*8*Dd
  float*  mlbuf  = ppart + (long)Bb * 8 * Dd;    // 2*Bb*Hh*Nn float2
  int*    mflag  = (int*)(mlbuf + (long)2 * 2 * Bb * Hh * Nn);
  __bf16* gb = qkvb;     // alias: gelu out Mm*FFf bf16 == qkvb+ob region exactly
  float*  hn = s0;       // final LN out (after loop; s0 free)

  detect_mask<<<1, 256, 0, stream>>>((const unsigned char*)mask, mflag);
  add_pe_k<<<(Mm * Dd) / 256, 256, 0, stream>>>(x, pe, h);
  ln_kernel<1><<<Mm, 256, 0, stream>>>(h, ln0_w, ln0_b, yb);

  for (int l = 0; l < NLl; ++l) {
    // qkv: bf16(Mm x 768) @ bf16(768 x 2304) -> bf16 qkvb
    gemm128<64,0,1><<<dim3(3 * Dd / 64, Mm / 128, 1), 256, 0, stream>>>(
        yb, Dd,
        qkv_w + (long)l * Dd * 3 * Dd, 3 * Dd,
        nullptr,
        qkvb, 3 * Dd, Dd, 0);

    // fused attention, KV-split x2: partials -> s0, s1 + (m,l) -> mlbuf; combine -> ob (bf16)
    flash_attn_split<<<dim3(Nn / 64, Hh, Bb * 2), 256, 0, stream>>>(
        qkvb, mask, mflag, s0, s1, (float2*)mlbuf);
    flash_combine<<<(Mm * Dd / 4) / 256, 256, 0, stream>>>(s0, s1, (const float2*)mlbuf, ob);

    // proj split-K x2: bf16 ob @ bf16 -> f32 partials s0 (z=0), s1 (z=1); K chunk = 384
    gemm128<64,0,0><<<dim3(Dd / 64, Mm / 128, 2), 256, 0, stream>>>(
        ob, Dd,
        proj_w + (long)l * Dd * Dd, Dd,
        nullptr,
        s0, Dd, Dd / 2, (long)(s1 - s0));

    // POST-LN attn stage: h <- LN1(h + s0 + s1 + proj_b); yb = same (bf16)
    res_ln_kernel<1,0><<<Mm, 256, 0, stream>>>(h, s0, s1, proj_b + l * Dd,
                                               ln1_w + l * Dd, ln1_b + l * Dd, yb);

    // ff1: bf16 yb @ bf16 + b -> gelu -> bf16 gb
    gemm128<64,2,1><<<dim3(FFf / 64, Mm / 128, 1), 256, 0, stream>>>(
        yb, Dd,
        ff1_w + (long)l * Dd * FFf, FFf,
        ff1_b + l * FFf,
        gb, FFf, Dd, 0);

    // ff2 split-K x2: bf16 gb @ bf16 -> f32 partials s0 (z=0), s1 (z=1); K chunk = 1536
    gemm128<64,0,0><<<dim3(Dd / 64, Mm / 128, 2), 256, 0, stream>>>(
        gb, FFf,
        ff2_w + (long)l * FFf * Dd, Dd,
        nullptr,
        s0, Dd, FFf / 2, (long)(s1 - s0));

    // ff2 stage: h <- h + s0 + s1 + ff2_b (residual); Y = LN of that for next layer / final
    if (l + 1 < NLl) {
      res_ln_kernel<1,1><<<Mm, 256, 0, stream>>>(h, s0, s1, ff2_b + l * Dd,
                                                 ln0_w + (l + 1) * Dd, ln0_b + (l + 1) * Dd, yb);
    } else {
      res_ln_kernel<0,1><<<Mm, 256, 0, stream>>>(h, s0, s1, ff2_b + l * Dd,
                                                 norm_w, norm_b, hn);
    }
  }

  pool_score<<<Mm, 256, 0, stream>>>(hn, pool_w, pool_b, spool);
  pool_softmax<<<Bb, 256, 0, stream>>>(spool, wpool);
  pool_reduce1<<<dim3(Dd / 256, 8, Bb), 256, 0, stream>>>(hn, wpool, ppart);
  pool_reduce2<<<dim3(Dd / 256, Bb), 256, 0, stream>>>(ppart, pooled);
  fc_kernel<<<dim3(4, Bb), 256, 0, stream>>>(pooled, fc_w, fc_b, out);
}

// Round 17
// 2063.400 us; speedup vs baseline: 20.7292x; 1.0241x over previous
//
#include <hip/hip_runtime.h>
#include <hip/hip_bf16.h>
#include <cfloat>
#include <cmath>

typedef __bf16 bf16x8 __attribute__((ext_vector_type(8)));
typedef __bf16 bf16x4 __attribute__((ext_vector_type(4)));
typedef float  f32x4  __attribute__((ext_vector_type(4)));

static constexpr int Bb = 2, Nn = 1024, Dd = 768, Hh = 12, HDd = 64, FFf = 3072, NLl = 12, NCc = 1000;
static constexpr int Mm = Bb * Nn; // 2048
static constexpr float NEGF = -3.402823466e38f;

// ---------- reductions (256-thread blocks = 4 waves) ----------
__device__ __forceinline__ float block_reduce_sum(float v, volatile float* smem) {
  for (int o = 32; o; o >>= 1) v += __shfl_down(v, o);
  int lane = threadIdx.x & 63, w = threadIdx.x >> 6;
  __syncthreads();
  if (lane == 0) smem[w] = v;
  __syncthreads();
  return smem[0] + smem[1] + smem[2] + smem[3];
}

__device__ __forceinline__ float block_reduce_max(float v, volatile float* smem) {
  for (int o = 32; o; o >>= 1) v = fmaxf(v, __shfl_down(v, o));
  int lane = threadIdx.x & 63, w = threadIdx.x >> 6;
  __syncthreads();
  if (lane == 0) smem[w] = v;
  __syncthreads();
  return fmaxf(fmaxf(smem[0], smem[1]), fmaxf(smem[2], smem[3]));
}

// ---------- mask dtype detection: 0=int32 1=bytes 2=f32 3=int64 4=bf16 ----------
__global__ void detect_mask(const unsigned char* __restrict__ m, int* __restrict__ flag) {
  __shared__ int s_nz1, s_nz2, s_nz3, s_nz84, s_pv;
  int tid = threadIdx.x;
  if (tid == 0) { s_nz1 = 0; s_nz2 = 0; s_nz3 = 0; s_nz84 = 0; s_pv = 0; }
  __syncthreads();
  int nz1 = 0, nz2 = 0, nz3 = 0, nz84 = 0, pv = 0;
  for (int i = tid; i < 2048; i += 256) {
    unsigned char v = m[i];
    if (v) {
      int p4 = i & 3;
      if (p4 == 1) nz1 = 1;
      if (p4 == 2) nz2 = 1;
      if (p4 == 3) nz3 = 1;
      if ((i & 7) == 4) nz84 = 1;
      if ((i & 1) == 0) { if (v != 0x80) pv = 1; }
      else              { if (v != 0x3f) pv = 1; }
    }
  }
  if (nz1)  atomicOr(&s_nz1, 1);
  if (nz2)  atomicOr(&s_nz2, 1);
  if (nz3)  atomicOr(&s_nz3, 1);
  if (nz84) atomicOr(&s_nz84, 1);
  if (pv)   atomicOr(&s_pv, 1);
  __syncthreads();
  if (tid == 0) {
    int f;
    if (!s_nz1 && !s_nz2 && !s_nz3) f = s_nz84 ? 0 : 3;
    else if (!s_pv)                 f = s_nz1 ? 4 : 2;
    else                            f = 1;
    *flag = f;
  }
}

__device__ __forceinline__ bool mask_at(const void* mraw, int flag, int idx) {
  switch (flag) {
    case 0:  return ((const int*)mraw)[idx] != 0;
    case 1:  return ((const unsigned char*)mraw)[idx] != 0;
    case 2:  return ((const float*)mraw)[idx] != 0.f;
    case 3:  return ((const long long*)mraw)[idx] != 0;
    default: return ((const unsigned short*)mraw)[idx] != 0;
  }
}

// ---------- weight f32 -> bf16 conversion (8 elems/thread) ----------
__global__ __launch_bounds__(256) void cvt_w(const float* __restrict__ src, __bf16* __restrict__ dst, int n8) {
  int i = blockIdx.x * 256 + threadIdx.x;
  if (i < n8) {
    float4 f0 = reinterpret_cast<const float4*>(src)[i * 2];
    float4 f1 = reinterpret_cast<const float4*>(src)[i * 2 + 1];
    bf16x8 r;
    r[0] = (__bf16)f0.x; r[1] = (__bf16)f0.y; r[2] = (__bf16)f0.z; r[3] = (__bf16)f0.w;
    r[4] = (__bf16)f1.x; r[5] = (__bf16)f1.y; r[6] = (__bf16)f1.z; r[7] = (__bf16)f1.w;
    reinterpret_cast<bf16x8*>(dst)[i] = r;
  }
}

// ---------- h = x + pe (pe broadcast over batch) ----------
__global__ __launch_bounds__(256) void add_pe_k(const float* __restrict__ x, const float* __restrict__ pe,
                                                float* __restrict__ h) {
  long i = (long)blockIdx.x * 256 + threadIdx.x;
  long nd = i % ((long)Nn * Dd);
  h[i] = x[i] + pe[nd];
}

// ---------- LayerNorm; OBF=1 writes bf16 output ----------
template<int OBF>
__global__ __launch_bounds__(256) void ln_kernel(const float* __restrict__ X,
                                                 const float* __restrict__ w, const float* __restrict__ b,
                                                 void* __restrict__ Y) {
  __shared__ float smem[4];
  int row = blockIdx.x, tid = threadIdx.x;
  const float* x = X + (size_t)row * Dd;
  float v[3];
  for (int j = 0; j < 3; ++j) v[j] = x[tid + j * 256];
  float s = v[0] + v[1] + v[2];
  s = block_reduce_sum(s, smem);
  float mean = s * (1.f / 768.f);
  float q = 0.f;
  for (int j = 0; j < 3; ++j) { float d = v[j] - mean; q += d * d; }
  q = block_reduce_sum(q, smem);
  float inv = rsqrtf(q * (1.f / 768.f) + 1e-5f);
  for (int j = 0; j < 3; ++j) {
    int c = tid + j * 256;
    float r = (v[j] - mean) * inv * w[c] + b[c];
    if (OBF) ((__bf16*)Y)[(size_t)row * Dd + c] = (__bf16)r;
    else     ((float*)Y)[(size_t)row * Dd + c] = r;
  }
}

// ---------- residual + LayerNorm: v = h + p0 + p1 + bias; Y = LN(v).
// HRES=0 (post-LN attn stage): h <- LN(v).  HRES=1 (ff2 stage / final): h <- v.
template<int OBF, int HRES>
__global__ __launch_bounds__(256) void res_ln_kernel(float* __restrict__ H,
                                                     const float* __restrict__ P0, const float* __restrict__ P1,
                                                     const float* __restrict__ pb,
                                                     const float* __restrict__ w, const float* __restrict__ b,
                                                     void* __restrict__ Y) {
  __shared__ float smem[4];
  int row = blockIdx.x, tid = threadIdx.x;
  float* x  = H  + (size_t)row * Dd;
  const float* p0 = P0 + (size_t)row * Dd;
  const float* p1 = P1 + (size_t)row * Dd;
  float v[3];
  for (int j = 0; j < 3; ++j) {
    int c = tid + j * 256;
    v[j] = x[c] + (p0[c] + p1[c] + pb[c]);
  }
  float s = v[0] + v[1] + v[2];
  s = block_reduce_sum(s, smem);
  float mean = s * (1.f / 768.f);
  float q = 0.f;
  for (int j = 0; j < 3; ++j) { float d = v[j] - mean; q += d * d; }
  q = block_reduce_sum(q, smem);
  float inv = rsqrtf(q * (1.f / 768.f) + 1e-5f);
  for (int j = 0; j < 3; ++j) {
    int c = tid + j * 256;
    float r = (v[j] - mean) * inv * w[c] + b[c];
    x[c] = HRES ? v[j] : r;
    if (OBF) ((__bf16*)Y)[(size_t)row * Dd + c] = (__bf16)r;
    else     ((float*)Y)[(size_t)row * Dd + c] = r;
  }
}

// ---------- 128xBN MFMA GEMM: A bf16 direct, B bf16 (pre-converted), reg prefetch,
// ---------- XCD chunk swizzle, optional split-K, optional bf16 output ----------
// EPI: 0 none, 1 +bias, 2 +bias->exact gelu.  grid: (Nsz/BN, Msz/128, nchunks).
template<int BN, int EPI, int OBF>
__global__ __launch_bounds__(256) void gemm128(
    const __bf16* __restrict__ Ap, long lda,
    const __bf16* __restrict__ Bp, long ldb,
    const float* __restrict__ bias,
    void* __restrict__ Cp, long ldc,
    int Ksize, long czs)
{
  constexpr int FN = BN / 32;
  constexpr int KB = BN / 8;
  int tid = threadIdx.x;

  int nwg2 = gridDim.x * gridDim.y;
  int bid = blockIdx.y * gridDim.x + blockIdx.x;
  int swz = (bid & 7) * (nwg2 >> 3) + (bid >> 3);
  int bx = swz % gridDim.x, by = swz / gridDim.x;
  int m0 = by * 128, n0 = bx * BN;
  int z = blockIdx.z;

  const __bf16* Aq = Ap + (long)z * Ksize;
  const __bf16* Bq = Bp + (long)z * Ksize * ldb;

  __shared__ __align__(16) __bf16 Ah[128][40];
  __shared__ __align__(16) __bf16 Bh[BN][40];

  f32x4 acc[4][FN];
  #pragma unroll
  for (int i = 0; i < 4; ++i)
    #pragma unroll
    for (int j = 0; j < FN; ++j)
      #pragma unroll
      for (int k = 0; k < 4; ++k) acc[i][j][k] = 0.f;

  int lane = tid & 63;
  int w = tid >> 6;
  int WR = (w >> 1) * 64, WC = (w & 1) * (BN / 2);
  int fr = lane & 15, kg = lane >> 4;

  const int ar = tid >> 1, acs = (tid & 1) * 16;
  const int bn = tid % BN;
  const int kb = (tid / BN) * KB;

  const __bf16* Abase = Aq + (long)(m0 + ar) * lda + acs;
  const __bf16* Bbase = Bq + (long)kb * ldb + (n0 + bn);

  bf16x8 pa0, pa1;
  __bf16 pbh[KB];
  {
    pa0 = *reinterpret_cast<const bf16x8*>(Abase);
    pa1 = *reinterpret_cast<const bf16x8*>(Abase + 8);
    #pragma unroll
    for (int j = 0; j < KB; ++j) pbh[j] = Bbase[(long)j * ldb];
  }

  for (int k0 = 0; k0 < Ksize; k0 += 32) {
    __syncthreads();
    {
      *reinterpret_cast<bf16x8*>(&Ah[ar][acs]) = pa0;
      *reinterpret_cast<bf16x8*>(&Ah[ar][acs + 8]) = pa1;
      #pragma unroll
      for (int g8 = 0; g8 < KB / 8; ++g8)
        *reinterpret_cast<bf16x8*>(&Bh[bn][kb + g8 * 8]) = *reinterpret_cast<bf16x8*>(&pbh[g8 * 8]);
    }
    __syncthreads();

    if (k0 + 32 < Ksize) {
      const __bf16* As = Abase + (k0 + 32);
      pa0 = *reinterpret_cast<const bf16x8*>(As);
      pa1 = *reinterpret_cast<const bf16x8*>(As + 8);
      const __bf16* Bs = Bbase + (long)(k0 + 32) * ldb;
      #pragma unroll
      for (int j = 0; j < KB; ++j) pbh[j] = Bs[(long)j * ldb];
    }

    bf16x8 ah[4], bh[FN];
    #pragma unroll
    for (int fm = 0; fm < 4; ++fm)
      ah[fm] = *reinterpret_cast<const bf16x8*>(&Ah[WR + fm * 16 + fr][kg * 8]);
    #pragma unroll
    for (int fn = 0; fn < FN; ++fn)
      bh[fn] = *reinterpret_cast<const bf16x8*>(&Bh[WC + fn * 16 + fr][kg * 8]);
    #pragma unroll
    for (int fm = 0; fm < 4; ++fm)
      #pragma unroll
      for (int fn = 0; fn < FN; ++fn)
        acc[fm][fn] = __builtin_amdgcn_mfma_f32_16x16x32_bf16(ah[fm], bh[fn], acc[fm][fn], 0, 0, 0);
  }

  #pragma unroll
  for (int fm = 0; fm < 4; ++fm)
    #pragma unroll
    for (int fn = 0; fn < FN; ++fn)
      #pragma unroll
      for (int i = 0; i < 4; ++i) {
        int rowg = m0 + WR + fm * 16 + kg * 4 + i;
        int coln = n0 + WC + fn * 16 + fr;
        float v = acc[fm][fn][i];
        if (EPI >= 1) v += bias[coln];
        if (EPI == 2) v = 0.5f * v * (1.f + erff(v * 0.70710678118654752f));
        long ci = (long)z * czs + (long)rowg * ldc + coln;
        if (OBF) ((__bf16*)Cp)[ci] = (__bf16)v;
        else     ((float*)Cp)[ci] = v;
      }
}

// ---------- MFMA flash attention, KV-split x2, bf16 qkv input, register prefetch ----------
__global__ __launch_bounds__(256) void flash_attn_split(const __bf16* __restrict__ qkvb,
                                                        const void* __restrict__ mraw,
                                                        const int* __restrict__ flagp,
                                                        float* __restrict__ p0, float* __restrict__ p1,
                                                        float2* __restrict__ ml) {
  __shared__ __align__(16) __bf16 Qs[64][72];
  __shared__ __align__(16) __bf16 Ks[64][72];
  __shared__ __align__(16) __bf16 Vt[64][66];  // V transposed: [d][key]
  __shared__ __align__(16) __bf16 Ps[64][72];
  __shared__ float kmf[64];
  __shared__ float qmf[64];

  int s = blockIdx.z & 1, b = blockIdx.z >> 1;
  int hh = blockIdx.y;
  int q0 = blockIdx.x * 64;
  int tid = threadIdx.x, lane = tid & 63, w = tid >> 6;
  int flag = *flagp;
  int fr = lane & 15, kg = lane >> 4;

  const int sr = tid >> 2;
  const int sc = (tid & 3) * 16;

  {
    const __bf16* Qsrc = qkvb + ((long)(b * Nn + q0 + sr)) * (3 * Dd) + hh * HDd + sc;
    *reinterpret_cast<bf16x8*>(&Qs[sr][sc])     = *reinterpret_cast<const bf16x8*>(Qsrc);
    *reinterpret_cast<bf16x8*>(&Qs[sr][sc + 8]) = *reinterpret_cast<const bf16x8*>(Qsrc + 8);
    if (tid < 64) qmf[tid] = mask_at(mraw, flag, b * Nn + q0 + tid) ? 1.f : 0.f;
  }
  __syncthreads();

  float qm[4];
  #pragma unroll
  for (int i = 0; i < 4; ++i) qm[i] = qmf[16 * w + kg * 4 + i];

  bf16x8 qa[2];
  #pragma unroll
  for (int ks = 0; ks < 2; ++ks)
    qa[ks] = *reinterpret_cast<const bf16x8*>(&Qs[16 * w + fr][ks * 32 + kg * 8]);

  float mrow[4], lrow[4];
  f32x4 accO[4];
  #pragma unroll
  for (int i = 0; i < 4; ++i) { mrow[i] = -INFINITY; lrow[i] = 0.f; }
  #pragma unroll
  for (int t = 0; t < 4; ++t)
    for (int i = 0; i < 4; ++i) accO[t][i] = 0.f;

  const int jbeg = s * (Nn / 2), jend = jbeg + (Nn / 2);

  bf16x8 rk0, rk1, rv0, rv1;
  {
    const __bf16* Ksrc = qkvb + ((long)(b * Nn + jbeg + sr)) * (3 * Dd) + Dd + hh * HDd + sc;
    const __bf16* Vsrc = Ksrc + Dd;
    rk0 = *reinterpret_cast<const bf16x8*>(Ksrc);
    rk1 = *reinterpret_cast<const bf16x8*>(Ksrc + 8);
    rv0 = *reinterpret_cast<const bf16x8*>(Vsrc);
    rv1 = *reinterpret_cast<const bf16x8*>(Vsrc + 8);
  }

  for (int j0 = jbeg; j0 < jend; j0 += 64) {
    __syncthreads();
    {
      *reinterpret_cast<bf16x8*>(&Ks[sr][sc])     = rk0;
      *reinterpret_cast<bf16x8*>(&Ks[sr][sc + 8]) = rk1;
      #pragma unroll
      for (int j = 0; j < 8; ++j) {
        Vt[sc + j][sr]     = rv0[j];
        Vt[sc + 8 + j][sr] = rv1[j];
      }
      if (tid < 64) kmf[tid] = mask_at(mraw, flag, b * Nn + j0 + tid) ? 1.f : 0.f;
    }
    __syncthreads();

    if (j0 + 64 < jend) {
      const __bf16* Ksrc = qkvb + ((long)(b * Nn + j0 + 64 + sr)) * (3 * Dd) + Dd + hh * HDd + sc;
      const __bf16* Vsrc = Ksrc + Dd;
      rk0 = *reinterpret_cast<const bf16x8*>(Ksrc);
      rk1 = *reinterpret_cast<const bf16x8*>(Ksrc + 8);
      rv0 = *reinterpret_cast<const bf16x8*>(Vsrc);
      rv1 = *reinterpret_cast<const bf16x8*>(Vsrc + 8);
    }

    f32x4 sacc[4];
    #pragma unroll
    for (int t = 0; t < 4; ++t)
      for (int i = 0; i < 4; ++i) sacc[t][i] = 0.f;
    #pragma unroll
    for (int ks = 0; ks < 2; ++ks) {
      #pragma unroll
      for (int t = 0; t < 4; ++t) {
        bf16x8 bh = *reinterpret_cast<const bf16x8*>(&Ks[16 * t + fr][ks * 32 + kg * 8]);
        sacc[t] = __builtin_amdgcn_mfma_f32_16x16x32_bf16(qa[ks], bh, sacc[t], 0, 0, 0);
      }
    }

    float sv[4][4];
    float mt[4] = {-INFINITY, -INFINITY, -INFINITY, -INFINITY};
    #pragma unroll
    for (int t = 0; t < 4; ++t) {
      float km = kmf[16 * t + fr];
      #pragma unroll
      for (int i = 0; i < 4; ++i) {
        float sx = (km > 0.f && qm[i] > 0.f) ? sacc[t][i] * 0.125f : NEGF;
        sv[t][i] = sx;
        mt[i] = fmaxf(mt[i], sx);
      }
    }
    #pragma unroll
    for (int off = 8; off; off >>= 1)
      #pragma unroll
      for (int i = 0; i < 4; ++i) mt[i] = fmaxf(mt[i], __shfl_xor(mt[i], off));

    float r[4], psum[4];
    #pragma unroll
    for (int i = 0; i < 4; ++i) {
      float mn = fmaxf(mrow[i], mt[i]);
      r[i] = __expf(mrow[i] - mn);
      mrow[i] = mn;
      psum[i] = 0.f;
    }
    #pragma unroll
    for (int t = 0; t < 4; ++t) {
      #pragma unroll
      for (int i = 0; i < 4; ++i) {
        float p = __expf(sv[t][i] - mrow[i]);
        psum[i] += p;
        Ps[16 * w + kg * 4 + i][16 * t + fr] = (__bf16)p;
      }
    }
    #pragma unroll
    for (int off = 8; off; off >>= 1)
      #pragma unroll
      for (int i = 0; i < 4; ++i) psum[i] += __shfl_xor(psum[i], off);
    #pragma unroll
    for (int i = 0; i < 4; ++i) lrow[i] = lrow[i] * r[i] + psum[i];
    #pragma unroll
    for (int t = 0; t < 4; ++t)
      #pragma unroll
      for (int i = 0; i < 4; ++i) accO[t][i] *= r[i];

    __syncthreads();

    #pragma unroll
    for (int ks = 0; ks < 2; ++ks) {
      bf16x8 pa = *reinterpret_cast<const bf16x8*>(&Ps[16 * w + fr][ks * 32 + kg * 8]);
      #pragma unroll
      for (int t2 = 0; t2 < 4; ++t2) {
        bf16x8 vb = *reinterpret_cast<const bf16x8*>(&Vt[16 * t2 + fr][ks * 32 + kg * 8]);
        accO[t2] = __builtin_amdgcn_mfma_f32_16x16x32_bf16(pa, vb, accO[t2], 0, 0, 0);
      }
    }
  }

  float* op = s ? p1 : p0;
  #pragma unroll
  for (int t2 = 0; t2 < 4; ++t2)
    #pragma unroll
    for (int i = 0; i < 4; ++i) {
      int qrow = q0 + 16 * w + kg * 4 + i;
      int col = 16 * t2 + fr;
      op[((long)(b * Nn + qrow)) * Dd + hh * HDd + col] = accO[t2][i];  // unnormalized
    }
  if (fr == 0) {
    #pragma unroll
    for (int i = 0; i < 4; ++i) {
      int qrow = q0 + 16 * w + kg * 4 + i;
      ml[((long)(s * Bb + b) * Hh + hh) * Nn + qrow] = make_float2(mrow[i], lrow[i]);
    }
  }
}

// ---------- combine two KV-splits -> bf16 attn output ----------
__global__ __launch_bounds__(256) void flash_combine(const float* __restrict__ p0, const float* __restrict__ p1,
                                                     const float2* __restrict__ ml, __bf16* __restrict__ ob) {
  long i4 = (long)blockIdx.x * 256 + threadIdx.x;
  long i = i4 * 4;
  int d = (int)(i % Dd);
  long row = i / Dd;
  int b = (int)(row >> 10), n = (int)(row & (Nn - 1));
  int hh = d >> 6;
  float2 a = ml[((long)b * Hh + hh) * Nn + n];
  float2 c = ml[(((long)Bb + b) * Hh + hh) * Nn + n];
  float M = fmaxf(a.x, c.x);
  float w0 = __expf(a.x - M), w1 = __expf(c.x - M);
  float inv = 1.f / (w0 * a.y + w1 * c.y);
  float4 v0 = reinterpret_cast<const float4*>(p0)[i4];
  float4 v1 = reinterpret_cast<const float4*>(p1)[i4];
  bf16x4 r;
  r[0] = (__bf16)((w0 * v0.x + w1 * v1.x) * inv);
  r[1] = (__bf16)((w0 * v0.y + w1 * v1.y) * inv);
  r[2] = (__bf16)((w0 * v0.z + w1 * v1.z) * inv);
  r[3] = (__bf16)((w0 * v0.w + w1 * v1.w) * inv);
  *reinterpret_cast<bf16x4*>(&ob[i]) = r;
}

// ---------- seq-pool ----------
__global__ __launch_bounds__(256) void pool_score(const float* __restrict__ hn, const float* __restrict__ pw,
                                                  const float* __restrict__ pb, float* __restrict__ s) {
  __shared__ float smem[4];
  int row = blockIdx.x, tid = threadIdx.x;
  const float* x = hn + (size_t)row * Dd;
  float acc = 0.f;
  for (int j = 0; j < 3; ++j) { int c = tid + j * 256; acc += x[c] * pw[c]; }
  acc = block_reduce_sum(acc, smem);
  if (tid == 0) s[row] = acc + pb[0];
}

__global__ __launch_bounds__(256) void pool_softmax(const float* __restrict__ s, float* __restrict__ w) {
  __shared__ float smem[4];
  int b = blockIdx.x, tid = threadIdx.x;
  const float* x = s + b * Nn;
  float v[4];
  for (int j = 0; j < 4; ++j) v[j] = x[tid * 4 + j];
  float mx = fmaxf(fmaxf(v[0], v[1]), fmaxf(v[2], v[3]));
  mx = block_reduce_max(mx, smem);
  float e[4], sum = 0.f;
  for (int j = 0; j < 4; ++j) { e[j] = expf(v[j] - mx); sum += e[j]; }
  sum = block_reduce_sum(sum, smem);
  float inv = 1.f / sum;
  for (int j = 0; j < 4; ++j) w[b * Nn + tid * 4 + j] = e[j] * inv;
}

// stage 1: partial sums over 128-token chunks. grid (Dd/256, 8, Bb), block 256.
__global__ __launch_bounds__(256) void pool_reduce1(const float* __restrict__ hn, const float* __restrict__ w,
                                                    float* __restrict__ part) {
  int d = blockIdx.x * 256 + threadIdx.x;
  int ch = blockIdx.y, b = blockIdx.z;
  int n0 = ch * 128;
  float a0 = 0.f, a1 = 0.f;
  for (int n = n0; n < n0 + 128; n += 2) {
    a0 = fmaf(w[b * Nn + n],     hn[((size_t)(b * Nn + n))     * Dd + d], a0);
    a1 = fmaf(w[b * Nn + n + 1], hn[((size_t)(b * Nn + n + 1)) * Dd + d], a1);
  }
  part[((size_t)(b * 8 + ch)) * Dd + d] = a0 + a1;
}

// stage 2: sum 8 partials. grid (Dd/256, Bb), block 256.
__global__ __launch_bounds__(256) void pool_reduce2(const float* __restrict__ part, float* __restrict__ pooled) {
  int d = blockIdx.x * 256 + threadIdx.x;
  int b = blockIdx.y;
  float s = 0.f;
  #pragma unroll
  for (int ch = 0; ch < 8; ++ch) s += part[((size_t)(b * 8 + ch)) * Dd + d];
  pooled[b * Dd + d] = s;
}

// fc: one class per thread, coalesced over c. grid (4, Bb), block 256.
__global__ __launch_bounds__(256) void fc_kernel(const float* __restrict__ pooled, const float* __restrict__ fw,
                                                 const float* __restrict__ fb, float* __restrict__ out) {
  __shared__ float p[768];
  int b = blockIdx.y, tid = threadIdx.x;
  for (int j = 0; j < 3; ++j) p[tid + j * 256] = pooled[b * Dd + tid + j * 256];
  __syncthreads();
  int c = blockIdx.x * 256 + tid;
  if (c < NCc) {
    float a0 = 0.f, a1 = 0.f, a2 = 0.f, a3 = 0.f;
    #pragma unroll 4
    for (int d = 0; d < Dd; d += 4) {
      a0 = fmaf(p[d],     fw[(size_t)d       * NCc + c], a0);
      a1 = fmaf(p[d + 1], fw[(size_t)(d + 1) * NCc + c], a1);
      a2 = fmaf(p[d + 2], fw[(size_t)(d + 2) * NCc + c], a2);
      a3 = fmaf(p[d + 3], fw[(size_t)(d + 3) * NCc + c], a3);
    }
    out[b * NCc + c] = fb[c] + ((a0 + a1) + (a2 + a3));
  }
}

extern "C" void kernel_launch(void* const* d_in, const int* in_sizes, int n_in,
                              void* d_out, int out_size, void* d_ws, size_t ws_size,
                              hipStream_t stream) {
  const float* x      = (const float*)d_in[0];
  const void*  mask   = d_in[1];
  const float* pe     = (const float*)d_in[2];
  const float* ln0_w  = (const float*)d_in[3];
  const float* ln0_b  = (const float*)d_in[4];
  const float* qkv_w  = (const float*)d_in[5];
  const float* proj_w = (const float*)d_in[6];
  const float* proj_b = (const float*)d_in[7];
  const float* ln1_w  = (const float*)d_in[8];
  const float* ln1_b  = (const float*)d_in[9];
  const float* ff1_w  = (const float*)d_in[10];
  const float* ff1_b  = (const float*)d_in[11];
  const float* ff2_w  = (const float*)d_in[12];
  const float* ff2_b  = (const float*)d_in[13];
  const float* norm_w = (const float*)d_in[14];
  const float* norm_b = (const float*)d_in[15];
  const float* pool_w = (const float*)d_in[16];
  const float* pool_b = (const float*)d_in[17];
  const float* fc_w   = (const float*)d_in[18];
  const float* fc_b   = (const float*)d_in[19];
  float* out = (float*)d_out;

  // Workspace ~40.1 MB (< 44.5 MB verified). bf16 activations + per-layer bf16 weight buffer.
  float* ws = (float*)d_ws;
  float*  h     = ws;                            // Mm*Dd f32 (residual)
  float*  s0    = h + (long)Mm * Dd;             // Mm*Dd f32 scratch
  float*  s1    = s0 + (long)Mm * Dd;            // Mm*Dd f32 scratch
  __bf16* qkvb  = (__bf16*)(s1 + (long)Mm * Dd); // Mm*3*Dd bf16
  __bf16* ob    = qkvb + (long)Mm * 3 * Dd;      // Mm*Dd bf16 (attn out)
  __bf16* yb    = ob + (long)Mm * Dd;            // Mm*Dd bf16 (ln out)
  __bf16* wbuf  = yb + (long)Mm * Dd;            // Dd*FFf bf16 = 4.7 MB (per-layer weight)
  float*  tail  = (float*)(wbuf + (long)Dd * FFf);
  float*  spool  = tail;                         // Mm
  float*  wpool  = spool + Mm;                   // Mm
  float*  pooled = wpool + Mm;                   // Bb*Dd
  float*  ppart  = pooled + Bb * Dd;             // Bb*8*Dd
  float*  mlbuf  = ppart + (long)Bb * 8 * Dd;    // 2*Bb*Hh*Nn float2
  int*    mflag  = (int*)(mlbuf + (long)2 * 2 * Bb * Hh * Nn);
  __bf16* gb = qkvb;     // alias: gelu out Mm*FFf bf16 == qkvb+ob region exactly
  float*  hn = s0;       // final LN out (after loop; s0 free)

  const int n8_qkv  = Dd * 3 * Dd / 8;
  const int n8_proj = Dd * Dd / 8;
  const int n8_ff   = Dd * FFf / 8;

  detect_mask<<<1, 256, 0, stream>>>((const unsigned char*)mask, mflag);
  add_pe_k<<<(Mm * Dd) / 256, 256, 0, stream>>>(x, pe, h);
  ln_kernel<1><<<Mm, 256, 0, stream>>>(h, ln0_w, ln0_b, yb);

  for (int l = 0; l < NLl; ++l) {
    // qkv weight -> bf16; gemm
    cvt_w<<<(n8_qkv + 255) / 256, 256, 0, stream>>>(qkv_w + (long)l * Dd * 3 * Dd, wbuf, n8_qkv);
    gemm128<64,0,1><<<dim3(3 * Dd / 64, Mm / 128, 1), 256, 0, stream>>>(
        yb, Dd, wbuf, 3 * Dd, nullptr, qkvb, 3 * Dd, Dd, 0);

    // fused attention, KV-split x2; combine -> ob (bf16)
    flash_attn_split<<<dim3(Nn / 64, Hh, Bb * 2), 256, 0, stream>>>(
        qkvb, mask, mflag, s0, s1, (float2*)mlbuf);
    flash_combine<<<(Mm * Dd / 4) / 256, 256, 0, stream>>>(s0, s1, (const float2*)mlbuf, ob);

    // proj weight -> bf16; split-K x2 -> s0, s1
    cvt_w<<<(n8_proj + 255) / 256, 256, 0, stream>>>(proj_w + (long)l * Dd * Dd, wbuf, n8_proj);
    gemm128<64,0,0><<<dim3(Dd / 64, Mm / 128, 2), 256, 0, stream>>>(
        ob, Dd, wbuf, Dd, nullptr, s0, Dd, Dd / 2, (long)(s1 - s0));

    // POST-LN attn stage: h <- LN1(h + s0 + s1 + proj_b); yb = same (bf16)
    res_ln_kernel<1,0><<<Mm, 256, 0, stream>>>(h, s0, s1, proj_b + l * Dd,
                                               ln1_w + l * Dd, ln1_b + l * Dd, yb);

    // ff1 weight -> bf16; gemm + gelu -> gb
    cvt_w<<<(n8_ff + 255) / 256, 256, 0, stream>>>(ff1_w + (long)l * Dd * FFf, wbuf, n8_ff);
    gemm128<64,2,1><<<dim3(FFf / 64, Mm / 128, 1), 256, 0, stream>>>(
        yb, Dd, wbuf, FFf, ff1_b + l * FFf, gb, FFf, Dd, 0);

    // ff2 weight -> bf16; split-K x2 -> s0, s1
    cvt_w<<<(n8_ff + 255) / 256, 256, 0, stream>>>(ff2_w + (long)l * FFf * Dd, wbuf, n8_ff);
    gemm128<64,0,0><<<dim3(Dd / 64, Mm / 128, 2), 256, 0, stream>>>(
        gb, FFf, wbuf, Dd, nullptr, s0, Dd, FFf / 2, (long)(s1 - s0));

    // ff2 stage: h <- h + s0 + s1 + ff2_b; Y = LN for next layer / final
    if (l + 1 < NLl) {
      res_ln_kernel<1,1><<<Mm, 256, 0, stream>>>(h, s0, s1, ff2_b + l * Dd,
                                                 ln0_w + (l + 1) * Dd, ln0_b + (l + 1) * Dd, yb);
    } else {
      res_ln_kernel<0,1><<<Mm, 256, 0, stream>>>(h, s0, s1, ff2_b + l * Dd,
                                                 norm_w, norm_b, hn);
    }
  }

  pool_score<<<Mm, 256, 0, stream>>>(hn, pool_w, pool_b, spool);
  pool_softmax<<<Bb, 256, 0, stream>>>(spool, wpool);
  pool_reduce1<<<dim3(Dd / 256, 8, Bb), 256, 0, stream>>>(hn, wpool, ppart);
  pool_reduce2<<<dim3(Dd / 256, Bb), 256, 0, stream>>>(ppart, pooled);
  fc_kernel<<<dim3(4, Bb), 256, 0, stream>>>(pooled, fc_w, fc_b, out);
}

// Round 18
// 1964.678 us; speedup vs baseline: 21.7709x; 1.0502x over previous
//
#include <hip/hip_runtime.h>
#include <hip/hip_bf16.h>
#include <cfloat>
#include <cmath>

typedef __bf16 bf16x8 __attribute__((ext_vector_type(8)));
typedef __bf16 bf16x4 __attribute__((ext_vector_type(4)));
typedef float  f32x4  __attribute__((ext_vector_type(4)));

static constexpr int Bb = 2, Nn = 1024, Dd = 768, Hh = 12, HDd = 64, FFf = 3072, NLl = 12, NCc = 1000;
static constexpr int Mm = Bb * Nn; // 2048
static constexpr float NEGF = -3.402823466e38f;

// ---------- reductions (256-thread blocks = 4 waves) ----------
__device__ __forceinline__ float block_reduce_sum(float v, volatile float* smem) {
  for (int o = 32; o; o >>= 1) v += __shfl_down(v, o);
  int lane = threadIdx.x & 63, w = threadIdx.x >> 6;
  __syncthreads();
  if (lane == 0) smem[w] = v;
  __syncthreads();
  return smem[0] + smem[1] + smem[2] + smem[3];
}

__device__ __forceinline__ float block_reduce_max(float v, volatile float* smem) {
  for (int o = 32; o; o >>= 1) v = fmaxf(v, __shfl_down(v, o));
  int lane = threadIdx.x & 63, w = threadIdx.x >> 6;
  __syncthreads();
  if (lane == 0) smem[w] = v;
  __syncthreads();
  return fmaxf(fmaxf(smem[0], smem[1]), fmaxf(smem[2], smem[3]));
}

// ---------- mask dtype detection: 0=int32 1=bytes 2=f32 3=int64 4=bf16 ----------
__global__ void detect_mask(const unsigned char* __restrict__ m, int* __restrict__ flag) {
  __shared__ int s_nz1, s_nz2, s_nz3, s_nz84, s_pv;
  int tid = threadIdx.x;
  if (tid == 0) { s_nz1 = 0; s_nz2 = 0; s_nz3 = 0; s_nz84 = 0; s_pv = 0; }
  __syncthreads();
  int nz1 = 0, nz2 = 0, nz3 = 0, nz84 = 0, pv = 0;
  for (int i = tid; i < 2048; i += 256) {
    unsigned char v = m[i];
    if (v) {
      int p4 = i & 3;
      if (p4 == 1) nz1 = 1;
      if (p4 == 2) nz2 = 1;
      if (p4 == 3) nz3 = 1;
      if ((i & 7) == 4) nz84 = 1;
      if ((i & 1) == 0) { if (v != 0x80) pv = 1; }
      else              { if (v != 0x3f) pv = 1; }
    }
  }
  if (nz1)  atomicOr(&s_nz1, 1);
  if (nz2)  atomicOr(&s_nz2, 1);
  if (nz3)  atomicOr(&s_nz3, 1);
  if (nz84) atomicOr(&s_nz84, 1);
  if (pv)   atomicOr(&s_pv, 1);
  __syncthreads();
  if (tid == 0) {
    int f;
    if (!s_nz1 && !s_nz2 && !s_nz3) f = s_nz84 ? 0 : 3;
    else if (!s_pv)                 f = s_nz1 ? 4 : 2;
    else                            f = 1;
    *flag = f;
  }
}

__device__ __forceinline__ bool mask_at(const void* mraw, int flag, int idx) {
  switch (flag) {
    case 0:  return ((const int*)mraw)[idx] != 0;
    case 1:  return ((const unsigned char*)mraw)[idx] != 0;
    case 2:  return ((const float*)mraw)[idx] != 0.f;
    case 3:  return ((const long long*)mraw)[idx] != 0;
    default: return ((const unsigned short*)mraw)[idx] != 0;
  }
}

// ---------- weight f32 -> bf16 (8 elems/thread) ----------
__device__ __forceinline__ void cvt8_store(const float* __restrict__ s, __bf16* __restrict__ d, int j) {
  float4 f0 = reinterpret_cast<const float4*>(s)[j * 2];
  float4 f1 = reinterpret_cast<const float4*>(s)[j * 2 + 1];
  bf16x8 r;
  r[0] = (__bf16)f0.x; r[1] = (__bf16)f0.y; r[2] = (__bf16)f0.z; r[3] = (__bf16)f0.w;
  r[4] = (__bf16)f1.x; r[5] = (__bf16)f1.y; r[6] = (__bf16)f1.z; r[7] = (__bf16)f1.w;
  reinterpret_cast<bf16x8*>(d)[j] = r;
}

__global__ __launch_bounds__(256) void cvt_w(const float* __restrict__ src, __bf16* __restrict__ dst, int n8) {
  int i = blockIdx.x * 256 + threadIdx.x;
  if (i < n8) cvt8_store(src, dst, i);
}

// one launch converts all 4 per-layer weights (qkv, proj, ff1, ff2)
__global__ __launch_bounds__(256) void cvt_w4(const float* __restrict__ sq, const float* __restrict__ sp,
                                              const float* __restrict__ s1, const float* __restrict__ s2,
                                              __bf16* __restrict__ dq, __bf16* __restrict__ dp,
                                              __bf16* __restrict__ d1, __bf16* __restrict__ d2) {
  const int N0 = Dd * 3 * Dd / 8, N1 = Dd * Dd / 8, N2 = Dd * FFf / 8, N3 = FFf * Dd / 8;
  int i = blockIdx.x * 256 + threadIdx.x;
  if (i < N0)                    cvt8_store(sq, dq, i);
  else if (i < N0 + N1)          cvt8_store(sp, dp, i - N0);
  else if (i < N0 + N1 + N2)     cvt8_store(s1, d1, i - N0 - N1);
  else if (i < N0 + N1 + N2 + N3) cvt8_store(s2, d2, i - N0 - N1 - N2);
}

// ---------- h = x + pe (pe broadcast over batch) ----------
__global__ __launch_bounds__(256) void add_pe_k(const float* __restrict__ x, const float* __restrict__ pe,
                                                float* __restrict__ h) {
  long i = (long)blockIdx.x * 256 + threadIdx.x;
  long nd = i % ((long)Nn * Dd);
  h[i] = x[i] + pe[nd];
}

// ---------- LayerNorm; OBF=1 writes bf16 output ----------
template<int OBF>
__global__ __launch_bounds__(256) void ln_kernel(const float* __restrict__ X,
                                                 const float* __restrict__ w, const float* __restrict__ b,
                                                 void* __restrict__ Y) {
  __shared__ float smem[4];
  int row = blockIdx.x, tid = threadIdx.x;
  const float* x = X + (size_t)row * Dd;
  float v[3];
  for (int j = 0; j < 3; ++j) v[j] = x[tid + j * 256];
  float s = v[0] + v[1] + v[2];
  s = block_reduce_sum(s, smem);
  float mean = s * (1.f / 768.f);
  float q = 0.f;
  for (int j = 0; j < 3; ++j) { float d = v[j] - mean; q += d * d; }
  q = block_reduce_sum(q, smem);
  float inv = rsqrtf(q * (1.f / 768.f) + 1e-5f);
  for (int j = 0; j < 3; ++j) {
    int c = tid + j * 256;
    float r = (v[j] - mean) * inv * w[c] + b[c];
    if (OBF) ((__bf16*)Y)[(size_t)row * Dd + c] = (__bf16)r;
    else     ((float*)Y)[(size_t)row * Dd + c] = r;
  }
}

// ---------- residual + LayerNorm: v = h + p0 + p1 + bias; Y = LN(v).
// HRES=0 (post-LN attn stage): h <- LN(v).  HRES=1 (ff2 stage / final): h <- v.
template<int OBF, int HRES>
__global__ __launch_bounds__(256) void res_ln_kernel(float* __restrict__ H,
                                                     const float* __restrict__ P0, const float* __restrict__ P1,
                                                     const float* __restrict__ pb,
                                                     const float* __restrict__ w, const float* __restrict__ b,
                                                     void* __restrict__ Y) {
  __shared__ float smem[4];
  int row = blockIdx.x, tid = threadIdx.x;
  float* x  = H  + (size_t)row * Dd;
  const float* p0 = P0 + (size_t)row * Dd;
  const float* p1 = P1 + (size_t)row * Dd;
  float v[3];
  for (int j = 0; j < 3; ++j) {
    int c = tid + j * 256;
    v[j] = x[c] + (p0[c] + p1[c] + pb[c]);
  }
  float s = v[0] + v[1] + v[2];
  s = block_reduce_sum(s, smem);
  float mean = s * (1.f / 768.f);
  float q = 0.f;
  for (int j = 0; j < 3; ++j) { float d = v[j] - mean; q += d * d; }
  q = block_reduce_sum(q, smem);
  float inv = rsqrtf(q * (1.f / 768.f) + 1e-5f);
  for (int j = 0; j < 3; ++j) {
    int c = tid + j * 256;
    float r = (v[j] - mean) * inv * w[c] + b[c];
    x[c] = HRES ? v[j] : r;
    if (OBF) ((__bf16*)Y)[(size_t)row * Dd + c] = (__bf16)r;
    else     ((float*)Y)[(size_t)row * Dd + c] = r;
  }
}

// ---------- 128xBN MFMA GEMM: A bf16 direct, B bf16 (pre-converted), reg prefetch,
// ---------- XCD chunk swizzle, optional split-K, optional bf16 output ----------
template<int BN, int EPI, int OBF>
__global__ __launch_bounds__(256) void gemm128(
    const __bf16* __restrict__ Ap, long lda,
    const __bf16* __restrict__ Bp, long ldb,
    const float* __restrict__ bias,
    void* __restrict__ Cp, long ldc,
    int Ksize, long czs)
{
  constexpr int FN = BN / 32;
  constexpr int KB = BN / 8;
  int tid = threadIdx.x;

  int nwg2 = gridDim.x * gridDim.y;
  int bid = blockIdx.y * gridDim.x + blockIdx.x;
  int swz = (bid & 7) * (nwg2 >> 3) + (bid >> 3);
  int bx = swz % gridDim.x, by = swz / gridDim.x;
  int m0 = by * 128, n0 = bx * BN;
  int z = blockIdx.z;

  const __bf16* Aq = Ap + (long)z * Ksize;
  const __bf16* Bq = Bp + (long)z * Ksize * ldb;

  __shared__ __align__(16) __bf16 Ah[128][40];
  __shared__ __align__(16) __bf16 Bh[BN][40];

  f32x4 acc[4][FN];
  #pragma unroll
  for (int i = 0; i < 4; ++i)
    #pragma unroll
    for (int j = 0; j < FN; ++j)
      #pragma unroll
      for (int k = 0; k < 4; ++k) acc[i][j][k] = 0.f;

  int lane = tid & 63;
  int w = tid >> 6;
  int WR = (w >> 1) * 64, WC = (w & 1) * (BN / 2);
  int fr = lane & 15, kg = lane >> 4;

  const int ar = tid >> 1, acs = (tid & 1) * 16;
  const int bn = tid % BN;
  const int kb = (tid / BN) * KB;

  const __bf16* Abase = Aq + (long)(m0 + ar) * lda + acs;
  const __bf16* Bbase = Bq + (long)kb * ldb + (n0 + bn);

  bf16x8 pa0, pa1;
  __bf16 pbh[KB];
  {
    pa0 = *reinterpret_cast<const bf16x8*>(Abase);
    pa1 = *reinterpret_cast<const bf16x8*>(Abase + 8);
    #pragma unroll
    for (int j = 0; j < KB; ++j) pbh[j] = Bbase[(long)j * ldb];
  }

  for (int k0 = 0; k0 < Ksize; k0 += 32) {
    __syncthreads();
    {
      *reinterpret_cast<bf16x8*>(&Ah[ar][acs]) = pa0;
      *reinterpret_cast<bf16x8*>(&Ah[ar][acs + 8]) = pa1;
      #pragma unroll
      for (int g8 = 0; g8 < KB / 8; ++g8)
        *reinterpret_cast<bf16x8*>(&Bh[bn][kb + g8 * 8]) = *reinterpret_cast<bf16x8*>(&pbh[g8 * 8]);
    }
    __syncthreads();

    if (k0 + 32 < Ksize) {
      const __bf16* As = Abase + (k0 + 32);
      pa0 = *reinterpret_cast<const bf16x8*>(As);
      pa1 = *reinterpret_cast<const bf16x8*>(As + 8);
      const __bf16* Bs = Bbase + (long)(k0 + 32) * ldb;
      #pragma unroll
      for (int j = 0; j < KB; ++j) pbh[j] = Bs[(long)j * ldb];
    }

    bf16x8 ah[4], bh[FN];
    #pragma unroll
    for (int fm = 0; fm < 4; ++fm)
      ah[fm] = *reinterpret_cast<const bf16x8*>(&Ah[WR + fm * 16 + fr][kg * 8]);
    #pragma unroll
    for (int fn = 0; fn < FN; ++fn)
      bh[fn] = *reinterpret_cast<const bf16x8*>(&Bh[WC + fn * 16 + fr][kg * 8]);
    #pragma unroll
    for (int fm = 0; fm < 4; ++fm)
      #pragma unroll
      for (int fn = 0; fn < FN; ++fn)
        acc[fm][fn] = __builtin_amdgcn_mfma_f32_16x16x32_bf16(ah[fm], bh[fn], acc[fm][fn], 0, 0, 0);
  }

  #pragma unroll
  for (int fm = 0; fm < 4; ++fm)
    #pragma unroll
    for (int fn = 0; fn < FN; ++fn)
      #pragma unroll
      for (int i = 0; i < 4; ++i) {
        int rowg = m0 + WR + fm * 16 + kg * 4 + i;
        int coln = n0 + WC + fn * 16 + fr;
        float v = acc[fm][fn][i];
        if (EPI >= 1) v += bias[coln];
        if (EPI == 2) v = 0.5f * v * (1.f + erff(v * 0.70710678118654752f));
        long ci = (long)z * czs + (long)rowg * ldc + coln;
        if (OBF) ((__bf16*)Cp)[ci] = (__bf16)v;
        else     ((float*)Cp)[ci] = v;
      }
}

// ---------- MFMA flash attention, KV-split x2, bf16 qkv input, register prefetch ----------
__global__ __launch_bounds__(256) void flash_attn_split(const __bf16* __restrict__ qkvb,
                                                        const void* __restrict__ mraw,
                                                        const int* __restrict__ flagp,
                                                        float* __restrict__ p0, float* __restrict__ p1,
                                                        float2* __restrict__ ml) {
  __shared__ __align__(16) __bf16 Qs[64][72];
  __shared__ __align__(16) __bf16 Ks[64][72];
  __shared__ __align__(16) __bf16 Vt[64][66];  // V transposed: [d][key]
  __shared__ __align__(16) __bf16 Ps[64][72];
  __shared__ float kmf[64];
  __shared__ float qmf[64];

  int s = blockIdx.z & 1, b = blockIdx.z >> 1;
  int hh = blockIdx.y;
  int q0 = blockIdx.x * 64;
  int tid = threadIdx.x, lane = tid & 63, w = tid >> 6;
  int flag = *flagp;
  int fr = lane & 15, kg = lane >> 4;

  const int sr = tid >> 2;
  const int sc = (tid & 3) * 16;

  {
    const __bf16* Qsrc = qkvb + ((long)(b * Nn + q0 + sr)) * (3 * Dd) + hh * HDd + sc;
    *reinterpret_cast<bf16x8*>(&Qs[sr][sc])     = *reinterpret_cast<const bf16x8*>(Qsrc);
    *reinterpret_cast<bf16x8*>(&Qs[sr][sc + 8]) = *reinterpret_cast<const bf16x8*>(Qsrc + 8);
    if (tid < 64) qmf[tid] = mask_at(mraw, flag, b * Nn + q0 + tid) ? 1.f : 0.f;
  }
  __syncthreads();

  float qm[4];
  #pragma unroll
  for (int i = 0; i < 4; ++i) qm[i] = qmf[16 * w + kg * 4 + i];

  bf16x8 qa[2];
  #pragma unroll
  for (int ks = 0; ks < 2; ++ks)
    qa[ks] = *reinterpret_cast<const bf16x8*>(&Qs[16 * w + fr][ks * 32 + kg * 8]);

  float mrow[4], lrow[4];
  f32x4 accO[4];
  #pragma unroll
  for (int i = 0; i < 4; ++i) { mrow[i] = -INFINITY; lrow[i] = 0.f; }
  #pragma unroll
  for (int t = 0; t < 4; ++t)
    for (int i = 0; i < 4; ++i) accO[t][i] = 0.f;

  const int jbeg = s * (Nn / 2), jend = jbeg + (Nn / 2);

  bf16x8 rk0, rk1, rv0, rv1;
  {
    const __bf16* Ksrc = qkvb + ((long)(b * Nn + jbeg + sr)) * (3 * Dd) + Dd + hh * HDd + sc;
    const __bf16* Vsrc = Ksrc + Dd;
    rk0 = *reinterpret_cast<const bf16x8*>(Ksrc);
    rk1 = *reinterpret_cast<const bf16x8*>(Ksrc + 8);
    rv0 = *reinterpret_cast<const bf16x8*>(Vsrc);
    rv1 = *reinterpret_cast<const bf16x8*>(Vsrc + 8);
  }

  for (int j0 = jbeg; j0 < jend; j0 += 64) {
    __syncthreads();
    {
      *reinterpret_cast<bf16x8*>(&Ks[sr][sc])     = rk0;
      *reinterpret_cast<bf16x8*>(&Ks[sr][sc + 8]) = rk1;
      #pragma unroll
      for (int j = 0; j < 8; ++j) {
        Vt[sc + j][sr]     = rv0[j];
        Vt[sc + 8 + j][sr] = rv1[j];
      }
      if (tid < 64) kmf[tid] = mask_at(mraw, flag, b * Nn + j0 + tid) ? 1.f : 0.f;
    }
    __syncthreads();

    if (j0 + 64 < jend) {
      const __bf16* Ksrc = qkvb + ((long)(b * Nn + j0 + 64 + sr)) * (3 * Dd) + Dd + hh * HDd + sc;
      const __bf16* Vsrc = Ksrc + Dd;
      rk0 = *reinterpret_cast<const bf16x8*>(Ksrc);
      rk1 = *reinterpret_cast<const bf16x8*>(Ksrc + 8);
      rv0 = *reinterpret_cast<const bf16x8*>(Vsrc);
      rv1 = *reinterpret_cast<const bf16x8*>(Vsrc + 8);
    }

    f32x4 sacc[4];
    #pragma unroll
    for (int t = 0; t < 4; ++t)
      for (int i = 0; i < 4; ++i) sacc[t][i] = 0.f;
    #pragma unroll
    for (int ks = 0; ks < 2; ++ks) {
      #pragma unroll
      for (int t = 0; t < 4; ++t) {
        bf16x8 bh = *reinterpret_cast<const bf16x8*>(&Ks[16 * t + fr][ks * 32 + kg * 8]);
        sacc[t] = __builtin_amdgcn_mfma_f32_16x16x32_bf16(qa[ks], bh, sacc[t], 0, 0, 0);
      }
    }

    float sv[4][4];
    float mt[4] = {-INFINITY, -INFINITY, -INFINITY, -INFINITY};
    #pragma unroll
    for (int t = 0; t < 4; ++t) {
      float km = kmf[16 * t + fr];
      #pragma unroll
      for (int i = 0; i < 4; ++i) {
        float sx = (km > 0.f && qm[i] > 0.f) ? sacc[t][i] * 0.125f : NEGF;
        sv[t][i] = sx;
        mt[i] = fmaxf(mt[i], sx);
      }
    }
    #pragma unroll
    for (int off = 8; off; off >>= 1)
      #pragma unroll
      for (int i = 0; i < 4; ++i) mt[i] = fmaxf(mt[i], __shfl_xor(mt[i], off));

    float r[4], psum[4];
    #pragma unroll
    for (int i = 0; i < 4; ++i) {
      float mn = fmaxf(mrow[i], mt[i]);
      r[i] = __expf(mrow[i] - mn);
      mrow[i] = mn;
      psum[i] = 0.f;
    }
    #pragma unroll
    for (int t = 0; t < 4; ++t) {
      #pragma unroll
      for (int i = 0; i < 4; ++i) {
        float p = __expf(sv[t][i] - mrow[i]);
        psum[i] += p;
        Ps[16 * w + kg * 4 + i][16 * t + fr] = (__bf16)p;
      }
    }
    #pragma unroll
    for (int off = 8; off; off >>= 1)
      #pragma unroll
      for (int i = 0; i < 4; ++i) psum[i] += __shfl_xor(psum[i], off);
    #pragma unroll
    for (int i = 0; i < 4; ++i) lrow[i] = lrow[i] * r[i] + psum[i];
    #pragma unroll
    for (int t = 0; t < 4; ++t)
      #pragma unroll
      for (int i = 0; i < 4; ++i) accO[t][i] *= r[i];

    __syncthreads();

    #pragma unroll
    for (int ks = 0; ks < 2; ++ks) {
      bf16x8 pa = *reinterpret_cast<const bf16x8*>(&Ps[16 * w + fr][ks * 32 + kg * 8]);
      #pragma unroll
      for (int t2 = 0; t2 < 4; ++t2) {
        bf16x8 vb = *reinterpret_cast<const bf16x8*>(&Vt[16 * t2 + fr][ks * 32 + kg * 8]);
        accO[t2] = __builtin_amdgcn_mfma_f32_16x16x32_bf16(pa, vb, accO[t2], 0, 0, 0);
      }
    }
  }

  float* op = s ? p1 : p0;
  #pragma unroll
  for (int t2 = 0; t2 < 4; ++t2)
    #pragma unroll
    for (int i = 0; i < 4; ++i) {
      int qrow = q0 + 16 * w + kg * 4 + i;
      int col = 16 * t2 + fr;
      op[((long)(b * Nn + qrow)) * Dd + hh * HDd + col] = accO[t2][i];  // unnormalized
    }
  if (fr == 0) {
    #pragma unroll
    for (int i = 0; i < 4; ++i) {
      int qrow = q0 + 16 * w + kg * 4 + i;
      ml[((long)(s * Bb + b) * Hh + hh) * Nn + qrow] = make_float2(mrow[i], lrow[i]);
    }
  }
}

// ---------- combine two KV-splits -> bf16 attn output ----------
__global__ __launch_bounds__(256) void flash_combine(const float* __restrict__ p0, const float* __restrict__ p1,
                                                     const float2* __restrict__ ml, __bf16* __restrict__ ob) {
  long i4 = (long)blockIdx.x * 256 + threadIdx.x;
  long i = i4 * 4;
  int d = (int)(i % Dd);
  long row = i / Dd;
  int b = (int)(row >> 10), n = (int)(row & (Nn - 1));
  int hh = d >> 6;
  float2 a = ml[((long)b * Hh + hh) * Nn + n];
  float2 c = ml[(((long)Bb + b) * Hh + hh) * Nn + n];
  float M = fmaxf(a.x, c.x);
  float w0 = __expf(a.x - M), w1 = __expf(c.x - M);
  float inv = 1.f / (w0 * a.y + w1 * c.y);
  float4 v0 = reinterpret_cast<const float4*>(p0)[i4];
  float4 v1 = reinterpret_cast<const float4*>(p1)[i4];
  bf16x4 r;
  r[0] = (__bf16)((w0 * v0.x + w1 * v1.x) * inv);
  r[1] = (__bf16)((w0 * v0.y + w1 * v1.y) * inv);
  r[2] = (__bf16)((w0 * v0.z + w1 * v1.z) * inv);
  r[3] = (__bf16)((w0 * v0.w + w1 * v1.w) * inv);
  *reinterpret_cast<bf16x4*>(&ob[i]) = r;
}

// ---------- seq-pool ----------
__global__ __launch_bounds__(256) void pool_score(const float* __restrict__ hn, const float* __restrict__ pw,
                                                  const float* __restrict__ pb, float* __restrict__ s) {
  __shared__ float smem[4];
  int row = blockIdx.x, tid = threadIdx.x;
  const float* x = hn + (size_t)row * Dd;
  float acc = 0.f;
  for (int j = 0; j < 3; ++j) { int c = tid + j * 256; acc += x[c] * pw[c]; }
  acc = block_reduce_sum(acc, smem);
  if (tid == 0) s[row] = acc + pb[0];
}

__global__ __launch_bounds__(256) void pool_softmax(const float* __restrict__ s, float* __restrict__ w) {
  __shared__ float smem[4];
  int b = blockIdx.x, tid = threadIdx.x;
  const float* x = s + b * Nn;
  float v[4];
  for (int j = 0; j < 4; ++j) v[j] = x[tid * 4 + j];
  float mx = fmaxf(fmaxf(v[0], v[1]), fmaxf(v[2], v[3]));
  mx = block_reduce_max(mx, smem);
  float e[4], sum = 0.f;
  for (int j = 0; j < 4; ++j) { e[j] = expf(v[j] - mx); sum += e[j]; }
  sum = block_reduce_sum(sum, smem);
  float inv = 1.f / sum;
  for (int j = 0; j < 4; ++j) w[b * Nn + tid * 4 + j] = e[j] * inv;
}

// stage 1: partial sums over 128-token chunks. grid (Dd/256, 8, Bb), block 256.
__global__ __launch_bounds__(256) void pool_reduce1(const float* __restrict__ hn, const float* __restrict__ w,
                                                    float* __restrict__ part) {
  int d = blockIdx.x * 256 + threadIdx.x;
  int ch = blockIdx.y, b = blockIdx.z;
  int n0 = ch * 128;
  float a0 = 0.f, a1 = 0.f;
  for (int n = n0; n < n0 + 128; n += 2) {
    a0 = fmaf(w[b * Nn + n],     hn[((size_t)(b * Nn + n))     * Dd + d], a0);
    a1 = fmaf(w[b * Nn + n + 1], hn[((size_t)(b * Nn + n + 1)) * Dd + d], a1);
  }
  part[((size_t)(b * 8 + ch)) * Dd + d] = a0 + a1;
}

// stage 2: sum 8 partials. grid (Dd/256, Bb), block 256.
__global__ __launch_bounds__(256) void pool_reduce2(const float* __restrict__ part, float* __restrict__ pooled) {
  int d = blockIdx.x * 256 + threadIdx.x;
  int b = blockIdx.y;
  float s = 0.f;
  #pragma unroll
  for (int ch = 0; ch < 8; ++ch) s += part[((size_t)(b * 8 + ch)) * Dd + d];
  pooled[b * Dd + d] = s;
}

// fc: one class per thread, coalesced over c. grid (4, Bb), block 256.
__global__ __launch_bounds__(256) void fc_kernel(const float* __restrict__ pooled, const float* __restrict__ fw,
                                                 const float* __restrict__ fb, float* __restrict__ out) {
  __shared__ float p[768];
  int b = blockIdx.y, tid = threadIdx.x;
  for (int j = 0; j < 3; ++j) p[tid + j * 256] = pooled[b * Dd + tid + j * 256];
  __syncthreads();
  int c = blockIdx.x * 256 + tid;
  if (c < NCc) {
    float a0 = 0.f, a1 = 0.f, a2 = 0.f, a3 = 0.f;
    #pragma unroll 4
    for (int d = 0; d < Dd; d += 4) {
      a0 = fmaf(p[d],     fw[(size_t)d       * NCc + c], a0);
      a1 = fmaf(p[d + 1], fw[(size_t)(d + 1) * NCc + c], a1);
      a2 = fmaf(p[d + 2], fw[(size_t)(d + 2) * NCc + c], a2);
      a3 = fmaf(p[d + 3], fw[(size_t)(d + 3) * NCc + c], a3);
    }
    out[b * NCc + c] = fb[c] + ((a0 + a1) + (a2 + a3));
  }
}

extern "C" void kernel_launch(void* const* d_in, const int* in_sizes, int n_in,
                              void* d_out, int out_size, void* d_ws, size_t ws_size,
                              hipStream_t stream) {
  const float* x      = (const float*)d_in[0];
  const void*  mask   = d_in[1];
  const float* pe     = (const float*)d_in[2];
  const float* ln0_w  = (const float*)d_in[3];
  const float* ln0_b  = (const float*)d_in[4];
  const float* qkv_w  = (const float*)d_in[5];
  const float* proj_w = (const float*)d_in[6];
  const float* proj_b = (const float*)d_in[7];
  const float* ln1_w  = (const float*)d_in[8];
  const float* ln1_b  = (const float*)d_in[9];
  const float* ff1_w  = (const float*)d_in[10];
  const float* ff1_b  = (const float*)d_in[11];
  const float* ff2_w  = (const float*)d_in[12];
  const float* ff2_b  = (const float*)d_in[13];
  const float* norm_w = (const float*)d_in[14];
  const float* norm_b = (const float*)d_in[15];
  const float* pool_w = (const float*)d_in[16];
  const float* pool_b = (const float*)d_in[17];
  const float* fc_w   = (const float*)d_in[18];
  const float* fc_b   = (const float*)d_in[19];
  float* out = (float*)d_out;

  float* ws = (float*)d_ws;
  float*  h     = ws;                            // Mm*Dd f32 (residual)
  float*  s0    = h + (long)Mm * Dd;             // Mm*Dd f32 scratch
  float*  s1    = s0 + (long)Mm * Dd;            // Mm*Dd f32 scratch
  __bf16* qkvb  = (__bf16*)(s1 + (long)Mm * Dd); // Mm*3*Dd bf16
  __bf16* ob    = qkvb + (long)Mm * 3 * Dd;      // Mm*Dd bf16 (attn out)
  __bf16* yb    = ob + (long)Mm * Dd;            // Mm*Dd bf16 (ln out)

  // Weight-buffer region: big layout (4 separate, 14.2 MB) if ws_size allows; else one shared 4.7 MB.
  const bool bigws = ws_size >= (size_t)54 * 1024 * 1024;
  __bf16* wreg = yb + (long)Mm * Dd;
  __bf16 *wq, *wp, *w1, *w2;
  __bf16* wend;
  if (bigws) {
    wq = wreg;
    wp = wq + (long)Dd * 3 * Dd;
    w1 = wp + (long)Dd * Dd;
    w2 = w1 + (long)Dd * FFf;
    wend = w2 + (long)FFf * Dd;
  } else {
    wq = wp = w1 = w2 = wreg;
    wend = wreg + (long)Dd * FFf;
  }
  float*  tail  = (float*)wend;
  float*  spool  = tail;                         // Mm
  float*  wpool  = spool + Mm;                   // Mm
  float*  pooled = wpool + Mm;                   // Bb*Dd
  float*  ppart  = pooled + Bb * Dd;             // Bb*8*Dd
  float*  mlbuf  = ppart + (long)Bb * 8 * Dd;    // 2*Bb*Hh*Nn float2
  int*    mflag  = (int*)(mlbuf + (long)2 * 2 * Bb * Hh * Nn);
  __bf16* gb = qkvb;     // alias: gelu out Mm*FFf bf16 == qkvb+ob region exactly
  float*  hn = s0;       // final LN out (after loop; s0 free)

  const int n8_qkv  = Dd * 3 * Dd / 8;
  const int n8_proj = Dd * Dd / 8;
  const int n8_ff   = Dd * FFf / 8;
  const int n8_all  = n8_qkv + n8_proj + 2 * n8_ff;

  detect_mask<<<1, 256, 0, stream>>>((const unsigned char*)mask, mflag);
  add_pe_k<<<(Mm * Dd) / 256, 256, 0, stream>>>(x, pe, h);
  ln_kernel<1><<<Mm, 256, 0, stream>>>(h, ln0_w, ln0_b, yb);

  for (int l = 0; l < NLl; ++l) {
    if (bigws) {
      // one conversion launch for all 4 weights of this layer
      cvt_w4<<<(n8_all + 255) / 256, 256, 0, stream>>>(
          qkv_w + (long)l * Dd * 3 * Dd, proj_w + (long)l * Dd * Dd,
          ff1_w + (long)l * Dd * FFf, ff2_w + (long)l * FFf * Dd,
          wq, wp, w1, w2);
    } else {
      cvt_w<<<(n8_qkv + 255) / 256, 256, 0, stream>>>(qkv_w + (long)l * Dd * 3 * Dd, wq, n8_qkv);
    }

    gemm128<64,0,1><<<dim3(3 * Dd / 64, Mm / 128, 1), 256, 0, stream>>>(
        yb, Dd, wq, 3 * Dd, nullptr, qkvb, 3 * Dd, Dd, 0);

    flash_attn_split<<<dim3(Nn / 64, Hh, Bb * 2), 256, 0, stream>>>(
        qkvb, mask, mflag, s0, s1, (float2*)mlbuf);
    flash_combine<<<(Mm * Dd / 4) / 256, 256, 0, stream>>>(s0, s1, (const float2*)mlbuf, ob);

    if (!bigws)
      cvt_w<<<(n8_proj + 255) / 256, 256, 0, stream>>>(proj_w + (long)l * Dd * Dd, wp, n8_proj);
    gemm128<64,0,0><<<dim3(Dd / 64, Mm / 128, 2), 256, 0, stream>>>(
        ob, Dd, wp, Dd, nullptr, s0, Dd, Dd / 2, (long)(s1 - s0));

    res_ln_kernel<1,0><<<Mm, 256, 0, stream>>>(h, s0, s1, proj_b + l * Dd,
                                               ln1_w + l * Dd, ln1_b + l * Dd, yb);

    if (!bigws)
      cvt_w<<<(n8_ff + 255) / 256, 256, 0, stream>>>(ff1_w + (long)l * Dd * FFf, w1, n8_ff);
    gemm128<64,2,1><<<dim3(FFf / 64, Mm / 128, 1), 256, 0, stream>>>(
        yb, Dd, w1, FFf, ff1_b + l * FFf, gb, FFf, Dd, 0);

    if (!bigws)
      cvt_w<<<(n8_ff + 255) / 256, 256, 0, stream>>>(ff2_w + (long)l * FFf * Dd, w2, n8_ff);
    gemm128<64,0,0><<<dim3(Dd / 64, Mm / 128, 2), 256, 0, stream>>>(
        gb, FFf, w2, Dd, nullptr, s0, Dd, FFf / 2, (long)(s1 - s0));

    if (l + 1 < NLl) {
      res_ln_kernel<1,1><<<Mm, 256, 0, stream>>>(h, s0, s1, ff2_b + l * Dd,
                                                 ln0_w + (l + 1) * Dd, ln0_b + (l + 1) * Dd, yb);
    } else {
      res_ln_kernel<0,1><<<Mm, 256, 0, stream>>>(h, s0, s1, ff2_b + l * Dd,
                                                 norm_w, norm_b, hn);
    }
  }

  pool_score<<<Mm, 256, 0, stream>>>(hn, pool_w, pool_b, spool);
  pool_softmax<<<Bb, 256, 0, stream>>>(spool, wpool);
  pool_reduce1<<<dim3(Dd / 256, 8, Bb), 256, 0, stream>>>(hn, wpool, ppart);
  pool_reduce2<<<dim3(Dd / 256, Bb), 256, 0, stream>>>(ppart, pooled);
  fc_kernel<<<dim3(4, Bb), 256, 0, stream>>>(pooled, fc_w, fc_b, out);
}